// Round 13
// baseline (1141.734 us; speedup 1.0000x reference)
//
#include <hip/hip_runtime.h>

typedef __attribute__((ext_vector_type(8))) short bf16x8;
typedef __attribute__((ext_vector_type(4))) float f32x4;

#define N_LAYER 4
#define QLEN 512
#define MLEN 512
#define KLEN 1024
#define BSZ 4
#define DM 1024
#define NH 16
#define DH 64
#define DINNER 4096
#define EK 1408
#define BDLD 1152  // BDs row stride (1024 + 128 pad; pad cols never written, always masked)

__device__ __forceinline__ unsigned short f2bf(float x) {
    unsigned u = __float_as_uint(x);
    u += 0x7fffu + ((u >> 16) & 1u);
    return (unsigned short)(u >> 16);
}
__device__ __forceinline__ float bf2f(unsigned short v) {
    return __uint_as_float(((unsigned)v) << 16);
}

__device__ __forceinline__ void gload16(const unsigned short* g, unsigned short* l) {
    __builtin_amdgcn_global_load_lds(
        (const __attribute__((address_space(1))) unsigned int*)g,
        (__attribute__((address_space(3))) unsigned int*)l, 16, 0, 0);
}

// swizzled b128 LDS read for 128B-row-stride bf16 tiles: byte ^= (row&7)<<4
__device__ __forceinline__ bf16x8 lds_read8_sw(const unsigned short* base, int row, int cb) {
    return *(const bf16x8*)((const char*)base + row * 128 + (cb ^ ((row & 7) << 4)));
}

// ---------------------------------------------------------------------------
// All 5 per-layer weight transposes in ONE launch. 64x64 tiles, float4 in /
// uint4 (8 bf16) out.
// ---------------------------------------------------------------------------
__global__ __launch_bounds__(256)
void transpose_all(const float* __restrict__ qkvWl, const float* __restrict__ rWl,
                   const float* __restrict__ oWl, const float* __restrict__ w1l,
                   const float* __restrict__ w2l,
                   unsigned short* __restrict__ qkvT, unsigned short* __restrict__ rT,
                   unsigned short* __restrict__ oT, unsigned short* __restrict__ w1T,
                   unsigned short* __restrict__ w2T) {
    __shared__ float tile[64][65];
    int id = blockIdx.x;
    const float* W; unsigned short* D; int K, N, bx, by;
    if (id < 768)       { W = qkvWl; D = qkvT; K = 1024; N = 3072; bx = id % 48; by = id / 48; }
    else if (id < 1024) { id -= 768;  W = rWl;  D = rT;  K = 1024; N = 1024; bx = id & 15; by = id >> 4; }
    else if (id < 1280) { id -= 1024; W = oWl;  D = oT;  K = 1024; N = 1024; bx = id & 15; by = id >> 4; }
    else if (id < 2304) { id -= 1280; W = w1l;  D = w1T; K = 1024; N = 4096; bx = id & 63; by = id >> 6; }
    else                { id -= 2304; W = w2l;  D = w2T; K = 4096; N = 1024; bx = id & 15; by = id >> 4; }
    const int tid = threadIdx.x;
#pragma unroll
    for (int s = 0; s < 4; ++s) {
        int idx = s * 256 + tid;
        int kr = idx >> 4, c4 = (idx & 15) * 4;
        float4 v = *(const float4*)(W + (size_t)(by * 64 + kr) * N + bx * 64 + c4);
        tile[kr][c4] = v.x; tile[kr][c4 + 1] = v.y;
        tile[kr][c4 + 2] = v.z; tile[kr][c4 + 3] = v.w;
    }
    __syncthreads();
#pragma unroll
    for (int s = 0; s < 2; ++s) {
        int idx = s * 256 + tid;
        int nl = idx >> 3, k8 = (idx & 7) * 8;
        unsigned short tmp[8];
#pragma unroll
        for (int j = 0; j < 8; ++j) tmp[j] = f2bf(tile[k8 + j][nl]);
        *(uint4*)(D + (size_t)(bx * 64 + nl) * K + by * 64 + k8) = *(uint4*)tmp;
    }
}

// Transpose with zero-padding beyond K rows, into a slice of a wider dst row.
__global__ __launch_bounds__(256)
void transpose_pad(const float* __restrict__ W, unsigned short* __restrict__ dst,
                   int K, int N, int dstLD, int dstOff) {
    __shared__ float tile[32][33];
    const int tx = threadIdx.x & 31, ty = threadIdx.x >> 5;
    const int bx = blockIdx.x, by = blockIdx.y;
#pragma unroll
    for (int i = 0; i < 4; ++i) {
        int k = by * 32 + ty + i * 8;
        tile[ty + i * 8][tx] = (k < K) ? W[(size_t)k * N + bx * 32 + tx] : 0.f;
    }
    __syncthreads();
#pragma unroll
    for (int i = 0; i < 4; ++i) {
        int n = bx * 32 + ty + i * 8;
        int k = by * 32 + tx;
        dst[(size_t)n * dstLD + dstOff + k] = f2bf(tile[tx][ty + i * 8]);
    }
}

// ---------------------------------------------------------------------------
// Adaptive-embedding gather: embA[t][0:1408) = masked cluster row * 32, bf16
// ---------------------------------------------------------------------------
__global__ __launch_bounds__(256)
void emb_gather(const int* __restrict__ ids,
                const float* __restrict__ e0, const float* __restrict__ e1,
                const float* __restrict__ e2, const float* __restrict__ e3,
                unsigned short* __restrict__ embA) {
    const int chunk = blockIdx.x * 256 + threadIdx.x;
    if (chunk >= 2048 * 176) return;
    const int t = chunk / 176;
    const int e8 = (chunk - t * 176) * 8;
    const int i = t >> 2, b = t & 3;
    const int id = ids[b * QLEN + i];
    const float* src = nullptr;
    if (e8 < 1024) {
        if (id < 20000) src = e0 + (size_t)id * 1024 + e8;
    } else if (e8 < 1280) {
        if (id >= 20000 && id < 40000) src = e1 + (size_t)(id - 20000) * 256 + (e8 - 1024);
    } else if (e8 < 1344) {
        if (id >= 40000 && id < 200000) src = e2 + (size_t)(id - 40000) * 64 + (e8 - 1280);
    } else if (e8 < 1360) {
        if (id >= 200000) src = e3 + (size_t)(id - 200000) * 16 + (e8 - 1344);
    }
    uint4 o = {0u, 0u, 0u, 0u};
    if (src) {
        float4 v0 = *(const float4*)src;
        float4 v1 = *(const float4*)(src + 4);
        o.x = (unsigned)f2bf(v0.x * 32.f) | ((unsigned)f2bf(v0.y * 32.f) << 16);
        o.y = (unsigned)f2bf(v0.z * 32.f) | ((unsigned)f2bf(v0.w * 32.f) << 16);
        o.z = (unsigned)f2bf(v1.x * 32.f) | ((unsigned)f2bf(v1.y * 32.f) << 16);
        o.w = (unsigned)f2bf(v1.z * 32.f) | ((unsigned)f2bf(v1.w * 32.f) << 16);
    }
    *(uint4*)(embA + (size_t)t * EK + e8) = o;
}

// ---------------------------------------------------------------------------
// GEMM: C[M,N] = A[M,K] @ B[K,N], A bf16 row-major, BT = B^T bf16 (N x K)
// 128xBN tile, BK=64 2-phase dbuf global_load_lds, T2 swizzle, XCD swizzle.
// MODE 3 folds the 1/8 attention scale into Qw. MODE 5: C f32 + Cbf bf16.
// ---------------------------------------------------------------------------
template <int MODE, int BN>
__global__ __launch_bounds__(256)
void gemm_bt(const unsigned short* __restrict__ A, const unsigned short* __restrict__ BT,
             float* __restrict__ C, unsigned short* __restrict__ Cbf,
             const float* __restrict__ bias,
             const float* __restrict__ rwb, const float* __restrict__ rrb,
             unsigned short* __restrict__ Qw, unsigned short* __restrict__ Qr,
             unsigned short* __restrict__ Kb, unsigned short* __restrict__ VTb,
             int M, int N, int K) {
    constexpr int NF = BN / 32;           // n-frags per wave
    __shared__ unsigned short lA[2][128 * 64];
    __shared__ unsigned short lB[2][BN * 64];
    const int tid = threadIdx.x;
    const int w = tid >> 6, l = tid & 63;
    const int lane15 = l & 15, lh = l >> 4;
    const int nwg = gridDim.x;
    const int cpx = nwg >> 3;
    const int swz = (blockIdx.x & 7) * cpx + (blockIdx.x >> 3);
    const int nbn = N / BN;
    const int bm = swz / nbn, bn = swz % nbn;
    const int wr = (w >> 1) * 64, wc = (w & 1) * (BN / 2);

    f32x4 acc[4][NF] = {};

    const unsigned short* gA = A + (size_t)(bm * 128) * K;
    const unsigned short* gB = BT + (size_t)(bn * BN) * K;

    auto stage = [&](int buf, int k0) {
#pragma unroll
        for (int s = 0; s < 4; ++s) {
            int g = tid + s * 256, row = g >> 3;
            gload16(gA + (size_t)row * K + k0 + ((g & 7) ^ (row & 7)) * 8,
                    lA[buf] + g * 8);
        }
#pragma unroll
        for (int s = 0; s < BN / 32; ++s) {
            int g = tid + s * 256, row = g >> 3;
            gload16(gB + (size_t)row * K + k0 + ((g & 7) ^ (row & 7)) * 8,
                    lB[buf] + g * 8);
        }
    };

    stage(0, 0);
    __syncthreads();
    int cur = 0;
    for (int k0 = 0; k0 < K; k0 += 64) {
        if (k0 + 64 < K) stage(cur ^ 1, k0 + 64);
        const unsigned short* cA = lA[cur];
        const unsigned short* cB = lB[cur];
#pragma unroll
        for (int kk = 0; kk < 2; ++kk) {
            bf16x8 af[4], bfr[NF];
#pragma unroll
            for (int f = 0; f < 4; ++f)
                af[f] = lds_read8_sw(cA, wr + f * 16 + lane15, kk * 64 + lh * 16);
#pragma unroll
            for (int f = 0; f < NF; ++f)
                bfr[f] = lds_read8_sw(cB, wc + f * 16 + lane15, kk * 64 + lh * 16);
#pragma unroll
            for (int mi = 0; mi < 4; ++mi)
#pragma unroll
                for (int ni = 0; ni < NF; ++ni)
                    acc[mi][ni] = __builtin_amdgcn_mfma_f32_16x16x32_bf16(
                        af[mi], bfr[ni], acc[mi][ni], 0, 0, 0);
        }
        __syncthreads();
        cur ^= 1;
    }

#pragma unroll
    for (int mi = 0; mi < 4; ++mi) {
        int rowb = bm * 128 + wr + mi * 16 + lh * 4;   // multiple of 4
#pragma unroll
        for (int ni = 0; ni < NF; ++ni) {
            int col = bn * BN + wc + ni * 16 + lane15;
#pragma unroll
            for (int r = 0; r < 4; ++r) {
                float x = acc[mi][ni][r];
                if (MODE == 0) {
                    C[(size_t)(rowb + r) * N + col] = x;
                } else if (MODE == 1) {
                    x += bias[col];
                    Cbf[(size_t)(rowb + r) * N + col] = f2bf(x > 0.f ? x : 0.f);
                } else if (MODE == 2) {
                    C[(size_t)(rowb + r) * N + col] = x + bias[col];
                } else if (MODE == 3) {
                    int j = rowb >> 2;
                    int bb_ = r;
                    if (col < 1024) {
                        if (j >= MLEN) {
                            int i = j - MLEN, n = col >> 6, d = col & 63;
                            size_t o = ((size_t)(bb_ * NH + n) * QLEN + i) * DH + d;
                            Qw[o] = f2bf((x + rwb[col]) * 0.125f);   // fold attn scale
                            Qr[o] = f2bf(x + rrb[col]);
                        }
                    } else if (col < 2048) {
                        int c2 = col - 1024, n = c2 >> 6, d = c2 & 63;
                        Kb[((size_t)(bb_ * NH + n) * KLEN + j) * DH + d] = f2bf(x);
                    } else {
                        int c2 = col - 2048, n = c2 >> 6, d = c2 & 63;
                        VTb[((size_t)(bb_ * NH + n) * DH + d) * KLEN + j] = f2bf(x);
                    }
                } else if (MODE == 4) {
                    int j = rowb + r;
                    int n = col >> 6, d = col & 63;
                    Kb[((size_t)n * KLEN + j) * DH + d] = f2bf(x);  // Kb := Rb here
                } else { // MODE 5: f32 + bf16 dual write
                    C[(size_t)(rowb + r) * N + col] = x;
                    Cbf[(size_t)(rowb + r) * N + col] = f2bf(x);
                }
            }
        }
    }
}

// ---------------------------------------------------------------------------
// Batched BD GEMM: BDs[bn][i][k] = (Qr[bn][i][:] . Rb[n][k][:]) * 0.125
// ---------------------------------------------------------------------------
__global__ __launch_bounds__(256)
void bd_gemm(const unsigned short* __restrict__ Qr, const unsigned short* __restrict__ Rb,
             unsigned short* __restrict__ BDs) {
    __shared__ unsigned short lA[128 * 64];
    __shared__ unsigned short lB[128 * 64];
    const int tid = threadIdx.x;
    const int w = tid >> 6, l = tid & 63;
    const int lane15 = l & 15, lh = l >> 4;
    const int blk = blockIdx.x;
    const int bn = blk & 63;          // head-local XCD
    const int tile = blk >> 6;        // 0..31
    const int mi_ = tile & 3, nj = tile >> 2;
    const int n = bn & 15;
    const int wr = (w >> 1) * 64, wc = (w & 1) * 64;

    const unsigned short* gA = Qr + (size_t)bn * QLEN * DH + (size_t)(mi_ * 128) * 64;
    const unsigned short* gB = Rb + (size_t)n * KLEN * DH + (size_t)(nj * 128) * 64;
#pragma unroll
    for (int s = 0; s < 4; ++s) {
        int g = tid + s * 256, row = g >> 3;
        gload16(gA + (size_t)row * 64 + ((g & 7) ^ (row & 7)) * 8, lA + g * 8);
        gload16(gB + (size_t)row * 64 + ((g & 7) ^ (row & 7)) * 8, lB + g * 8);
    }
    __syncthreads();
    f32x4 acc[4][4] = {};
#pragma unroll
    for (int kk = 0; kk < 2; ++kk) {
        bf16x8 af[4], bfr[4];
#pragma unroll
        for (int f = 0; f < 4; ++f) {
            af[f]  = lds_read8_sw(lA, wr + f * 16 + lane15, kk * 64 + lh * 16);
            bfr[f] = lds_read8_sw(lB, wc + f * 16 + lane15, kk * 64 + lh * 16);
        }
#pragma unroll
        for (int mi = 0; mi < 4; ++mi)
#pragma unroll
            for (int ni = 0; ni < 4; ++ni)
                acc[mi][ni] = __builtin_amdgcn_mfma_f32_16x16x32_bf16(
                    af[mi], bfr[ni], acc[mi][ni], 0, 0, 0);
    }
    unsigned short* out = BDs + (size_t)bn * 512 * BDLD;
#pragma unroll
    for (int mi = 0; mi < 4; ++mi) {
        int rowb = mi_ * 128 + wr + mi * 16 + lh * 4;
#pragma unroll
        for (int ni = 0; ni < 4; ++ni) {
            int col = nj * 128 + wc + ni * 16 + lane15;
#pragma unroll
            for (int r = 0; r < 4; ++r)
                out[(size_t)(rowb + r) * BDLD + col] = f2bf(acc[mi][ni][r] * 0.125f);
        }
    }
}

// ---------------------------------------------------------------------------
// Positional embedding table (1024 x 1024), bf16
// ---------------------------------------------------------------------------
__global__ __launch_bounds__(256)
void pos_kernel(unsigned short* __restrict__ posbf) {
    const int p = blockIdx.x, tid = threadIdx.x;
    const float ps = (float)(KLEN - 1 - p);
    const float c = -2.0f * 9.210340371976184f / 1024.0f; // -2*ln(10000)/D
#pragma unroll
    for (int j4 = 0; j4 < 4; ++j4) {
        int j = tid + j4 * 256;
        int m = (j < 512) ? j : j - 512;
        float freq = __expf((float)m * c);
        float ang = ps * freq;
        float v = (j < 512) ? sinf(ang) : cosf(ang);
        posbf[(size_t)p * DM + j] = f2bf(v);
    }
}

// ---------------------------------------------------------------------------
// mems[l] rows -> bf16 catb rows [0,2048)  (h-half written by ln2/emb gemm)
// ---------------------------------------------------------------------------
__global__ __launch_bounds__(256)
void mems_cat(const float* __restrict__ mem_l, unsigned short* __restrict__ catbf) {
    const int t = blockIdx.x, tid = threadIdx.x;
    float4 v = ((const float4*)(mem_l + (size_t)t * DM))[tid];
    uint2 o;
    o.x = (unsigned)f2bf(v.x) | ((unsigned)f2bf(v.y) << 16);
    o.y = (unsigned)f2bf(v.z) | ((unsigned)f2bf(v.w) << 16);
    ((uint2*)(catbf + (size_t)t * DM))[tid] = o;
}

// ---------------------------------------------------------------------------
// Split-j-chunk rel-attention, stage 1: one wave per block; BD precomputed;
// constant-shift softmax; ones-MFMA row sums; 2-DEEP SOFTWARE PIPELINE:
// K/V fragments of tile jt+1 prefetched into a second register set while
// tile jt computes (chunk length <= 3, fully unrolled, static indexing).
// ---------------------------------------------------------------------------
__global__ __launch_bounds__(64)
void attn_part(const unsigned short* __restrict__ Qw,
               const unsigned short* __restrict__ Kb, const unsigned short* __restrict__ VTb,
               const unsigned short* __restrict__ BDs,
               unsigned short* __restrict__ Opart, float* __restrict__ ms) {
    __shared__ unsigned short lP[16 * 64];

    const int l = threadIdx.x;
    const int lane15 = l & 15, lh = l >> 4;
    const int blk = blockIdx.x;
    const int bn = blk & 63;          // head-local XCD
    const int rest = blk >> 6;        // 0..143
    const int rg = rest & 3;          // 16-row group within the 64-row i-tile
    const int c = rest >> 2;          // 0..35 chunk unit

    const int offt[8] = {0, 3, 7, 11, 15, 20, 25, 30};
    const int nctt[8] = {3, 4, 4, 4, 5, 5, 5, 6};
    int it = 0;
#pragma unroll
    for (int i = 1; i < 8; ++i) if (c >= offt[i]) it = i;
    const int cl = c - offt[it];
    const int nck = nctt[it];
    const int ntiles = it + 9;
    const int jt0 = (cl * ntiles) / nck;
    const int jt1 = ((cl + 1) * ntiles) / nck;
    const int nt = jt1 - jt0;         // 2 or 3
    const int i0 = it * 64;
    const int rowl = rg * 16 + lh * 4;

    bf16x8 qw[2];
    {
        size_t qb = ((size_t)bn * QLEN + i0 + rg * 16 + lane15) * DH + lh * 8;
        qw[0] = *(const bf16x8*)(Qw + qb);
        qw[1] = *(const bf16x8*)(Qw + qb + 32);
    }
    bf16x8 onesb;
#pragma unroll
    for (int j = 0; j < 8; ++j) onesb[j] = (short)0x3F80;   // bf16 1.0

    const unsigned short* kp = Kb + (size_t)bn * KLEN * DH + (size_t)(jt0 * 64 + lane15) * DH + lh * 8;
    const unsigned short* vp = VTb + (size_t)bn * DH * KLEN + (size_t)lane15 * KLEN + jt0 * 64 + lh * 8;
    const unsigned short* bdp[4];
#pragma unroll
    for (int r = 0; r < 4; ++r) {
        int row = i0 + rowl + r;                       // absolute i (<= 511)
        bdp[r] = BDs + (size_t)bn * 512 * BDLD + (size_t)row * BDLD
                 + (511 - row) + jt0 * 64 + lane15;    // col k = 511 + j - i
    }

    f32x4 oacc[4] = {};
    f32x4 srowv = {};   // row sums via ones-MFMA

    auto loadt = [&](bf16x8 (&kf)[2][4], bf16x8 (&vf)[2][4], int d) {
#pragma unroll
        for (int f = 0; f < 4; ++f) {
            const unsigned short* p = kp + (size_t)(d * 64 + f * 16) * DH;
            kf[0][f] = *(const bf16x8*)p;
            kf[1][f] = *(const bf16x8*)(p + 32);
        }
#pragma unroll
        for (int kk = 0; kk < 2; ++kk)
#pragma unroll
            for (int f = 0; f < 4; ++f)
                vf[kk][f] = *(const bf16x8*)(vp + d * 64 + (size_t)(f * 16) * KLEN + kk * 32);
    };

    auto computet = [&](bf16x8 (&kf)[2][4], bf16x8 (&vf)[2][4], int jt) {
        const int d = jt - jt0;
        float bdv[4][4];
#pragma unroll
        for (int f = 0; f < 4; ++f)
#pragma unroll
            for (int r = 0; r < 4; ++r)
                bdv[f][r] = bf2f(bdp[r][d * 64 + 16 * f]);

        f32x4 sac[4] = {};
        __builtin_amdgcn_s_setprio(1);
#pragma unroll
        for (int kk = 0; kk < 2; ++kk)
#pragma unroll
            for (int f = 0; f < 4; ++f)
                sac[f] = __builtin_amdgcn_mfma_f32_16x16x32_bf16(qw[kk], kf[kk][f], sac[f], 0, 0, 0);
        __builtin_amdgcn_s_setprio(0);

        const bool lastTile = (jt == it + 8);
        float pv[4][4];
#pragma unroll
        for (int f = 0; f < 4; ++f) {
            int lj = lane15 + 16 * f;
#pragma unroll
            for (int r = 0; r < 4; ++r) {
                float s = sac[f][r] + bdv[f][r];
                if (lastTile && (lj > rowl + r)) s = -1e30f;
                pv[f][r] = __expf(s - 8.f);
            }
        }
#pragma unroll
        for (int f = 0; f < 4; ++f)
#pragma unroll
            for (int r = 0; r < 4; ++r) {
                int row = lh * 4 + r, cb2 = (lane15 + 16 * f) * 2;
                *(unsigned short*)((char*)lP + row * 128 + (cb2 ^ ((row & 7) << 4))) =
                    f2bf(pv[f][r]);
            }
        bf16x8 pa0 = lds_read8_sw(lP, lane15, lh * 16);
        bf16x8 pa1 = lds_read8_sw(lP, lane15, 64 + lh * 16);

        __builtin_amdgcn_s_setprio(1);
#pragma unroll
        for (int f = 0; f < 4; ++f)
            oacc[f] = __builtin_amdgcn_mfma_f32_16x16x32_bf16(pa0, vf[0][f], oacc[f], 0, 0, 0);
        srowv = __builtin_amdgcn_mfma_f32_16x16x32_bf16(pa0, onesb, srowv, 0, 0, 0);
#pragma unroll
        for (int f = 0; f < 4; ++f)
            oacc[f] = __builtin_amdgcn_mfma_f32_16x16x32_bf16(pa1, vf[1][f], oacc[f], 0, 0, 0);
        srowv = __builtin_amdgcn_mfma_f32_16x16x32_bf16(pa1, onesb, srowv, 0, 0, 0);
        __builtin_amdgcn_s_setprio(0);
    };

    bf16x8 kfA[2][4], vfA[2][4], kfB[2][4], vfB[2][4];
    loadt(kfA, vfA, 0);
    if (nt >= 2) loadt(kfB, vfB, 1);
    computet(kfA, vfA, jt0);
    if (nt == 2) {
        computet(kfB, vfB, jt0 + 1);
    } else if (nt >= 3) {
        loadt(kfA, vfA, 2);          // prefetch tile 2 while tile 1 computes
        computet(kfB, vfB, jt0 + 1);
        computet(kfA, vfA, jt0 + 2);
    }

    // ---- write partial (O bf16, s) ----
    const int slot = (bn * 8 + it) * 6 + cl;
    unsigned short* Op = Opart + (size_t)slot * 4096;
#pragma unroll
    for (int f = 0; f < 4; ++f)
#pragma unroll
        for (int r = 0; r < 4; ++r)
            Op[(rowl + r) * 64 + lane15 + 16 * f] = f2bf(oacc[f][r]);
    if (lane15 == 0) {
        float* msp = ms + (size_t)slot * 64;
#pragma unroll
        for (int r = 0; r < 4; ++r) msp[rowl + r] = srowv[r];
    }
}

// ---------------------------------------------------------------------------
// Split-j merge: block = (head, i-tile); sums <=6 partials per row.
// ---------------------------------------------------------------------------
__global__ __launch_bounds__(256)
void attn_merge(const unsigned short* __restrict__ Opart, const float* __restrict__ ms,
                unsigned short* __restrict__ avec) {
    const int blk = blockIdx.x;          // 512
    const int bn = blk & 63, it = blk >> 6;
    const int n = bn & 15, b = bn >> 4;
    const int nctt[8] = {3, 4, 4, 4, 5, 5, 5, 6};
    const int k = nctt[it];
    const int tid = threadIdx.x;
    const int r = tid >> 2, cq = (tid & 3) * 16;
    const int base_slot = (bn * 8 + it) * 6;

    float S = 0.f;
    for (int c = 0; c < k; ++c) S += ms[(size_t)(base_slot + c) * 64 + r];

    float acc[16];
#pragma unroll
    for (int j = 0; j < 16; ++j) acc[j] = 0.f;
    for (int c = 0; c < k; ++c) {
        const bf16x8* op = (const bf16x8*)(Opart + (size_t)(base_slot + c) * 4096 + r * 64 + cq);
        bf16x8 v0 = op[0], v1 = op[1];
#pragma unroll
        for (int j = 0; j < 8; ++j) {
            acc[j]     += bf2f((unsigned short)v0[j]);
            acc[8 + j] += bf2f((unsigned short)v1[j]);
        }
    }
    float inv = 1.0f / S;
    int t = (it * 64 + r) * 4 + b;
    unsigned short* dst = avec + (size_t)t * DM + n * 64 + cq;
#pragma unroll
    for (int j = 0; j < 16; ++j) dst[j] = f2bf(acc[j] * inv);
}

// ---------------------------------------------------------------------------
// LayerNorm: h = LN(hin + res) * g + b ; emits f32 h and bf16 h (dst hbf)
// ---------------------------------------------------------------------------
__global__ __launch_bounds__(256)
void ln_kernel(const float* __restrict__ hin, const float* __restrict__ res,
               const float* __restrict__ g, const float* __restrict__ bb,
               float* __restrict__ hout, unsigned short* __restrict__ hbf) {
    __shared__ float ls[8];
    const int t = blockIdx.x, tid = threadIdx.x;
    float4 x = ((const float4*)(hin + (size_t)t * DM))[tid];
    float4 rr = ((const float4*)(res + (size_t)t * DM))[tid];
    float v0 = x.x + rr.x, v1 = x.y + rr.y, v2 = x.z + rr.z, v3 = x.w + rr.w;
    float s = v0 + v1 + v2 + v3;
    float sq = v0 * v0 + v1 * v1 + v2 * v2 + v3 * v3;
#pragma unroll
    for (int off = 1; off < 64; off <<= 1) {
        s += __shfl_xor(s, off);
        sq += __shfl_xor(sq, off);
    }
    const int w = tid >> 6;
    if ((tid & 63) == 0) { ls[w] = s; ls[4 + w] = sq; }
    __syncthreads();
    s = ls[0] + ls[1] + ls[2] + ls[3];
    sq = ls[4] + ls[5] + ls[6] + ls[7];
    float mu = s * (1.f / 1024.f);
    float var = sq * (1.f / 1024.f) - mu * mu;
    float rstd = rsqrtf(var + 1e-5f);
    float y[4] = {v0, v1, v2, v3};
    float4 of;
    uint2 ob;
    float* op = &of.x;
#pragma unroll
    for (int j = 0; j < 4; ++j) {
        int d = tid * 4 + j;
        op[j] = (y[j] - mu) * rstd * g[d] + bb[d];
    }
    ob.x = (unsigned)f2bf(of.x) | ((unsigned)f2bf(of.y) << 16);
    ob.y = (unsigned)f2bf(of.z) | ((unsigned)f2bf(of.w) << 16);
    ((float4*)(hout + (size_t)t * DM))[tid] = of;
    ((uint2*)(hbf + (size_t)t * DM))[tid] = ob;
}

__global__ __launch_bounds__(256)
void out_kernel(const float* __restrict__ h, float* __restrict__ out) {
    const int t = blockIdx.x, tid = threadIdx.x;
    const int i = t >> 2, b = t & 3;
    ((float4*)(out + ((size_t)b * QLEN + i) * DM))[tid] =
        ((const float4*)(h + (size_t)t * DM))[tid];
}

// ---------------------------------------------------------------------------
extern "C" void kernel_launch(void* const* d_in, const int* in_sizes, int n_in,
                              void* d_out, int out_size, void* d_ws, size_t ws_size,
                              hipStream_t stream) {
    const int* ids = (const int*)d_in[0];
    const float* mems = (const float*)d_in[1];
    const float* embp[4] = {nullptr, nullptr, nullptr, nullptr};
    const float* projp[4] = {nullptr, nullptr, nullptr, nullptr};
    const long long esz[4] = {20000LL * 1024, 20000LL * 256, 160000LL * 64, 67735LL * 16};
    const long long psz[4] = {1024LL * 1024, 256LL * 1024, 64LL * 1024, 16LL * 1024};
    for (int idx = 2; idx <= 9 && idx < n_in; ++idx) {
        long long s = in_sizes[idx];
        for (int c = 0; c < 4; ++c) {
            if (s == esz[c]) embp[c] = (const float*)d_in[idx];
            else if (s == psz[c]) projp[c] = (const float*)d_in[idx];
        }
    }
    const float* qkvW = (const float*)d_in[10];
    const float* rW   = (const float*)d_in[11];
    const float* oW   = (const float*)d_in[12];
    const float* rwb  = (const float*)d_in[13];
    const float* rrb  = (const float*)d_in[14];
    const float* ln1g = (const float*)d_in[15];
    const float* ln1b = (const float*)d_in[16];
    const float* ffw1 = (const float*)d_in[17];
    const float* ffb1 = (const float*)d_in[18];
    const float* ffw2 = (const float*)d_in[19];
    const float* ffb2 = (const float*)d_in[20];
    const float* ln2g = (const float*)d_in[21];
    const float* ln2b = (const float*)d_in[22];

    size_t off = 0;
    char* base = (char*)d_ws;
    auto alloc = [&](size_t bytes) -> char* {
        char* p = base + off;
        off = (off + bytes + 255) & ~(size_t)255;
        return p;
    };
    unsigned short* qkvT  = (unsigned short*)alloc(3072ull * 1024 * 2);
    unsigned short* rT    = (unsigned short*)alloc(1024ull * 1024 * 2);
    unsigned short* oT    = (unsigned short*)alloc(1024ull * 1024 * 2);
    unsigned short* w1T   = (unsigned short*)alloc(4096ull * 1024 * 2);
    unsigned short* w2T   = (unsigned short*)alloc(1024ull * 4096 * 2);
    unsigned short* embA  = (unsigned short*)alloc(2048ull * EK * 2);
    unsigned short* embBT = (unsigned short*)alloc(1024ull * EK * 2);
    float* h              = (float*)alloc(2048ull * 1024 * 4);
    unsigned short* hbf   = (unsigned short*)alloc(2048ull * 1024 * 2);
    unsigned short* catb  = (unsigned short*)alloc(4096ull * 1024 * 2);
    unsigned short* posb  = (unsigned short*)alloc(1024ull * 1024 * 2);
    unsigned short* Qw    = (unsigned short*)alloc(4ull * 16 * 512 * 64 * 2);
    unsigned short* Qr    = (unsigned short*)alloc(4ull * 16 * 512 * 64 * 2);
    unsigned short* Kb    = (unsigned short*)alloc(4ull * 16 * 1024 * 64 * 2);
    unsigned short* VTb   = (unsigned short*)alloc(4ull * 16 * 1024 * 64 * 2);
    unsigned short* Rb    = (unsigned short*)alloc(16ull * 1024 * 64 * 2);
    unsigned short* avec  = (unsigned short*)alloc(2048ull * 1024 * 2);
    float* resid          = (float*)alloc(2048ull * 1024 * 4);
    unsigned short* ff1b  = (unsigned short*)alloc(2048ull * 4096 * 2);
    unsigned short* Opart = (unsigned short*)alloc(3072ull * 4096 * 2);   // 24 MB
    float* msbuf          = (float*)alloc(3072ull * 64 * 4);              // 0.75 MB
    unsigned short* BDs   = (unsigned short*)alloc(64ull * 512 * BDLD * 2); // 75.5 MB
    (void)ws_size; (void)out_size;

    unsigned short* catbHi = catb + 2048ull * 1024;   // h-half of cat (bf16)

    // ---- embeddings (gather + GEMM) + positional table ----
    emb_gather<<<(2048 * 176 + 255) / 256, 256, 0, stream>>>(
        ids, embp[0], embp[1], embp[2], embp[3], embA);
    transpose_pad<<<dim3(32, 32), 256, 0, stream>>>(projp[0], embBT, 1024, 1024, EK, 0);
    transpose_pad<<<dim3(32, 8),  256, 0, stream>>>(projp[1], embBT, 256,  1024, EK, 1024);
    transpose_pad<<<dim3(32, 2),  256, 0, stream>>>(projp[2], embBT, 64,   1024, EK, 1280);
    transpose_pad<<<dim3(32, 2),  256, 0, stream>>>(projp[3], embBT, 16,   1024, EK, 1344);
    pos_kernel<<<1024, 256, 0, stream>>>(posb);
    // emb GEMM writes h (f32) AND catb high half (bf16) for layer 0
    gemm_bt<5, 128><<<(2048 / 128) * (1024 / 128), 256, 0, stream>>>(
        embA, embBT, h, catbHi, nullptr, nullptr, nullptr, nullptr, nullptr, nullptr, nullptr,
        2048, 1024, EK);

    for (int l = 0; l < N_LAYER; ++l) {
        const float* qkvWl = qkvW + (size_t)l * 1024 * 3072;
        const float* rWl   = rW + (size_t)l * 1024 * 1024;
        const float* oWl   = oW + (size_t)l * 1024 * 1024;
        const float* w1l   = ffw1 + (size_t)l * 1024 * 4096;
        const float* w2l   = ffw2 + (size_t)l * 4096 * 1024;

        transpose_all<<<3328, 256, 0, stream>>>(qkvWl, rWl, oWl, w1l, w2l,
                                                qkvT, rT, oT, w1T, w2T);

        mems_cat<<<2048, 256, 0, stream>>>(mems + (size_t)l * 2048 * 1024, catb);

        gemm_bt<3, 128><<<(4096 / 128) * (3072 / 128), 256, 0, stream>>>(
            catb, qkvT, nullptr, nullptr, nullptr,
            rwb + l * 1024, rrb + l * 1024, Qw, Qr, Kb, VTb, 4096, 3072, 1024);

        gemm_bt<4, 64><<<(1024 / 128) * (1024 / 64), 256, 0, stream>>>(
            posb, rT, nullptr, nullptr, nullptr,
            nullptr, nullptr, nullptr, nullptr, Rb, nullptr, 1024, 1024, 1024);

        bd_gemm<<<64 * 32, 256, 0, stream>>>(Qr, Rb, BDs);

        attn_part<<<64 * 144, 64, 0, stream>>>(Qw, Kb, VTb, BDs, Opart, msbuf);
        attn_merge<<<512, 256, 0, stream>>>(Opart, msbuf, avec);

        gemm_bt<0, 64><<<(2048 / 128) * (1024 / 64), 256, 0, stream>>>(
            avec, oT, resid, nullptr, nullptr, nullptr, nullptr, nullptr, nullptr, nullptr, nullptr,
            2048, 1024, 1024);
        ln_kernel<<<2048, 256, 0, stream>>>(h, resid, ln1g + l * 1024, ln1b + l * 1024, h, hbf);

        gemm_bt<1, 128><<<(2048 / 128) * (4096 / 128), 256, 0, stream>>>(
            hbf, w1T, nullptr, ff1b, ffb1 + l * 4096, nullptr, nullptr, nullptr, nullptr, nullptr, nullptr,
            2048, 4096, 1024);
        gemm_bt<2, 64><<<(2048 / 128) * (1024 / 64), 256, 0, stream>>>(
            ff1b, w2T, resid, nullptr, ffb2 + l * 1024, nullptr, nullptr, nullptr, nullptr, nullptr, nullptr,
            2048, 1024, 4096);
        // ln2 writes bf16 directly into next layer's cat high half (l<3)
        ln_kernel<<<2048, 256, 0, stream>>>(h, resid, ln2g + l * 1024, ln2b + l * 1024, h,
                                            (l < 3) ? catbHi : hbf);
    }

    out_kernel<<<2048, 256, 0, stream>>>(h, (float*)d_out);
}

// Round 14
// 1077.953 us; speedup vs baseline: 1.0592x; 1.0592x over previous
//
#include <hip/hip_runtime.h>

typedef __attribute__((ext_vector_type(8))) short bf16x8;
typedef __attribute__((ext_vector_type(4))) float f32x4;

#define N_LAYER 4
#define QLEN 512
#define MLEN 512
#define KLEN 1024
#define BSZ 4
#define DM 1024
#define NH 16
#define DH 64
#define DINNER 4096
#define EK 1408
#define BDLD 1152  // BDs row stride (1024 + 128 pad; pad cols never written, always masked)

__device__ __forceinline__ unsigned short f2bf(float x) {
    unsigned u = __float_as_uint(x);
    u += 0x7fffu + ((u >> 16) & 1u);
    return (unsigned short)(u >> 16);
}
__device__ __forceinline__ float bf2f(unsigned short v) {
    return __uint_as_float(((unsigned)v) << 16);
}

__device__ __forceinline__ void gload16(const unsigned short* g, unsigned short* l) {
    __builtin_amdgcn_global_load_lds(
        (const __attribute__((address_space(1))) unsigned int*)g,
        (__attribute__((address_space(3))) unsigned int*)l, 16, 0, 0);
}

// swizzled b128 LDS read for 128B-row-stride bf16 tiles: byte ^= (row&7)<<4
__device__ __forceinline__ bf16x8 lds_read8_sw(const unsigned short* base, int row, int cb) {
    return *(const bf16x8*)((const char*)base + row * 128 + (cb ^ ((row & 7) << 4)));
}

// ---------------------------------------------------------------------------
// All 5 per-layer weight transposes in ONE launch. 64x64 tiles.
// ---------------------------------------------------------------------------
__global__ __launch_bounds__(256)
void transpose_all(const float* __restrict__ qkvWl, const float* __restrict__ rWl,
                   const float* __restrict__ oWl, const float* __restrict__ w1l,
                   const float* __restrict__ w2l,
                   unsigned short* __restrict__ qkvT, unsigned short* __restrict__ rT,
                   unsigned short* __restrict__ oT, unsigned short* __restrict__ w1T,
                   unsigned short* __restrict__ w2T) {
    __shared__ float tile[64][65];
    int id = blockIdx.x;
    const float* W; unsigned short* D; int K, N, bx, by;
    if (id < 768)       { W = qkvWl; D = qkvT; K = 1024; N = 3072; bx = id % 48; by = id / 48; }
    else if (id < 1024) { id -= 768;  W = rWl;  D = rT;  K = 1024; N = 1024; bx = id & 15; by = id >> 4; }
    else if (id < 1280) { id -= 1024; W = oWl;  D = oT;  K = 1024; N = 1024; bx = id & 15; by = id >> 4; }
    else if (id < 2304) { id -= 1280; W = w1l;  D = w1T; K = 1024; N = 4096; bx = id & 63; by = id >> 6; }
    else                { id -= 2304; W = w2l;  D = w2T; K = 4096; N = 1024; bx = id & 15; by = id >> 4; }
    const int tid = threadIdx.x;
#pragma unroll
    for (int s = 0; s < 4; ++s) {
        int idx = s * 256 + tid;
        int kr = idx >> 4, c4 = (idx & 15) * 4;
        float4 v = *(const float4*)(W + (size_t)(by * 64 + kr) * N + bx * 64 + c4);
        tile[kr][c4] = v.x; tile[kr][c4 + 1] = v.y;
        tile[kr][c4 + 2] = v.z; tile[kr][c4 + 3] = v.w;
    }
    __syncthreads();
#pragma unroll
    for (int s = 0; s < 2; ++s) {
        int idx = s * 256 + tid;
        int nl = idx >> 3, k8 = (idx & 7) * 8;
        unsigned short tmp[8];
#pragma unroll
        for (int j = 0; j < 8; ++j) tmp[j] = f2bf(tile[k8 + j][nl]);
        *(uint4*)(D + (size_t)(bx * 64 + nl) * K + by * 64 + k8) = *(uint4*)tmp;
    }
}

// Transpose with zero-padding beyond K rows, into a slice of a wider dst row.
__global__ __launch_bounds__(256)
void transpose_pad(const float* __restrict__ W, unsigned short* __restrict__ dst,
                   int K, int N, int dstLD, int dstOff) {
    __shared__ float tile[32][33];
    const int tx = threadIdx.x & 31, ty = threadIdx.x >> 5;
    const int bx = blockIdx.x, by = blockIdx.y;
#pragma unroll
    for (int i = 0; i < 4; ++i) {
        int k = by * 32 + ty + i * 8;
        tile[ty + i * 8][tx] = (k < K) ? W[(size_t)k * N + bx * 32 + tx] : 0.f;
    }
    __syncthreads();
#pragma unroll
    for (int i = 0; i < 4; ++i) {
        int n = bx * 32 + ty + i * 8;
        int k = by * 32 + tx;
        dst[(size_t)n * dstLD + dstOff + k] = f2bf(tile[tx][ty + i * 8]);
    }
}

// ---------------------------------------------------------------------------
// Adaptive-embedding gather: embA[t][0:1408) = masked cluster row * 32, bf16
// ---------------------------------------------------------------------------
__global__ __launch_bounds__(256)
void emb_gather(const int* __restrict__ ids,
                const float* __restrict__ e0, const float* __restrict__ e1,
                const float* __restrict__ e2, const float* __restrict__ e3,
                unsigned short* __restrict__ embA) {
    const int chunk = blockIdx.x * 256 + threadIdx.x;
    if (chunk >= 2048 * 176) return;
    const int t = chunk / 176;
    const int e8 = (chunk - t * 176) * 8;
    const int i = t >> 2, b = t & 3;
    const int id = ids[b * QLEN + i];
    const float* src = nullptr;
    if (e8 < 1024) {
        if (id < 20000) src = e0 + (size_t)id * 1024 + e8;
    } else if (e8 < 1280) {
        if (id >= 20000 && id < 40000) src = e1 + (size_t)(id - 20000) * 256 + (e8 - 1024);
    } else if (e8 < 1344) {
        if (id >= 40000 && id < 200000) src = e2 + (size_t)(id - 40000) * 64 + (e8 - 1280);
    } else if (e8 < 1360) {
        if (id >= 200000) src = e3 + (size_t)(id - 200000) * 16 + (e8 - 1344);
    }
    uint4 o = {0u, 0u, 0u, 0u};
    if (src) {
        float4 v0 = *(const float4*)src;
        float4 v1 = *(const float4*)(src + 4);
        o.x = (unsigned)f2bf(v0.x * 32.f) | ((unsigned)f2bf(v0.y * 32.f) << 16);
        o.y = (unsigned)f2bf(v0.z * 32.f) | ((unsigned)f2bf(v0.w * 32.f) << 16);
        o.z = (unsigned)f2bf(v1.x * 32.f) | ((unsigned)f2bf(v1.y * 32.f) << 16);
        o.w = (unsigned)f2bf(v1.z * 32.f) | ((unsigned)f2bf(v1.w * 32.f) << 16);
    }
    *(uint4*)(embA + (size_t)t * EK + e8) = o;
}

// ---------------------------------------------------------------------------
// Generic GEMM (BK=64 dbuf, T2 swizzle, XCD swizzle).
// MODE 0: f32. 1: bf16(relu(+bias)). 2: f32+bias. 5: f32 + bf16 dual.
// ---------------------------------------------------------------------------
template <int MODE, int BN>
__global__ __launch_bounds__(256)
void gemm_bt(const unsigned short* __restrict__ A, const unsigned short* __restrict__ BT,
             float* __restrict__ C, unsigned short* __restrict__ Cbf,
             const float* __restrict__ bias, int M, int N, int K) {
    constexpr int NF = BN / 32;
    __shared__ unsigned short lA[2][128 * 64];
    __shared__ unsigned short lB[2][BN * 64];
    const int tid = threadIdx.x;
    const int w = tid >> 6, l = tid & 63;
    const int lane15 = l & 15, lh = l >> 4;
    const int nwg = gridDim.x;
    const int cpx = nwg >> 3;
    const int swz = (blockIdx.x & 7) * cpx + (blockIdx.x >> 3);
    const int nbn = N / BN;
    const int bm = swz / nbn, bn = swz % nbn;
    const int wr = (w >> 1) * 64, wc = (w & 1) * (BN / 2);

    f32x4 acc[4][NF] = {};

    const unsigned short* gA = A + (size_t)(bm * 128) * K;
    const unsigned short* gB = BT + (size_t)(bn * BN) * K;

    auto stage = [&](int buf, int k0) {
#pragma unroll
        for (int s = 0; s < 4; ++s) {
            int g = tid + s * 256, row = g >> 3;
            gload16(gA + (size_t)row * K + k0 + ((g & 7) ^ (row & 7)) * 8,
                    lA[buf] + g * 8);
        }
#pragma unroll
        for (int s = 0; s < BN / 32; ++s) {
            int g = tid + s * 256, row = g >> 3;
            gload16(gB + (size_t)row * K + k0 + ((g & 7) ^ (row & 7)) * 8,
                    lB[buf] + g * 8);
        }
    };

    stage(0, 0);
    __syncthreads();
    int cur = 0;
    for (int k0 = 0; k0 < K; k0 += 64) {
        if (k0 + 64 < K) stage(cur ^ 1, k0 + 64);
        const unsigned short* cA = lA[cur];
        const unsigned short* cB = lB[cur];
#pragma unroll
        for (int kk = 0; kk < 2; ++kk) {
            bf16x8 af[4], bfr[NF];
#pragma unroll
            for (int f = 0; f < 4; ++f)
                af[f] = lds_read8_sw(cA, wr + f * 16 + lane15, kk * 64 + lh * 16);
#pragma unroll
            for (int f = 0; f < NF; ++f)
                bfr[f] = lds_read8_sw(cB, wc + f * 16 + lane15, kk * 64 + lh * 16);
#pragma unroll
            for (int mi = 0; mi < 4; ++mi)
#pragma unroll
                for (int ni = 0; ni < NF; ++ni)
                    acc[mi][ni] = __builtin_amdgcn_mfma_f32_16x16x32_bf16(
                        af[mi], bfr[ni], acc[mi][ni], 0, 0, 0);
        }
        __syncthreads();
        cur ^= 1;
    }

#pragma unroll
    for (int mi = 0; mi < 4; ++mi) {
        int rowb = bm * 128 + wr + mi * 16 + lh * 4;
#pragma unroll
        for (int ni = 0; ni < NF; ++ni) {
            int col = bn * BN + wc + ni * 16 + lane15;
#pragma unroll
            for (int r = 0; r < 4; ++r) {
                float x = acc[mi][ni][r];
                if (MODE == 0) {
                    C[(size_t)(rowb + r) * N + col] = x;
                } else if (MODE == 1) {
                    x += bias[col];
                    Cbf[(size_t)(rowb + r) * N + col] = f2bf(x > 0.f ? x : 0.f);
                } else if (MODE == 2) {
                    C[(size_t)(rowb + r) * N + col] = x + bias[col];
                } else { // MODE 5
                    C[(size_t)(rowb + r) * N + col] = x;
                    Cbf[(size_t)(rowb + r) * N + col] = f2bf(x);
                }
            }
        }
    }
}

// ---------------------------------------------------------------------------
// Combined QKV(KV) + QKV(Q, live rows only) + r_head_k GEMM, one launch.
// Grid 704: [0,512) KV (4096x2048), [512,640) Q (2048x1024 live rows),
// [640,704) RK (1024x1024). Uniform K=1024 staging; part-decoded epilogue.
// Q-part folds +r_w_bias/+r_r_bias and the 1/8 scale (Qw only).
// ---------------------------------------------------------------------------
__global__ __launch_bounds__(256)
void qkv_rk_gemm(const unsigned short* __restrict__ catb, const unsigned short* __restrict__ posb,
                 const unsigned short* __restrict__ qkvT, const unsigned short* __restrict__ rT,
                 const float* __restrict__ rwb, const float* __restrict__ rrb,
                 unsigned short* __restrict__ Qw, unsigned short* __restrict__ Qr,
                 unsigned short* __restrict__ Kb, unsigned short* __restrict__ VTb,
                 unsigned short* __restrict__ Rb) {
    __shared__ unsigned short lA[2][128 * 64];
    __shared__ unsigned short lB[2][128 * 64];
    const int tid = threadIdx.x;
    const int w = tid >> 6, l = tid & 63;
    const int lane15 = l & 15, lh = l >> 4;
    const int cpx = gridDim.x >> 3;   // 88
    const int swz = (blockIdx.x & 7) * cpx + (blockIdx.x >> 3);
    const int wr = (w >> 1) * 64, wc = (w & 1) * 64;

    const unsigned short* gA;
    const unsigned short* gB;
    int part, bm, bn;
    if (swz < 512)      { part = 0; bm = swz >> 4; bn = swz & 15;
                          gA = catb + (size_t)(bm * 128) * 1024;
                          gB = qkvT + (size_t)(1024 + bn * 128) * 1024; }
    else if (swz < 640) { part = 1; int q = swz - 512; bm = q >> 3; bn = q & 7;
                          gA = catb + (size_t)(2048 + bm * 128) * 1024;
                          gB = qkvT + (size_t)(bn * 128) * 1024; }
    else                { part = 2; int q = swz - 640; bm = q >> 3; bn = q & 7;
                          gA = posb + (size_t)(bm * 128) * 1024;
                          gB = rT + (size_t)(bn * 128) * 1024; }

    f32x4 acc[4][4] = {};
    auto stage = [&](int buf, int k0) {
#pragma unroll
        for (int s = 0; s < 4; ++s) {
            int g = tid + s * 256, row = g >> 3;
            gload16(gA + (size_t)row * 1024 + k0 + ((g & 7) ^ (row & 7)) * 8, lA[buf] + g * 8);
            gload16(gB + (size_t)row * 1024 + k0 + ((g & 7) ^ (row & 7)) * 8, lB[buf] + g * 8);
        }
    };
    stage(0, 0);
    __syncthreads();
    int cur = 0;
    for (int k0 = 0; k0 < 1024; k0 += 64) {
        if (k0 + 64 < 1024) stage(cur ^ 1, k0 + 64);
        const unsigned short* cA = lA[cur];
        const unsigned short* cB = lB[cur];
#pragma unroll
        for (int kk = 0; kk < 2; ++kk) {
            bf16x8 af[4], bfr[4];
#pragma unroll
            for (int f = 0; f < 4; ++f) {
                af[f]  = lds_read8_sw(cA, wr + f * 16 + lane15, kk * 64 + lh * 16);
                bfr[f] = lds_read8_sw(cB, wc + f * 16 + lane15, kk * 64 + lh * 16);
            }
#pragma unroll
            for (int mi = 0; mi < 4; ++mi)
#pragma unroll
                for (int ni = 0; ni < 4; ++ni)
                    acc[mi][ni] = __builtin_amdgcn_mfma_f32_16x16x32_bf16(
                        af[mi], bfr[ni], acc[mi][ni], 0, 0, 0);
        }
        __syncthreads();
        cur ^= 1;
    }

#pragma unroll
    for (int mi = 0; mi < 4; ++mi) {
        int rowb = bm * 128 + wr + mi * 16 + lh * 4;
#pragma unroll
        for (int ni = 0; ni < 4; ++ni) {
            int col = bn * 128 + wc + ni * 16 + lane15;
#pragma unroll
            for (int r = 0; r < 4; ++r) {
                float x = acc[mi][ni][r];
                if (part == 0) {           // KV scatter (all 4096 rows)
                    int j = rowb >> 2, bb_ = r;
                    if (col < 1024) {
                        int n = col >> 6, d = col & 63;
                        Kb[((size_t)(bb_ * NH + n) * KLEN + j) * DH + d] = f2bf(x);
                    } else {
                        int c2 = col - 1024, n = c2 >> 6, d = c2 & 63;
                        VTb[((size_t)(bb_ * NH + n) * DH + d) * KLEN + j] = f2bf(x);
                    }
                } else if (part == 1) {    // Q scatter (live rows), +biases, x1/8 into Qw
                    int i = rowb >> 2, bb_ = r;
                    int n = col >> 6, d = col & 63;
                    size_t o = ((size_t)(bb_ * NH + n) * QLEN + i) * DH + d;
                    Qw[o] = f2bf((x + rwb[col]) * 0.125f);
                    Qr[o] = f2bf(x + rrb[col]);
                } else {                   // RK scatter
                    int j = rowb + r;
                    int n = col >> 6, d = col & 63;
                    Rb[((size_t)n * KLEN + j) * DH + d] = f2bf(x);
                }
            }
        }
    }
}

// ---------------------------------------------------------------------------
// Batched BD GEMM (band-only): BDs[bn][i][k] = (Qr[i].Rb[k]) * 0.125
// Only the 26 of 32 k-tiles per head intersecting k in [384-128*mi, 1023].
// ---------------------------------------------------------------------------
__global__ __launch_bounds__(256)
void bd_gemm(const unsigned short* __restrict__ Qr, const unsigned short* __restrict__ Rb,
             unsigned short* __restrict__ BDs) {
    __shared__ unsigned short lA[128 * 64];
    __shared__ unsigned short lB[128 * 64];
    const int tid = threadIdx.x;
    const int w = tid >> 6, l = tid & 63;
    const int lane15 = l & 15, lh = l >> 4;
    const int blk = blockIdx.x;
    const int bn = blk & 63;          // head-local XCD
    const int tile = blk >> 6;        // 0..25
    const int bd_mi[26] = {0,0,0,0,0, 1,1,1,1,1,1, 2,2,2,2,2,2,2, 3,3,3,3,3,3,3,3};
    const int bd_nj[26] = {3,4,5,6,7, 2,3,4,5,6,7, 1,2,3,4,5,6,7, 0,1,2,3,4,5,6,7};
    const int mi_ = bd_mi[tile], nj = bd_nj[tile];
    const int n = bn & 15;
    const int wr = (w >> 1) * 64, wc = (w & 1) * 64;

    const unsigned short* gA = Qr + (size_t)bn * QLEN * DH + (size_t)(mi_ * 128) * 64;
    const unsigned short* gB = Rb + (size_t)n * KLEN * DH + (size_t)(nj * 128) * 64;
#pragma unroll
    for (int s = 0; s < 4; ++s) {
        int g = tid + s * 256, row = g >> 3;
        gload16(gA + (size_t)row * 64 + ((g & 7) ^ (row & 7)) * 8, lA + g * 8);
        gload16(gB + (size_t)row * 64 + ((g & 7) ^ (row & 7)) * 8, lB + g * 8);
    }
    __syncthreads();
    f32x4 acc[4][4] = {};
#pragma unroll
    for (int kk = 0; kk < 2; ++kk) {
        bf16x8 af[4], bfr[4];
#pragma unroll
        for (int f = 0; f < 4; ++f) {
            af[f]  = lds_read8_sw(lA, wr + f * 16 + lane15, kk * 64 + lh * 16);
            bfr[f] = lds_read8_sw(lB, wc + f * 16 + lane15, kk * 64 + lh * 16);
        }
#pragma unroll
        for (int mi = 0; mi < 4; ++mi)
#pragma unroll
            for (int ni = 0; ni < 4; ++ni)
                acc[mi][ni] = __builtin_amdgcn_mfma_f32_16x16x32_bf16(
                    af[mi], bfr[ni], acc[mi][ni], 0, 0, 0);
    }
    unsigned short* out = BDs + (size_t)bn * 512 * BDLD;
#pragma unroll
    for (int mi = 0; mi < 4; ++mi) {
        int rowb = mi_ * 128 + wr + mi * 16 + lh * 4;
#pragma unroll
        for (int ni = 0; ni < 4; ++ni) {
            int col = nj * 128 + wc + ni * 16 + lane15;
#pragma unroll
            for (int r = 0; r < 4; ++r)
                out[(size_t)(rowb + r) * BDLD + col] = f2bf(acc[mi][ni][r] * 0.125f);
        }
    }
}

// ---------------------------------------------------------------------------
// Positional embedding table (1024 x 1024), bf16
// ---------------------------------------------------------------------------
__global__ __launch_bounds__(256)
void pos_kernel(unsigned short* __restrict__ posbf) {
    const int p = blockIdx.x, tid = threadIdx.x;
    const float ps = (float)(KLEN - 1 - p);
    const float c = -2.0f * 9.210340371976184f / 1024.0f; // -2*ln(10000)/D
#pragma unroll
    for (int j4 = 0; j4 < 4; ++j4) {
        int j = tid + j4 * 256;
        int m = (j < 512) ? j : j - 512;
        float freq = __expf((float)m * c);
        float ang = ps * freq;
        float v = (j < 512) ? sinf(ang) : cosf(ang);
        posbf[(size_t)p * DM + j] = f2bf(v);
    }
}

// ---------------------------------------------------------------------------
// mems[l] rows -> bf16 catb rows [0,2048)  (h-half written by ln2/emb gemm)
// ---------------------------------------------------------------------------
__global__ __launch_bounds__(256)
void mems_cat(const float* __restrict__ mem_l, unsigned short* __restrict__ catbf) {
    const int t = blockIdx.x, tid = threadIdx.x;
    float4 v = ((const float4*)(mem_l + (size_t)t * DM))[tid];
    uint2 o;
    o.x = (unsigned)f2bf(v.x) | ((unsigned)f2bf(v.y) << 16);
    o.y = (unsigned)f2bf(v.z) | ((unsigned)f2bf(v.w) << 16);
    ((uint2*)(catbf + (size_t)t * DM))[tid] = o;
}

// ---------------------------------------------------------------------------
// Split-j-chunk rel-attention, stage 1 (R11 structure: 1-deep rolling loop,
// BD precomputed, constant-shift softmax, ones-MFMA row sums).
// ---------------------------------------------------------------------------
__global__ __launch_bounds__(64)
void attn_part(const unsigned short* __restrict__ Qw,
               const unsigned short* __restrict__ Kb, const unsigned short* __restrict__ VTb,
               const unsigned short* __restrict__ BDs,
               unsigned short* __restrict__ Opart, float* __restrict__ ms) {
    __shared__ unsigned short lP[16 * 64];

    const int l = threadIdx.x;
    const int lane15 = l & 15, lh = l >> 4;
    const int blk = blockIdx.x;
    const int bn = blk & 63;          // head-local XCD
    const int rest = blk >> 6;        // 0..143
    const int rg = rest & 3;          // 16-row group within the 64-row i-tile
    const int c = rest >> 2;          // 0..35 chunk unit

    const int offt[8] = {0, 3, 7, 11, 15, 20, 25, 30};
    const int nctt[8] = {3, 4, 4, 4, 5, 5, 5, 6};
    int it = 0;
#pragma unroll
    for (int i = 1; i < 8; ++i) if (c >= offt[i]) it = i;
    const int cl = c - offt[it];
    const int nck = nctt[it];
    const int ntiles = it + 9;
    const int jt0 = (cl * ntiles) / nck;
    const int jt1 = ((cl + 1) * ntiles) / nck;
    const int i0 = it * 64;
    const int rowl = rg * 16 + lh * 4;

    bf16x8 qw[2];
    {
        size_t qb = ((size_t)bn * QLEN + i0 + rg * 16 + lane15) * DH + lh * 8;
        qw[0] = *(const bf16x8*)(Qw + qb);
        qw[1] = *(const bf16x8*)(Qw + qb + 32);
    }
    bf16x8 onesb;
#pragma unroll
    for (int j = 0; j < 8; ++j) onesb[j] = (short)0x3F80;   // bf16 1.0

    const unsigned short* kp = Kb + (size_t)bn * KLEN * DH + (size_t)(jt0 * 64 + lane15) * DH + lh * 8;
    const unsigned short* vp = VTb + (size_t)bn * DH * KLEN + (size_t)lane15 * KLEN + jt0 * 64 + lh * 8;
    const unsigned short* bdp[4];
#pragma unroll
    for (int r = 0; r < 4; ++r) {
        int row = i0 + rowl + r;                       // absolute i (<= 511)
        bdp[r] = BDs + (size_t)bn * 512 * BDLD + (size_t)row * BDLD
                 + (511 - row) + jt0 * 64 + lane15;    // col k = 511 + j - i
    }

    f32x4 oacc[4] = {};
    f32x4 srowv = {};   // row sums via ones-MFMA

    for (int jt = jt0; jt < jt1; ++jt) {
        // ---- BD gather (16 scalar u16, pre-scaled by 1/8) ----
        float bdv[4][4];
#pragma unroll
        for (int f = 0; f < 4; ++f)
#pragma unroll
            for (int r = 0; r < 4; ++r)
                bdv[f][r] = bf2f(bdp[r][16 * f]);

        // ---- K fragments ----
        bf16x8 kf[2][4];
#pragma unroll
        for (int f = 0; f < 4; ++f) {
            const unsigned short* p = kp + (size_t)(f * 16) * DH;
            kf[0][f] = *(const bf16x8*)p;
            kf[1][f] = *(const bf16x8*)(p + 32);
        }

        f32x4 sac[4] = {};
        __builtin_amdgcn_s_setprio(1);
#pragma unroll
        for (int kk = 0; kk < 2; ++kk)
#pragma unroll
            for (int f = 0; f < 4; ++f)
                sac[f] = __builtin_amdgcn_mfma_f32_16x16x32_bf16(qw[kk], kf[kk][f], sac[f], 0, 0, 0);
        __builtin_amdgcn_s_setprio(0);

        // ---- V loads issued early; exp pass hides their latency ----
        bf16x8 vf[2][4];
#pragma unroll
        for (int kk = 0; kk < 2; ++kk)
#pragma unroll
            for (int f = 0; f < 4; ++f)
                vf[kk][f] = *(const bf16x8*)(vp + (size_t)(f * 16) * KLEN + kk * 32);

        // ---- constant-shift softmax numerator: P = exp(s - 8) ----
        const bool lastTile = (jt == it + 8);
        float pv[4][4];
#pragma unroll
        for (int f = 0; f < 4; ++f) {
            int lj = lane15 + 16 * f;
#pragma unroll
            for (int r = 0; r < 4; ++r) {
                float s = sac[f][r] + bdv[f][r];
                if (lastTile && (lj > rowl + r)) s = -1e30f;
                pv[f][r] = __expf(s - 8.f);
            }
        }

        // P -> bf16 LDS (swizzled), reload as A-fragments
#pragma unroll
        for (int f = 0; f < 4; ++f)
#pragma unroll
            for (int r = 0; r < 4; ++r) {
                int row = lh * 4 + r, cb2 = (lane15 + 16 * f) * 2;
                *(unsigned short*)((char*)lP + row * 128 + (cb2 ^ ((row & 7) << 4))) =
                    f2bf(pv[f][r]);
            }
        bf16x8 pa[2];
        pa[0] = lds_read8_sw(lP, lane15, lh * 16);
        pa[1] = lds_read8_sw(lP, lane15, 64 + lh * 16);

        __builtin_amdgcn_s_setprio(1);
#pragma unroll
        for (int kk = 0; kk < 2; ++kk) {
#pragma unroll
            for (int f = 0; f < 4; ++f)
                oacc[f] = __builtin_amdgcn_mfma_f32_16x16x32_bf16(pa[kk], vf[kk][f], oacc[f], 0, 0, 0);
            srowv = __builtin_amdgcn_mfma_f32_16x16x32_bf16(pa[kk], onesb, srowv, 0, 0, 0);
        }
        __builtin_amdgcn_s_setprio(0);

        kp += 64 * DH;
        vp += 64;
#pragma unroll
        for (int r = 0; r < 4; ++r) bdp[r] += 64;
    }

    // ---- write partial (O bf16, s) ----
    const int slot = (bn * 8 + it) * 6 + cl;
    unsigned short* Op = Opart + (size_t)slot * 4096;
#pragma unroll
    for (int f = 0; f < 4; ++f)
#pragma unroll
        for (int r = 0; r < 4; ++r)
            Op[(rowl + r) * 64 + lane15 + 16 * f] = f2bf(oacc[f][r]);
    if (lane15 == 0) {
        float* msp = ms + (size_t)slot * 64;
#pragma unroll
        for (int r = 0; r < 4; ++r) msp[rowl + r] = srowv[r];
    }
}

// ---------------------------------------------------------------------------
// Split-j merge: block = (head, i-tile); sums <=6 partials per row.
// ---------------------------------------------------------------------------
__global__ __launch_bounds__(256)
void attn_merge(const unsigned short* __restrict__ Opart, const float* __restrict__ ms,
                unsigned short* __restrict__ avec) {
    const int blk = blockIdx.x;          // 512
    const int bn = blk & 63, it = blk >> 6;
    const int n = bn & 15, b = bn >> 4;
    const int nctt[8] = {3, 4, 4, 4, 5, 5, 5, 6};
    const int k = nctt[it];
    const int tid = threadIdx.x;
    const int r = tid >> 2, cq = (tid & 3) * 16;
    const int base_slot = (bn * 8 + it) * 6;

    float S = 0.f;
    for (int c = 0; c < k; ++c) S += ms[(size_t)(base_slot + c) * 64 + r];

    float acc[16];
#pragma unroll
    for (int j = 0; j < 16; ++j) acc[j] = 0.f;
    for (int c = 0; c < k; ++c) {
        const bf16x8* op = (const bf16x8*)(Opart + (size_t)(base_slot + c) * 4096 + r * 64 + cq);
        bf16x8 v0 = op[0], v1 = op[1];
#pragma unroll
        for (int j = 0; j < 8; ++j) {
            acc[j]     += bf2f((unsigned short)v0[j]);
            acc[8 + j] += bf2f((unsigned short)v1[j]);
        }
    }
    float inv = 1.0f / S;
    int t = (it * 64 + r) * 4 + b;
    unsigned short* dst = avec + (size_t)t * DM + n * 64 + cq;
#pragma unroll
    for (int j = 0; j < 16; ++j) dst[j] = f2bf(acc[j] * inv);
}

// ---------------------------------------------------------------------------
// LayerNorm: h = LN(hin + res) * g + b ; emits f32 h and bf16 h (dst hbf)
// ---------------------------------------------------------------------------
__global__ __launch_bounds__(256)
void ln_kernel(const float* __restrict__ hin, const float* __restrict__ res,
               const float* __restrict__ g, const float* __restrict__ bb,
               float* __restrict__ hout, unsigned short* __restrict__ hbf) {
    __shared__ float ls[8];
    const int t = blockIdx.x, tid = threadIdx.x;
    float4 x = ((const float4*)(hin + (size_t)t * DM))[tid];
    float4 rr = ((const float4*)(res + (size_t)t * DM))[tid];
    float v0 = x.x + rr.x, v1 = x.y + rr.y, v2 = x.z + rr.z, v3 = x.w + rr.w;
    float s = v0 + v1 + v2 + v3;
    float sq = v0 * v0 + v1 * v1 + v2 * v2 + v3 * v3;
#pragma unroll
    for (int off = 1; off < 64; off <<= 1) {
        s += __shfl_xor(s, off);
        sq += __shfl_xor(sq, off);
    }
    const int w = tid >> 6;
    if ((tid & 63) == 0) { ls[w] = s; ls[4 + w] = sq; }
    __syncthreads();
    s = ls[0] + ls[1] + ls[2] + ls[3];
    sq = ls[4] + ls[5] + ls[6] + ls[7];
    float mu = s * (1.f / 1024.f);
    float var = sq * (1.f / 1024.f) - mu * mu;
    float rstd = rsqrtf(var + 1e-5f);
    float y[4] = {v0, v1, v2, v3};
    float4 of;
    uint2 ob;
    float* op = &of.x;
#pragma unroll
    for (int j = 0; j < 4; ++j) {
        int d = tid * 4 + j;
        op[j] = (y[j] - mu) * rstd * g[d] + bb[d];
    }
    ob.x = (unsigned)f2bf(of.x) | ((unsigned)f2bf(of.y) << 16);
    ob.y = (unsigned)f2bf(of.z) | ((unsigned)f2bf(of.w) << 16);
    ((float4*)(hout + (size_t)t * DM))[tid] = of;
    ((uint2*)(hbf + (size_t)t * DM))[tid] = ob;
}

__global__ __launch_bounds__(256)
void out_kernel(const float* __restrict__ h, float* __restrict__ out) {
    const int t = blockIdx.x, tid = threadIdx.x;
    const int i = t >> 2, b = t & 3;
    ((float4*)(out + ((size_t)b * QLEN + i) * DM))[tid] =
        ((const float4*)(h + (size_t)t * DM))[tid];
}

// ---------------------------------------------------------------------------
extern "C" void kernel_launch(void* const* d_in, const int* in_sizes, int n_in,
                              void* d_out, int out_size, void* d_ws, size_t ws_size,
                              hipStream_t stream) {
    const int* ids = (const int*)d_in[0];
    const float* mems = (const float*)d_in[1];
    const float* embp[4] = {nullptr, nullptr, nullptr, nullptr};
    const float* projp[4] = {nullptr, nullptr, nullptr, nullptr};
    const long long esz[4] = {20000LL * 1024, 20000LL * 256, 160000LL * 64, 67735LL * 16};
    const long long psz[4] = {1024LL * 1024, 256LL * 1024, 64LL * 1024, 16LL * 1024};
    for (int idx = 2; idx <= 9 && idx < n_in; ++idx) {
        long long s = in_sizes[idx];
        for (int c = 0; c < 4; ++c) {
            if (s == esz[c]) embp[c] = (const float*)d_in[idx];
            else if (s == psz[c]) projp[c] = (const float*)d_in[idx];
        }
    }
    const float* qkvW = (const float*)d_in[10];
    const float* rW   = (const float*)d_in[11];
    const float* oW   = (const float*)d_in[12];
    const float* rwb  = (const float*)d_in[13];
    const float* rrb  = (const float*)d_in[14];
    const float* ln1g = (const float*)d_in[15];
    const float* ln1b = (const float*)d_in[16];
    const float* ffw1 = (const float*)d_in[17];
    const float* ffb1 = (const float*)d_in[18];
    const float* ffw2 = (const float*)d_in[19];
    const float* ffb2 = (const float*)d_in[20];
    const float* ln2g = (const float*)d_in[21];
    const float* ln2b = (const float*)d_in[22];

    size_t off = 0;
    char* base = (char*)d_ws;
    auto alloc = [&](size_t bytes) -> char* {
        char* p = base + off;
        off = (off + bytes + 255) & ~(size_t)255;
        return p;
    };
    unsigned short* qkvT  = (unsigned short*)alloc(3072ull * 1024 * 2);
    unsigned short* rT    = (unsigned short*)alloc(1024ull * 1024 * 2);
    unsigned short* oT    = (unsigned short*)alloc(1024ull * 1024 * 2);
    unsigned short* w1T   = (unsigned short*)alloc(4096ull * 1024 * 2);
    unsigned short* w2T   = (unsigned short*)alloc(1024ull * 4096 * 2);
    unsigned short* embA  = (unsigned short*)alloc(2048ull * EK * 2);
    unsigned short* embBT = (unsigned short*)alloc(1024ull * EK * 2);
    float* h              = (float*)alloc(2048ull * 1024 * 4);
    unsigned short* hbf   = (unsigned short*)alloc(2048ull * 1024 * 2);
    unsigned short* catb  = (unsigned short*)alloc(4096ull * 1024 * 2);
    unsigned short* posb  = (unsigned short*)alloc(1024ull * 1024 * 2);
    unsigned short* Qw    = (unsigned short*)alloc(4ull * 16 * 512 * 64 * 2);
    unsigned short* Qr    = (unsigned short*)alloc(4ull * 16 * 512 * 64 * 2);
    unsigned short* Kb    = (unsigned short*)alloc(4ull * 16 * 1024 * 64 * 2);
    unsigned short* VTb   = (unsigned short*)alloc(4ull * 16 * 1024 * 64 * 2);
    unsigned short* Rb    = (unsigned short*)alloc(16ull * 1024 * 64 * 2);
    unsigned short* avec  = (unsigned short*)alloc(2048ull * 1024 * 2);
    float* resid          = (float*)alloc(2048ull * 1024 * 4);
    unsigned short* ff1b  = (unsigned short*)alloc(2048ull * 4096 * 2);
    unsigned short* Opart = (unsigned short*)alloc(3072ull * 4096 * 2);   // 24 MB
    float* msbuf          = (float*)alloc(3072ull * 64 * 4);              // 0.75 MB
    unsigned short* BDs   = (unsigned short*)alloc(64ull * 512 * BDLD * 2); // 75.5 MB
    (void)ws_size; (void)out_size;

    unsigned short* catbHi = catb + 2048ull * 1024;   // h-half of cat (bf16)

    // ---- embeddings (gather + GEMM) + positional table ----
    emb_gather<<<(2048 * 176 + 255) / 256, 256, 0, stream>>>(
        ids, embp[0], embp[1], embp[2], embp[3], embA);
    transpose_pad<<<dim3(32, 32), 256, 0, stream>>>(projp[0], embBT, 1024, 1024, EK, 0);
    transpose_pad<<<dim3(32, 8),  256, 0, stream>>>(projp[1], embBT, 256,  1024, EK, 1024);
    transpose_pad<<<dim3(32, 2),  256, 0, stream>>>(projp[2], embBT, 64,   1024, EK, 1280);
    transpose_pad<<<dim3(32, 2),  256, 0, stream>>>(projp[3], embBT, 16,   1024, EK, 1344);
    pos_kernel<<<1024, 256, 0, stream>>>(posb);
    // emb GEMM writes h (f32) AND catb high half (bf16) for layer 0
    gemm_bt<5, 128><<<(2048 / 128) * (1024 / 128), 256, 0, stream>>>(
        embA, embBT, h, catbHi, nullptr, 2048, 1024, EK);

    for (int l = 0; l < N_LAYER; ++l) {
        const float* qkvWl = qkvW + (size_t)l * 1024 * 3072;
        const float* rWl   = rW + (size_t)l * 1024 * 1024;
        const float* oWl   = oW + (size_t)l * 1024 * 1024;
        const float* w1l   = ffw1 + (size_t)l * 1024 * 4096;
        const float* w2l   = ffw2 + (size_t)l * 4096 * 1024;

        transpose_all<<<3328, 256, 0, stream>>>(qkvWl, rWl, oWl, w1l, w2l,
                                                qkvT, rT, oT, w1T, w2T);

        mems_cat<<<2048, 256, 0, stream>>>(mems + (size_t)l * 2048 * 1024, catb);

        qkv_rk_gemm<<<704, 256, 0, stream>>>(catb, posb, qkvT, rT,
                                             rwb + l * 1024, rrb + l * 1024,
                                             Qw, Qr, Kb, VTb, Rb);

        bd_gemm<<<64 * 26, 256, 0, stream>>>(Qr, Rb, BDs);

        attn_part<<<64 * 144, 64, 0, stream>>>(Qw, Kb, VTb, BDs, Opart, msbuf);
        attn_merge<<<512, 256, 0, stream>>>(Opart, msbuf, avec);

        gemm_bt<0, 64><<<(2048 / 128) * (1024 / 64), 256, 0, stream>>>(
            avec, oT, resid, nullptr, nullptr, 2048, 1024, 1024);
        ln_kernel<<<2048, 256, 0, stream>>>(h, resid, ln1g + l * 1024, ln1b + l * 1024, h, hbf);

        gemm_bt<1, 128><<<(2048 / 128) * (4096 / 128), 256, 0, stream>>>(
            hbf, w1T, nullptr, ff1b, ffb1 + l * 4096, 2048, 4096, 1024);
        gemm_bt<2, 64><<<(2048 / 128) * (1024 / 64), 256, 0, stream>>>(
            ff1b, w2T, resid, nullptr, ffb2 + l * 1024, 2048, 1024, 4096);
        // ln2 writes bf16 directly into next layer's cat high half (l<3)
        ln_kernel<<<2048, 256, 0, stream>>>(h, resid, ln2g + l * 1024, ln2b + l * 1024, h,
                                            (l < 3) ? catbHi : hbf);
    }

    out_kernel<<<2048, 256, 0, stream>>>(h, (float*)d_out);
}

// Round 15
// 975.382 us; speedup vs baseline: 1.1706x; 1.1052x over previous
//
#include <hip/hip_runtime.h>

typedef __attribute__((ext_vector_type(8))) short bf16x8;
typedef __attribute__((ext_vector_type(4))) float f32x4;

#define N_LAYER 4
#define QLEN 512
#define MLEN 512
#define KLEN 1024
#define BSZ 4
#define DM 1024
#define NH 16
#define DH 64
#define DINNER 4096
#define EK 1408
#define BDLD 1152  // BDs row stride (1024 + 128 pad; pad cols never written, always masked)

__device__ __forceinline__ unsigned short f2bf(float x) {
    unsigned u = __float_as_uint(x);
    u += 0x7fffu + ((u >> 16) & 1u);
    return (unsigned short)(u >> 16);
}
__device__ __forceinline__ float bf2f(unsigned short v) {
    return __uint_as_float(((unsigned)v) << 16);
}

__device__ __forceinline__ void gload16(const unsigned short* g, unsigned short* l) {
    __builtin_amdgcn_global_load_lds(
        (const __attribute__((address_space(1))) unsigned int*)g,
        (__attribute__((address_space(3))) unsigned int*)l, 16, 0, 0);
}

// swizzled b128 LDS read for 128B-row-stride bf16 tiles: byte ^= (row&7)<<4
__device__ __forceinline__ bf16x8 lds_read8_sw(const unsigned short* base, int row, int cb) {
    return *(const bf16x8*)((const char*)base + row * 128 + (cb ^ ((row & 7) << 4)));
}

// ---------------------------------------------------------------------------
// All 5 per-layer weight transposes in ONE launch. 64x64 tiles.
// ---------------------------------------------------------------------------
__global__ __launch_bounds__(256)
void transpose_all(const float* __restrict__ qkvWl, const float* __restrict__ rWl,
                   const float* __restrict__ oWl, const float* __restrict__ w1l,
                   const float* __restrict__ w2l,
                   unsigned short* __restrict__ qkvT, unsigned short* __restrict__ rT,
                   unsigned short* __restrict__ oT, unsigned short* __restrict__ w1T,
                   unsigned short* __restrict__ w2T) {
    __shared__ float tile[64][65];
    int id = blockIdx.x;
    const float* W; unsigned short* D; int K, N, bx, by;
    if (id < 768)       { W = qkvWl; D = qkvT; K = 1024; N = 3072; bx = id % 48; by = id / 48; }
    else if (id < 1024) { id -= 768;  W = rWl;  D = rT;  K = 1024; N = 1024; bx = id & 15; by = id >> 4; }
    else if (id < 1280) { id -= 1024; W = oWl;  D = oT;  K = 1024; N = 1024; bx = id & 15; by = id >> 4; }
    else if (id < 2304) { id -= 1280; W = w1l;  D = w1T; K = 1024; N = 4096; bx = id & 63; by = id >> 6; }
    else                { id -= 2304; W = w2l;  D = w2T; K = 4096; N = 1024; bx = id & 15; by = id >> 4; }
    const int tid = threadIdx.x;
#pragma unroll
    for (int s = 0; s < 4; ++s) {
        int idx = s * 256 + tid;
        int kr = idx >> 4, c4 = (idx & 15) * 4;
        float4 v = *(const float4*)(W + (size_t)(by * 64 + kr) * N + bx * 64 + c4);
        tile[kr][c4] = v.x; tile[kr][c4 + 1] = v.y;
        tile[kr][c4 + 2] = v.z; tile[kr][c4 + 3] = v.w;
    }
    __syncthreads();
#pragma unroll
    for (int s = 0; s < 2; ++s) {
        int idx = s * 256 + tid;
        int nl = idx >> 3, k8 = (idx & 7) * 8;
        unsigned short tmp[8];
#pragma unroll
        for (int j = 0; j < 8; ++j) tmp[j] = f2bf(tile[k8 + j][nl]);
        *(uint4*)(D + (size_t)(bx * 64 + nl) * K + by * 64 + k8) = *(uint4*)tmp;
    }
}

// Transpose with zero-padding beyond K rows, into a slice of a wider dst row.
__global__ __launch_bounds__(256)
void transpose_pad(const float* __restrict__ W, unsigned short* __restrict__ dst,
                   int K, int N, int dstLD, int dstOff) {
    __shared__ float tile[32][33];
    const int tx = threadIdx.x & 31, ty = threadIdx.x >> 5;
    const int bx = blockIdx.x, by = blockIdx.y;
#pragma unroll
    for (int i = 0; i < 4; ++i) {
        int k = by * 32 + ty + i * 8;
        tile[ty + i * 8][tx] = (k < K) ? W[(size_t)k * N + bx * 32 + tx] : 0.f;
    }
    __syncthreads();
#pragma unroll
    for (int i = 0; i < 4; ++i) {
        int n = bx * 32 + ty + i * 8;
        int k = by * 32 + tx;
        dst[(size_t)n * dstLD + dstOff + k] = f2bf(tile[tx][ty + i * 8]);
    }
}

// ---------------------------------------------------------------------------
// Adaptive-embedding gather: embA[t][0:1408) = masked cluster row * 32, bf16
// ---------------------------------------------------------------------------
__global__ __launch_bounds__(256)
void emb_gather(const int* __restrict__ ids,
                const float* __restrict__ e0, const float* __restrict__ e1,
                const float* __restrict__ e2, const float* __restrict__ e3,
                unsigned short* __restrict__ embA) {
    const int chunk = blockIdx.x * 256 + threadIdx.x;
    if (chunk >= 2048 * 176) return;
    const int t = chunk / 176;
    const int e8 = (chunk - t * 176) * 8;
    const int i = t >> 2, b = t & 3;
    const int id = ids[b * QLEN + i];
    const float* src = nullptr;
    if (e8 < 1024) {
        if (id < 20000) src = e0 + (size_t)id * 1024 + e8;
    } else if (e8 < 1280) {
        if (id >= 20000 && id < 40000) src = e1 + (size_t)(id - 20000) * 256 + (e8 - 1024);
    } else if (e8 < 1344) {
        if (id >= 40000 && id < 200000) src = e2 + (size_t)(id - 40000) * 64 + (e8 - 1280);
    } else if (e8 < 1360) {
        if (id >= 200000) src = e3 + (size_t)(id - 200000) * 16 + (e8 - 1344);
    }
    uint4 o = {0u, 0u, 0u, 0u};
    if (src) {
        float4 v0 = *(const float4*)src;
        float4 v1 = *(const float4*)(src + 4);
        o.x = (unsigned)f2bf(v0.x * 32.f) | ((unsigned)f2bf(v0.y * 32.f) << 16);
        o.y = (unsigned)f2bf(v0.z * 32.f) | ((unsigned)f2bf(v0.w * 32.f) << 16);
        o.z = (unsigned)f2bf(v1.x * 32.f) | ((unsigned)f2bf(v1.y * 32.f) << 16);
        o.w = (unsigned)f2bf(v1.z * 32.f) | ((unsigned)f2bf(v1.w * 32.f) << 16);
    }
    *(uint4*)(embA + (size_t)t * EK + e8) = o;
}

// ---------------------------------------------------------------------------
// Generic GEMM (BK=64 dbuf, T2 swizzle, XCD swizzle).
// MODE 0: f32. 1: bf16(relu(+bias)). 2: f32+bias. 5: f32 + bf16 dual.
// ---------------------------------------------------------------------------
template <int MODE, int BN>
__global__ __launch_bounds__(256)
void gemm_bt(const unsigned short* __restrict__ A, const unsigned short* __restrict__ BT,
             float* __restrict__ C, unsigned short* __restrict__ Cbf,
             const float* __restrict__ bias, int M, int N, int K) {
    constexpr int NF = BN / 32;
    __shared__ unsigned short lA[2][128 * 64];
    __shared__ unsigned short lB[2][BN * 64];
    const int tid = threadIdx.x;
    const int w = tid >> 6, l = tid & 63;
    const int lane15 = l & 15, lh = l >> 4;
    const int nwg = gridDim.x;
    const int cpx = nwg >> 3;
    const int swz = (blockIdx.x & 7) * cpx + (blockIdx.x >> 3);
    const int nbn = N / BN;
    const int bm = swz / nbn, bn = swz % nbn;
    const int wr = (w >> 1) * 64, wc = (w & 1) * (BN / 2);

    f32x4 acc[4][NF] = {};

    const unsigned short* gA = A + (size_t)(bm * 128) * K;
    const unsigned short* gB = BT + (size_t)(bn * BN) * K;

    auto stage = [&](int buf, int k0) {
#pragma unroll
        for (int s = 0; s < 4; ++s) {
            int g = tid + s * 256, row = g >> 3;
            gload16(gA + (size_t)row * K + k0 + ((g & 7) ^ (row & 7)) * 8,
                    lA[buf] + g * 8);
        }
#pragma unroll
        for (int s = 0; s < BN / 32; ++s) {
            int g = tid + s * 256, row = g >> 3;
            gload16(gB + (size_t)row * K + k0 + ((g & 7) ^ (row & 7)) * 8,
                    lB[buf] + g * 8);
        }
    };

    stage(0, 0);
    __syncthreads();
    int cur = 0;
    for (int k0 = 0; k0 < K; k0 += 64) {
        if (k0 + 64 < K) stage(cur ^ 1, k0 + 64);
        const unsigned short* cA = lA[cur];
        const unsigned short* cB = lB[cur];
#pragma unroll
        for (int kk = 0; kk < 2; ++kk) {
            bf16x8 af[4], bfr[NF];
#pragma unroll
            for (int f = 0; f < 4; ++f)
                af[f] = lds_read8_sw(cA, wr + f * 16 + lane15, kk * 64 + lh * 16);
#pragma unroll
            for (int f = 0; f < NF; ++f)
                bfr[f] = lds_read8_sw(cB, wc + f * 16 + lane15, kk * 64 + lh * 16);
#pragma unroll
            for (int mi = 0; mi < 4; ++mi)
#pragma unroll
                for (int ni = 0; ni < NF; ++ni)
                    acc[mi][ni] = __builtin_amdgcn_mfma_f32_16x16x32_bf16(
                        af[mi], bfr[ni], acc[mi][ni], 0, 0, 0);
        }
        __syncthreads();
        cur ^= 1;
    }

#pragma unroll
    for (int mi = 0; mi < 4; ++mi) {
        int rowb = bm * 128 + wr + mi * 16 + lh * 4;
#pragma unroll
        for (int ni = 0; ni < NF; ++ni) {
            int col = bn * BN + wc + ni * 16 + lane15;
#pragma unroll
            for (int r = 0; r < 4; ++r) {
                float x = acc[mi][ni][r];
                if (MODE == 0) {
                    C[(size_t)(rowb + r) * N + col] = x;
                } else if (MODE == 1) {
                    x += bias[col];
                    Cbf[(size_t)(rowb + r) * N + col] = f2bf(x > 0.f ? x : 0.f);
                } else if (MODE == 2) {
                    C[(size_t)(rowb + r) * N + col] = x + bias[col];
                } else { // MODE 5
                    C[(size_t)(rowb + r) * N + col] = x;
                    Cbf[(size_t)(rowb + r) * N + col] = f2bf(x);
                }
            }
        }
    }
}

// ---------------------------------------------------------------------------
// Split-K=2 GEMM (one launch, 2x blocks): half h computes k in [h*K/2,(h+1)*K/2)
// and writes f32 partial C01 + h*M*N. Reduce is fused into the LN kernels.
// ---------------------------------------------------------------------------
template <int BN>
__global__ __launch_bounds__(256)
void gemm_sk(const unsigned short* __restrict__ A, const unsigned short* __restrict__ BT,
             float* __restrict__ C01, int M, int N, int K) {
    constexpr int NF = BN / 32;
    __shared__ unsigned short lA[2][128 * 64];
    __shared__ unsigned short lB[2][BN * 64];
    const int tid = threadIdx.x;
    const int w = tid >> 6, l = tid & 63;
    const int lane15 = l & 15, lh = l >> 4;
    const int nwg = gridDim.x;
    const int cpx = nwg >> 3;
    const int swz = (blockIdx.x & 7) * cpx + (blockIdx.x >> 3);
    const int nbn = N / BN;
    const int nhalf = (M / 128) * nbn;
    const int half = swz / nhalf;
    const int rem = swz % nhalf;
    const int bm = rem / nbn, bn = rem % nbn;
    const int KH = K >> 1;
    const int koff = half * KH;
    const int wr = (w >> 1) * 64, wc = (w & 1) * (BN / 2);

    f32x4 acc[4][NF] = {};

    const unsigned short* gA = A + (size_t)(bm * 128) * K + koff;
    const unsigned short* gB = BT + (size_t)(bn * BN) * K + koff;

    auto stage = [&](int buf, int k0) {
#pragma unroll
        for (int s = 0; s < 4; ++s) {
            int g = tid + s * 256, row = g >> 3;
            gload16(gA + (size_t)row * K + k0 + ((g & 7) ^ (row & 7)) * 8,
                    lA[buf] + g * 8);
        }
#pragma unroll
        for (int s = 0; s < BN / 32; ++s) {
            int g = tid + s * 256, row = g >> 3;
            gload16(gB + (size_t)row * K + k0 + ((g & 7) ^ (row & 7)) * 8,
                    lB[buf] + g * 8);
        }
    };

    stage(0, 0);
    __syncthreads();
    int cur = 0;
    for (int k0 = 0; k0 < KH; k0 += 64) {
        if (k0 + 64 < KH) stage(cur ^ 1, k0 + 64);
        const unsigned short* cA = lA[cur];
        const unsigned short* cB = lB[cur];
#pragma unroll
        for (int kk = 0; kk < 2; ++kk) {
            bf16x8 af[4], bfr[NF];
#pragma unroll
            for (int f = 0; f < 4; ++f)
                af[f] = lds_read8_sw(cA, wr + f * 16 + lane15, kk * 64 + lh * 16);
#pragma unroll
            for (int f = 0; f < NF; ++f)
                bfr[f] = lds_read8_sw(cB, wc + f * 16 + lane15, kk * 64 + lh * 16);
#pragma unroll
            for (int mi = 0; mi < 4; ++mi)
#pragma unroll
                for (int ni = 0; ni < NF; ++ni)
                    acc[mi][ni] = __builtin_amdgcn_mfma_f32_16x16x32_bf16(
                        af[mi], bfr[ni], acc[mi][ni], 0, 0, 0);
        }
        __syncthreads();
        cur ^= 1;
    }

    float* Cout = C01 + (size_t)half * M * N;
#pragma unroll
    for (int mi = 0; mi < 4; ++mi) {
        int rowb = bm * 128 + wr + mi * 16 + lh * 4;
#pragma unroll
        for (int ni = 0; ni < NF; ++ni) {
            int col = bn * BN + wc + ni * 16 + lane15;
#pragma unroll
            for (int r = 0; r < 4; ++r)
                Cout[(size_t)(rowb + r) * N + col] = acc[mi][ni][r];
        }
    }
}

// ---------------------------------------------------------------------------
// Combined QKV(KV) + QKV(Q, live rows only) + r_head_k GEMM, one launch.
// ---------------------------------------------------------------------------
__global__ __launch_bounds__(256)
void qkv_rk_gemm(const unsigned short* __restrict__ catb, const unsigned short* __restrict__ posb,
                 const unsigned short* __restrict__ qkvT, const unsigned short* __restrict__ rT,
                 const float* __restrict__ rwb, const float* __restrict__ rrb,
                 unsigned short* __restrict__ Qw, unsigned short* __restrict__ Qr,
                 unsigned short* __restrict__ Kb, unsigned short* __restrict__ VTb,
                 unsigned short* __restrict__ Rb) {
    __shared__ unsigned short lA[2][128 * 64];
    __shared__ unsigned short lB[2][128 * 64];
    const int tid = threadIdx.x;
    const int w = tid >> 6, l = tid & 63;
    const int lane15 = l & 15, lh = l >> 4;
    const int cpx = gridDim.x >> 3;   // 88
    const int swz = (blockIdx.x & 7) * cpx + (blockIdx.x >> 3);
    const int wr = (w >> 1) * 64, wc = (w & 1) * 64;

    const unsigned short* gA;
    const unsigned short* gB;
    int part, bm, bn;
    if (swz < 512)      { part = 0; bm = swz >> 4; bn = swz & 15;
                          gA = catb + (size_t)(bm * 128) * 1024;
                          gB = qkvT + (size_t)(1024 + bn * 128) * 1024; }
    else if (swz < 640) { part = 1; int q = swz - 512; bm = q >> 3; bn = q & 7;
                          gA = catb + (size_t)(2048 + bm * 128) * 1024;
                          gB = qkvT + (size_t)(bn * 128) * 1024; }
    else                { part = 2; int q = swz - 640; bm = q >> 3; bn = q & 7;
                          gA = posb + (size_t)(bm * 128) * 1024;
                          gB = rT + (size_t)(bn * 128) * 1024; }

    f32x4 acc[4][4] = {};
    auto stage = [&](int buf, int k0) {
#pragma unroll
        for (int s = 0; s < 4; ++s) {
            int g = tid + s * 256, row = g >> 3;
            gload16(gA + (size_t)row * 1024 + k0 + ((g & 7) ^ (row & 7)) * 8, lA[buf] + g * 8);
            gload16(gB + (size_t)row * 1024 + k0 + ((g & 7) ^ (row & 7)) * 8, lB[buf] + g * 8);
        }
    };
    stage(0, 0);
    __syncthreads();
    int cur = 0;
    for (int k0 = 0; k0 < 1024; k0 += 64) {
        if (k0 + 64 < 1024) stage(cur ^ 1, k0 + 64);
        const unsigned short* cA = lA[cur];
        const unsigned short* cB = lB[cur];
#pragma unroll
        for (int kk = 0; kk < 2; ++kk) {
            bf16x8 af[4], bfr[4];
#pragma unroll
            for (int f = 0; f < 4; ++f) {
                af[f]  = lds_read8_sw(cA, wr + f * 16 + lane15, kk * 64 + lh * 16);
                bfr[f] = lds_read8_sw(cB, wc + f * 16 + lane15, kk * 64 + lh * 16);
            }
#pragma unroll
            for (int mi = 0; mi < 4; ++mi)
#pragma unroll
                for (int ni = 0; ni < 4; ++ni)
                    acc[mi][ni] = __builtin_amdgcn_mfma_f32_16x16x32_bf16(
                        af[mi], bfr[ni], acc[mi][ni], 0, 0, 0);
        }
        __syncthreads();
        cur ^= 1;
    }

#pragma unroll
    for (int mi = 0; mi < 4; ++mi) {
        int rowb = bm * 128 + wr + mi * 16 + lh * 4;
#pragma unroll
        for (int ni = 0; ni < 4; ++ni) {
            int col = bn * 128 + wc + ni * 16 + lane15;
#pragma unroll
            for (int r = 0; r < 4; ++r) {
                float x = acc[mi][ni][r];
                if (part == 0) {           // KV scatter (all 4096 rows)
                    int j = rowb >> 2, bb_ = r;
                    if (col < 1024) {
                        int n = col >> 6, d = col & 63;
                        Kb[((size_t)(bb_ * NH + n) * KLEN + j) * DH + d] = f2bf(x);
                    } else {
                        int c2 = col - 1024, n = c2 >> 6, d = c2 & 63;
                        VTb[((size_t)(bb_ * NH + n) * DH + d) * KLEN + j] = f2bf(x);
                    }
                } else if (part == 1) {    // Q scatter (live rows), +biases, x1/8 into Qw
                    int i = rowb >> 2, bb_ = r;
                    int n = col >> 6, d = col & 63;
                    size_t o = ((size_t)(bb_ * NH + n) * QLEN + i) * DH + d;
                    Qw[o] = f2bf((x + rwb[col]) * 0.125f);
                    Qr[o] = f2bf(x + rrb[col]);
                } else {                   // RK scatter
                    int j = rowb + r;
                    int n = col >> 6, d = col & 63;
                    Rb[((size_t)n * KLEN + j) * DH + d] = f2bf(x);
                }
            }
        }
    }
}

// ---------------------------------------------------------------------------
// Batched BD GEMM (band-only): BDs[bn][i][k] = (Qr[i].Rb[k]) * 0.125
// ---------------------------------------------------------------------------
__global__ __launch_bounds__(256)
void bd_gemm(const unsigned short* __restrict__ Qr, const unsigned short* __restrict__ Rb,
             unsigned short* __restrict__ BDs) {
    __shared__ unsigned short lA[128 * 64];
    __shared__ unsigned short lB[128 * 64];
    const int tid = threadIdx.x;
    const int w = tid >> 6, l = tid & 63;
    const int lane15 = l & 15, lh = l >> 4;
    const int blk = blockIdx.x;
    const int bn = blk & 63;          // head-local XCD
    const int tile = blk >> 6;        // 0..25
    const int bd_mi[26] = {0,0,0,0,0, 1,1,1,1,1,1, 2,2,2,2,2,2,2, 3,3,3,3,3,3,3,3};
    const int bd_nj[26] = {3,4,5,6,7, 2,3,4,5,6,7, 1,2,3,4,5,6,7, 0,1,2,3,4,5,6,7};
    const int mi_ = bd_mi[tile], nj = bd_nj[tile];
    const int n = bn & 15;
    const int wr = (w >> 1) * 64, wc = (w & 1) * 64;

    const unsigned short* gA = Qr + (size_t)bn * QLEN * DH + (size_t)(mi_ * 128) * 64;
    const unsigned short* gB = Rb + (size_t)n * KLEN * DH + (size_t)(nj * 128) * 64;
#pragma unroll
    for (int s = 0; s < 4; ++s) {
        int g = tid + s * 256, row = g >> 3;
        gload16(gA + (size_t)row * 64 + ((g & 7) ^ (row & 7)) * 8, lA + g * 8);
        gload16(gB + (size_t)row * 64 + ((g & 7) ^ (row & 7)) * 8, lB + g * 8);
    }
    __syncthreads();
    f32x4 acc[4][4] = {};
#pragma unroll
    for (int kk = 0; kk < 2; ++kk) {
        bf16x8 af[4], bfr[4];
#pragma unroll
        for (int f = 0; f < 4; ++f) {
            af[f]  = lds_read8_sw(lA, wr + f * 16 + lane15, kk * 64 + lh * 16);
            bfr[f] = lds_read8_sw(lB, wc + f * 16 + lane15, kk * 64 + lh * 16);
        }
#pragma unroll
        for (int mi = 0; mi < 4; ++mi)
#pragma unroll
            for (int ni = 0; ni < 4; ++ni)
                acc[mi][ni] = __builtin_amdgcn_mfma_f32_16x16x32_bf16(
                    af[mi], bfr[ni], acc[mi][ni], 0, 0, 0);
    }
    unsigned short* out = BDs + (size_t)bn * 512 * BDLD;
#pragma unroll
    for (int mi = 0; mi < 4; ++mi) {
        int rowb = mi_ * 128 + wr + mi * 16 + lh * 4;
#pragma unroll
        for (int ni = 0; ni < 4; ++ni) {
            int col = nj * 128 + wc + ni * 16 + lane15;
#pragma unroll
            for (int r = 0; r < 4; ++r)
                out[(size_t)(rowb + r) * BDLD + col] = f2bf(acc[mi][ni][r] * 0.125f);
        }
    }
}

// ---------------------------------------------------------------------------
// Positional embedding table (1024 x 1024), bf16
// ---------------------------------------------------------------------------
__global__ __launch_bounds__(256)
void pos_kernel(unsigned short* __restrict__ posbf) {
    const int p = blockIdx.x, tid = threadIdx.x;
    const float ps = (float)(KLEN - 1 - p);
    const float c = -2.0f * 9.210340371976184f / 1024.0f; // -2*ln(10000)/D
#pragma unroll
    for (int j4 = 0; j4 < 4; ++j4) {
        int j = tid + j4 * 256;
        int m = (j < 512) ? j : j - 512;
        float freq = __expf((float)m * c);
        float ang = ps * freq;
        float v = (j < 512) ? sinf(ang) : cosf(ang);
        posbf[(size_t)p * DM + j] = f2bf(v);
    }
}

// ---------------------------------------------------------------------------
// mems[l] rows -> bf16 catb rows [0,2048)
// ---------------------------------------------------------------------------
__global__ __launch_bounds__(256)
void mems_cat(const float* __restrict__ mem_l, unsigned short* __restrict__ catbf) {
    const int t = blockIdx.x, tid = threadIdx.x;
    float4 v = ((const float4*)(mem_l + (size_t)t * DM))[tid];
    uint2 o;
    o.x = (unsigned)f2bf(v.x) | ((unsigned)f2bf(v.y) << 16);
    o.y = (unsigned)f2bf(v.z) | ((unsigned)f2bf(v.w) << 16);
    ((uint2*)(catbf + (size_t)t * DM))[tid] = o;
}

// ---------------------------------------------------------------------------
// Split-j-chunk rel-attention, stage 1 (R11/R13 structure).
// ---------------------------------------------------------------------------
__global__ __launch_bounds__(64)
void attn_part(const unsigned short* __restrict__ Qw,
               const unsigned short* __restrict__ Kb, const unsigned short* __restrict__ VTb,
               const unsigned short* __restrict__ BDs,
               unsigned short* __restrict__ Opart, float* __restrict__ ms) {
    __shared__ unsigned short lP[16 * 64];

    const int l = threadIdx.x;
    const int lane15 = l & 15, lh = l >> 4;
    const int blk = blockIdx.x;
    const int bn = blk & 63;          // head-local XCD
    const int rest = blk >> 6;        // 0..143
    const int rg = rest & 3;          // 16-row group within the 64-row i-tile
    const int c = rest >> 2;          // 0..35 chunk unit

    const int offt[8] = {0, 3, 7, 11, 15, 20, 25, 30};
    const int nctt[8] = {3, 4, 4, 4, 5, 5, 5, 6};
    int it = 0;
#pragma unroll
    for (int i = 1; i < 8; ++i) if (c >= offt[i]) it = i;
    const int cl = c - offt[it];
    const int nck = nctt[it];
    const int ntiles = it + 9;
    const int jt0 = (cl * ntiles) / nck;
    const int jt1 = ((cl + 1) * ntiles) / nck;
    const int i0 = it * 64;
    const int rowl = rg * 16 + lh * 4;

    bf16x8 qw[2];
    {
        size_t qb = ((size_t)bn * QLEN + i0 + rg * 16 + lane15) * DH + lh * 8;
        qw[0] = *(const bf16x8*)(Qw + qb);
        qw[1] = *(const bf16x8*)(Qw + qb + 32);
    }
    bf16x8 onesb;
#pragma unroll
    for (int j = 0; j < 8; ++j) onesb[j] = (short)0x3F80;   // bf16 1.0

    const unsigned short* kp = Kb + (size_t)bn * KLEN * DH + (size_t)(jt0 * 64 + lane15) * DH + lh * 8;
    const unsigned short* vp = VTb + (size_t)bn * DH * KLEN + (size_t)lane15 * KLEN + jt0 * 64 + lh * 8;
    const unsigned short* bdp[4];
#pragma unroll
    for (int r = 0; r < 4; ++r) {
        int row = i0 + rowl + r;                       // absolute i (<= 511)
        bdp[r] = BDs + (size_t)bn * 512 * BDLD + (size_t)row * BDLD
                 + (511 - row) + jt0 * 64 + lane15;    // col k = 511 + j - i
    }

    f32x4 oacc[4] = {};
    f32x4 srowv = {};   // row sums via ones-MFMA

    for (int jt = jt0; jt < jt1; ++jt) {
        float bdv[4][4];
#pragma unroll
        for (int f = 0; f < 4; ++f)
#pragma unroll
            for (int r = 0; r < 4; ++r)
                bdv[f][r] = bf2f(bdp[r][16 * f]);

        bf16x8 kf[2][4];
#pragma unroll
        for (int f = 0; f < 4; ++f) {
            const unsigned short* p = kp + (size_t)(f * 16) * DH;
            kf[0][f] = *(const bf16x8*)p;
            kf[1][f] = *(const bf16x8*)(p + 32);
        }

        f32x4 sac[4] = {};
        __builtin_amdgcn_s_setprio(1);
#pragma unroll
        for (int kk = 0; kk < 2; ++kk)
#pragma unroll
            for (int f = 0; f < 4; ++f)
                sac[f] = __builtin_amdgcn_mfma_f32_16x16x32_bf16(qw[kk], kf[kk][f], sac[f], 0, 0, 0);
        __builtin_amdgcn_s_setprio(0);

        bf16x8 vf[2][4];
#pragma unroll
        for (int kk = 0; kk < 2; ++kk)
#pragma unroll
            for (int f = 0; f < 4; ++f)
                vf[kk][f] = *(const bf16x8*)(vp + (size_t)(f * 16) * KLEN + kk * 32);

        const bool lastTile = (jt == it + 8);
        float pv[4][4];
#pragma unroll
        for (int f = 0; f < 4; ++f) {
            int lj = lane15 + 16 * f;
#pragma unroll
            for (int r = 0; r < 4; ++r) {
                float s = sac[f][r] + bdv[f][r];
                if (lastTile && (lj > rowl + r)) s = -1e30f;
                pv[f][r] = __expf(s - 8.f);
            }
        }

#pragma unroll
        for (int f = 0; f < 4; ++f)
#pragma unroll
            for (int r = 0; r < 4; ++r) {
                int row = lh * 4 + r, cb2 = (lane15 + 16 * f) * 2;
                *(unsigned short*)((char*)lP + row * 128 + (cb2 ^ ((row & 7) << 4))) =
                    f2bf(pv[f][r]);
            }
        bf16x8 pa[2];
        pa[0] = lds_read8_sw(lP, lane15, lh * 16);
        pa[1] = lds_read8_sw(lP, lane15, 64 + lh * 16);

        __builtin_amdgcn_s_setprio(1);
#pragma unroll
        for (int kk = 0; kk < 2; ++kk) {
#pragma unroll
            for (int f = 0; f < 4; ++f)
                oacc[f] = __builtin_amdgcn_mfma_f32_16x16x32_bf16(pa[kk], vf[kk][f], oacc[f], 0, 0, 0);
            srowv = __builtin_amdgcn_mfma_f32_16x16x32_bf16(pa[kk], onesb, srowv, 0, 0, 0);
        }
        __builtin_amdgcn_s_setprio(0);

        kp += 64 * DH;
        vp += 64;
#pragma unroll
        for (int r = 0; r < 4; ++r) bdp[r] += 64;
    }

    const int slot = (bn * 8 + it) * 6 + cl;
    unsigned short* Op = Opart + (size_t)slot * 4096;
#pragma unroll
    for (int f = 0; f < 4; ++f)
#pragma unroll
        for (int r = 0; r < 4; ++r)
            Op[(rowl + r) * 64 + lane15 + 16 * f] = f2bf(oacc[f][r]);
    if (lane15 == 0) {
        float* msp = ms + (size_t)slot * 64;
#pragma unroll
        for (int r = 0; r < 4; ++r) msp[rowl + r] = srowv[r];
    }
}

// ---------------------------------------------------------------------------
// Split-j merge: block = (head, i-tile); sums <=6 partials per row.
// ---------------------------------------------------------------------------
__global__ __launch_bounds__(256)
void attn_merge(const unsigned short* __restrict__ Opart, const float* __restrict__ ms,
                unsigned short* __restrict__ avec) {
    const int blk = blockIdx.x;          // 512
    const int bn = blk & 63, it = blk >> 6;
    const int n = bn & 15, b = bn >> 4;
    const int nctt[8] = {3, 4, 4, 4, 5, 5, 5, 6};
    const int k = nctt[it];
    const int tid = threadIdx.x;
    const int r = tid >> 2, cq = (tid & 3) * 16;
    const int base_slot = (bn * 8 + it) * 6;

    float S = 0.f;
    for (int c = 0; c < k; ++c) S += ms[(size_t)(base_slot + c) * 64 + r];

    float acc[16];
#pragma unroll
    for (int j = 0; j < 16; ++j) acc[j] = 0.f;
    for (int c = 0; c < k; ++c) {
        const bf16x8* op = (const bf16x8*)(Opart + (size_t)(base_slot + c) * 4096 + r * 64 + cq);
        bf16x8 v0 = op[0], v1 = op[1];
#pragma unroll
        for (int j = 0; j < 8; ++j) {
            acc[j]     += bf2f((unsigned short)v0[j]);
            acc[8 + j] += bf2f((unsigned short)v1[j]);
        }
    }
    float inv = 1.0f / S;
    int t = (it * 64 + r) * 4 + b;
    unsigned short* dst = avec + (size_t)t * DM + n * 64 + cq;
#pragma unroll
    for (int j = 0; j < 16; ++j) dst[j] = f2bf(acc[j] * inv);
}

// ---------------------------------------------------------------------------
// LayerNorm with fused split-K reduce: h = LN(hin + res0 + res1 [+ bias2])
// emits f32 h and bf16 (dst hbf).
// ---------------------------------------------------------------------------
__global__ __launch_bounds__(256)
void ln_kernel(const float* __restrict__ hin, const float* __restrict__ res0,
               const float* __restrict__ res1, const float* __restrict__ bias2,
               const float* __restrict__ g, const float* __restrict__ bb,
               float* __restrict__ hout, unsigned short* __restrict__ hbf) {
    __shared__ float ls[8];
    const int t = blockIdx.x, tid = threadIdx.x;
    float4 x = ((const float4*)(hin + (size_t)t * DM))[tid];
    float4 r0 = ((const float4*)(res0 + (size_t)t * DM))[tid];
    float4 r1 = ((const float4*)(res1 + (size_t)t * DM))[tid];
    float v0 = x.x + r0.x + r1.x, v1 = x.y + r0.y + r1.y;
    float v2 = x.z + r0.z + r1.z, v3 = x.w + r0.w + r1.w;
    if (bias2) {
        float4 b2 = ((const float4*)bias2)[tid];
        v0 += b2.x; v1 += b2.y; v2 += b2.z; v3 += b2.w;
    }
    float s = v0 + v1 + v2 + v3;
    float sq = v0 * v0 + v1 * v1 + v2 * v2 + v3 * v3;
#pragma unroll
    for (int off = 1; off < 64; off <<= 1) {
        s += __shfl_xor(s, off);
        sq += __shfl_xor(sq, off);
    }
    const int w = tid >> 6;
    if ((tid & 63) == 0) { ls[w] = s; ls[4 + w] = sq; }
    __syncthreads();
    s = ls[0] + ls[1] + ls[2] + ls[3];
    sq = ls[4] + ls[5] + ls[6] + ls[7];
    float mu = s * (1.f / 1024.f);
    float var = sq * (1.f / 1024.f) - mu * mu;
    float rstd = rsqrtf(var + 1e-5f);
    float y[4] = {v0, v1, v2, v3};
    float4 of;
    uint2 ob;
    float* op = &of.x;
#pragma unroll
    for (int j = 0; j < 4; ++j) {
        int d = tid * 4 + j;
        op[j] = (y[j] - mu) * rstd * g[d] + bb[d];
    }
    ob.x = (unsigned)f2bf(of.x) | ((unsigned)f2bf(of.y) << 16);
    ob.y = (unsigned)f2bf(of.z) | ((unsigned)f2bf(of.w) << 16);
    ((float4*)(hout + (size_t)t * DM))[tid] = of;
    ((uint2*)(hbf + (size_t)t * DM))[tid] = ob;
}

__global__ __launch_bounds__(256)
void out_kernel(const float* __restrict__ h, float* __restrict__ out) {
    const int t = blockIdx.x, tid = threadIdx.x;
    const int i = t >> 2, b = t & 3;
    ((float4*)(out + ((size_t)b * QLEN + i) * DM))[tid] =
        ((const float4*)(h + (size_t)t * DM))[tid];
}

// ---------------------------------------------------------------------------
extern "C" void kernel_launch(void* const* d_in, const int* in_sizes, int n_in,
                              void* d_out, int out_size, void* d_ws, size_t ws_size,
                              hipStream_t stream) {
    const int* ids = (const int*)d_in[0];
    const float* mems = (const float*)d_in[1];
    const float* embp[4] = {nullptr, nullptr, nullptr, nullptr};
    const float* projp[4] = {nullptr, nullptr, nullptr, nullptr};
    const long long esz[4] = {20000LL * 1024, 20000LL * 256, 160000LL * 64, 67735LL * 16};
    const long long psz[4] = {1024LL * 1024, 256LL * 1024, 64LL * 1024, 16LL * 1024};
    for (int idx = 2; idx <= 9 && idx < n_in; ++idx) {
        long long s = in_sizes[idx];
        for (int c = 0; c < 4; ++c) {
            if (s == esz[c]) embp[c] = (const float*)d_in[idx];
            else if (s == psz[c]) projp[c] = (const float*)d_in[idx];
        }
    }
    const float* qkvW = (const float*)d_in[10];
    const float* rW   = (const float*)d_in[11];
    const float* oW   = (const float*)d_in[12];
    const float* rwb  = (const float*)d_in[13];
    const float* rrb  = (const float*)d_in[14];
    const float* ln1g = (const float*)d_in[15];
    const float* ln1b = (const float*)d_in[16];
    const float* ffw1 = (const float*)d_in[17];
    const float* ffb1 = (const float*)d_in[18];
    const float* ffw2 = (const float*)d_in[19];
    const float* ffb2 = (const float*)d_in[20];
    const float* ln2g = (const float*)d_in[21];
    const float* ln2b = (const float*)d_in[22];

    size_t off = 0;
    char* base = (char*)d_ws;
    auto alloc = [&](size_t bytes) -> char* {
        char* p = base + off;
        off = (off + bytes + 255) & ~(size_t)255;
        return p;
    };
    unsigned short* qkvT  = (unsigned short*)alloc(3072ull * 1024 * 2);
    unsigned short* rT    = (unsigned short*)alloc(1024ull * 1024 * 2);
    unsigned short* oT    = (unsigned short*)alloc(1024ull * 1024 * 2);
    unsigned short* w1T   = (unsigned short*)alloc(4096ull * 1024 * 2);
    unsigned short* w2T   = (unsigned short*)alloc(1024ull * 4096 * 2);
    unsigned short* embA  = (unsigned short*)alloc(2048ull * EK * 2);
    unsigned short* embBT = (unsigned short*)alloc(1024ull * EK * 2);
    float* h              = (float*)alloc(2048ull * 1024 * 4);
    unsigned short* hbf   = (unsigned short*)alloc(2048ull * 1024 * 2);
    unsigned short* catb  = (unsigned short*)alloc(4096ull * 1024 * 2);
    unsigned short* posb  = (unsigned short*)alloc(1024ull * 1024 * 2);
    unsigned short* Qw    = (unsigned short*)alloc(4ull * 16 * 512 * 64 * 2);
    unsigned short* Qr    = (unsigned short*)alloc(4ull * 16 * 512 * 64 * 2);
    unsigned short* Kb    = (unsigned short*)alloc(4ull * 16 * 1024 * 64 * 2);
    unsigned short* VTb   = (unsigned short*)alloc(4ull * 16 * 1024 * 64 * 2);
    unsigned short* Rb    = (unsigned short*)alloc(16ull * 1024 * 64 * 2);
    unsigned short* avec  = (unsigned short*)alloc(2048ull * 1024 * 2);
    float* resid01        = (float*)alloc(2ull * 2048 * 1024 * 4);        // 16 MB (split-K partials)
    unsigned short* ff1b  = (unsigned short*)alloc(2048ull * 4096 * 2);
    unsigned short* Opart = (unsigned short*)alloc(3072ull * 4096 * 2);   // 24 MB
    float* msbuf          = (float*)alloc(3072ull * 64 * 4);              // 0.75 MB
    unsigned short* BDs   = (unsigned short*)alloc(64ull * 512 * BDLD * 2); // 75.5 MB
    (void)ws_size; (void)out_size;

    unsigned short* catbHi = catb + 2048ull * 1024;   // h-half of cat (bf16)
    float* resid1 = resid01 + 2048ull * 1024;

    // ---- embeddings (gather + GEMM) + positional table ----
    emb_gather<<<(2048 * 176 + 255) / 256, 256, 0, stream>>>(
        ids, embp[0], embp[1], embp[2], embp[3], embA);
    transpose_pad<<<dim3(32, 32), 256, 0, stream>>>(projp[0], embBT, 1024, 1024, EK, 0);
    transpose_pad<<<dim3(32, 8),  256, 0, stream>>>(projp[1], embBT, 256,  1024, EK, 1024);
    transpose_pad<<<dim3(32, 2),  256, 0, stream>>>(projp[2], embBT, 64,   1024, EK, 1280);
    transpose_pad<<<dim3(32, 2),  256, 0, stream>>>(projp[3], embBT, 16,   1024, EK, 1344);
    pos_kernel<<<1024, 256, 0, stream>>>(posb);
    gemm_bt<5, 128><<<(2048 / 128) * (1024 / 128), 256, 0, stream>>>(
        embA, embBT, h, catbHi, nullptr, 2048, 1024, EK);

    for (int l = 0; l < N_LAYER; ++l) {
        const float* qkvWl = qkvW + (size_t)l * 1024 * 3072;
        const float* rWl   = rW + (size_t)l * 1024 * 1024;
        const float* oWl   = oW + (size_t)l * 1024 * 1024;
        const float* w1l   = ffw1 + (size_t)l * 1024 * 4096;
        const float* w2l   = ffw2 + (size_t)l * 4096 * 1024;

        transpose_all<<<3328, 256, 0, stream>>>(qkvWl, rWl, oWl, w1l, w2l,
                                                qkvT, rT, oT, w1T, w2T);

        mems_cat<<<2048, 256, 0, stream>>>(mems + (size_t)l * 2048 * 1024, catb);

        qkv_rk_gemm<<<704, 256, 0, stream>>>(catb, posb, qkvT, rT,
                                             rwb + l * 1024, rrb + l * 1024,
                                             Qw, Qr, Kb, VTb, Rb);

        bd_gemm<<<64 * 26, 256, 0, stream>>>(Qr, Rb, BDs);

        attn_part<<<64 * 144, 64, 0, stream>>>(Qw, Kb, VTb, BDs, Opart, msbuf);
        attn_merge<<<512, 256, 0, stream>>>(Opart, msbuf, avec);

        // o-proj split-K=2 (one launch, 512 blocks); reduce fused into ln1
        gemm_sk<64><<<2 * (2048 / 128) * (1024 / 64), 256, 0, stream>>>(
            avec, oT, resid01, 2048, 1024, 1024);
        ln_kernel<<<2048, 256, 0, stream>>>(h, resid01, resid1, nullptr,
                                            ln1g + l * 1024, ln1b + l * 1024, h, hbf);

        gemm_bt<1, 128><<<(2048 / 128) * (4096 / 128), 256, 0, stream>>>(
            hbf, w1T, nullptr, ff1b, ffb1 + l * 4096, 2048, 4096, 1024);

        // ff2 split-K=2; reduce + ffb2 bias fused into ln2
        gemm_sk<64><<<2 * (2048 / 128) * (1024 / 64), 256, 0, stream>>>(
            ff1b, w2T, resid01, 2048, 1024, 4096);
        ln_kernel<<<2048, 256, 0, stream>>>(h, resid01, resid1, ffb2 + l * 1024,
                                            ln2g + l * 1024, ln2b + l * 1024, h,
                                            (l < 3) ? catbHi : hbf);
    }

    out_kernel<<<2048, 256, 0, stream>>>(h, (float*)d_out);
}

// Round 16
// 969.970 us; speedup vs baseline: 1.1771x; 1.0056x over previous
//
#include <hip/hip_runtime.h>

typedef __attribute__((ext_vector_type(8))) short bf16x8;
typedef __attribute__((ext_vector_type(4))) float f32x4;

#define N_LAYER 4
#define QLEN 512
#define MLEN 512
#define KLEN 1024
#define BSZ 4
#define DM 1024
#define NH 16
#define DH 64
#define DINNER 4096
#define EK 1408
#define BDLD 1152  // BDs row stride (1024 + 128 pad; pad cols never written, always masked)

__device__ __forceinline__ unsigned short f2bf(float x) {
    unsigned u = __float_as_uint(x);
    u += 0x7fffu + ((u >> 16) & 1u);
    return (unsigned short)(u >> 16);
}
__device__ __forceinline__ float bf2f(unsigned short v) {
    return __uint_as_float(((unsigned)v) << 16);
}

__device__ __forceinline__ void gload16(const unsigned short* g, unsigned short* l) {
    __builtin_amdgcn_global_load_lds(
        (const __attribute__((address_space(1))) unsigned int*)g,
        (__attribute__((address_space(3))) unsigned int*)l, 16, 0, 0);
}

// swizzled b128 LDS read for 128B-row-stride bf16 tiles: byte ^= (row&7)<<4
__device__ __forceinline__ bf16x8 lds_read8_sw(const unsigned short* base, int row, int cb) {
    return *(const bf16x8*)((const char*)base + row * 128 + (cb ^ ((row & 7) << 4)));
}

// ---------------------------------------------------------------------------
// All 5 per-layer weight transposes in ONE launch. 64x64 tiles.
// ---------------------------------------------------------------------------
__global__ __launch_bounds__(256)
void transpose_all(const float* __restrict__ qkvWl, const float* __restrict__ rWl,
                   const float* __restrict__ oWl, const float* __restrict__ w1l,
                   const float* __restrict__ w2l,
                   unsigned short* __restrict__ qkvT, unsigned short* __restrict__ rT,
                   unsigned short* __restrict__ oT, unsigned short* __restrict__ w1T,
                   unsigned short* __restrict__ w2T) {
    __shared__ float tile[64][65];
    int id = blockIdx.x;
    const float* W; unsigned short* D; int K, N, bx, by;
    if (id < 768)       { W = qkvWl; D = qkvT; K = 1024; N = 3072; bx = id % 48; by = id / 48; }
    else if (id < 1024) { id -= 768;  W = rWl;  D = rT;  K = 1024; N = 1024; bx = id & 15; by = id >> 4; }
    else if (id < 1280) { id -= 1024; W = oWl;  D = oT;  K = 1024; N = 1024; bx = id & 15; by = id >> 4; }
    else if (id < 2304) { id -= 1280; W = w1l;  D = w1T; K = 1024; N = 4096; bx = id & 63; by = id >> 6; }
    else                { id -= 2304; W = w2l;  D = w2T; K = 4096; N = 1024; bx = id & 15; by = id >> 4; }
    const int tid = threadIdx.x;
#pragma unroll
    for (int s = 0; s < 4; ++s) {
        int idx = s * 256 + tid;
        int kr = idx >> 4, c4 = (idx & 15) * 4;
        float4 v = *(const float4*)(W + (size_t)(by * 64 + kr) * N + bx * 64 + c4);
        tile[kr][c4] = v.x; tile[kr][c4 + 1] = v.y;
        tile[kr][c4 + 2] = v.z; tile[kr][c4 + 3] = v.w;
    }
    __syncthreads();
#pragma unroll
    for (int s = 0; s < 2; ++s) {
        int idx = s * 256 + tid;
        int nl = idx >> 3, k8 = (idx & 7) * 8;
        unsigned short tmp[8];
#pragma unroll
        for (int j = 0; j < 8; ++j) tmp[j] = f2bf(tile[k8 + j][nl]);
        *(uint4*)(D + (size_t)(bx * 64 + nl) * K + by * 64 + k8) = *(uint4*)tmp;
    }
}

// Transpose with zero-padding beyond K rows, into a slice of a wider dst row.
__global__ __launch_bounds__(256)
void transpose_pad(const float* __restrict__ W, unsigned short* __restrict__ dst,
                   int K, int N, int dstLD, int dstOff) {
    __shared__ float tile[32][33];
    const int tx = threadIdx.x & 31, ty = threadIdx.x >> 5;
    const int bx = blockIdx.x, by = blockIdx.y;
#pragma unroll
    for (int i = 0; i < 4; ++i) {
        int k = by * 32 + ty + i * 8;
        tile[ty + i * 8][tx] = (k < K) ? W[(size_t)k * N + bx * 32 + tx] : 0.f;
    }
    __syncthreads();
#pragma unroll
    for (int i = 0; i < 4; ++i) {
        int n = bx * 32 + ty + i * 8;
        int k = by * 32 + tx;
        dst[(size_t)n * dstLD + dstOff + k] = f2bf(tile[tx][ty + i * 8]);
    }
}

// ---------------------------------------------------------------------------
// Adaptive-embedding gather: embA[t][0:1408) = masked cluster row * 32, bf16
// ---------------------------------------------------------------------------
__global__ __launch_bounds__(256)
void emb_gather(const int* __restrict__ ids,
                const float* __restrict__ e0, const float* __restrict__ e1,
                const float* __restrict__ e2, const float* __restrict__ e3,
                unsigned short* __restrict__ embA) {
    const int chunk = blockIdx.x * 256 + threadIdx.x;
    if (chunk >= 2048 * 176) return;
    const int t = chunk / 176;
    const int e8 = (chunk - t * 176) * 8;
    const int i = t >> 2, b = t & 3;
    const int id = ids[b * QLEN + i];
    const float* src = nullptr;
    if (e8 < 1024) {
        if (id < 20000) src = e0 + (size_t)id * 1024 + e8;
    } else if (e8 < 1280) {
        if (id >= 20000 && id < 40000) src = e1 + (size_t)(id - 20000) * 256 + (e8 - 1024);
    } else if (e8 < 1344) {
        if (id >= 40000 && id < 200000) src = e2 + (size_t)(id - 40000) * 64 + (e8 - 1280);
    } else if (e8 < 1360) {
        if (id >= 200000) src = e3 + (size_t)(id - 200000) * 16 + (e8 - 1344);
    }
    uint4 o = {0u, 0u, 0u, 0u};
    if (src) {
        float4 v0 = *(const float4*)src;
        float4 v1 = *(const float4*)(src + 4);
        o.x = (unsigned)f2bf(v0.x * 32.f) | ((unsigned)f2bf(v0.y * 32.f) << 16);
        o.y = (unsigned)f2bf(v0.z * 32.f) | ((unsigned)f2bf(v0.w * 32.f) << 16);
        o.z = (unsigned)f2bf(v1.x * 32.f) | ((unsigned)f2bf(v1.y * 32.f) << 16);
        o.w = (unsigned)f2bf(v1.z * 32.f) | ((unsigned)f2bf(v1.w * 32.f) << 16);
    }
    *(uint4*)(embA + (size_t)t * EK + e8) = o;
}

// ---------------------------------------------------------------------------
// Generic GEMM (BK=64 dbuf, T2 swizzle, XCD swizzle).
// MODE 0: f32. 1: bf16(relu(+bias)). 2: f32+bias. 5: f32 + bf16 dual.
// ---------------------------------------------------------------------------
template <int MODE, int BN>
__global__ __launch_bounds__(256)
void gemm_bt(const unsigned short* __restrict__ A, const unsigned short* __restrict__ BT,
             float* __restrict__ C, unsigned short* __restrict__ Cbf,
             const float* __restrict__ bias, int M, int N, int K) {
    constexpr int NF = BN / 32;
    __shared__ unsigned short lA[2][128 * 64];
    __shared__ unsigned short lB[2][BN * 64];
    const int tid = threadIdx.x;
    const int w = tid >> 6, l = tid & 63;
    const int lane15 = l & 15, lh = l >> 4;
    const int nwg = gridDim.x;
    const int cpx = nwg >> 3;
    const int swz = (blockIdx.x & 7) * cpx + (blockIdx.x >> 3);
    const int nbn = N / BN;
    const int bm = swz / nbn, bn = swz % nbn;
    const int wr = (w >> 1) * 64, wc = (w & 1) * (BN / 2);

    f32x4 acc[4][NF] = {};

    const unsigned short* gA = A + (size_t)(bm * 128) * K;
    const unsigned short* gB = BT + (size_t)(bn * BN) * K;

    auto stage = [&](int buf, int k0) {
#pragma unroll
        for (int s = 0; s < 4; ++s) {
            int g = tid + s * 256, row = g >> 3;
            gload16(gA + (size_t)row * K + k0 + ((g & 7) ^ (row & 7)) * 8,
                    lA[buf] + g * 8);
        }
#pragma unroll
        for (int s = 0; s < BN / 32; ++s) {
            int g = tid + s * 256, row = g >> 3;
            gload16(gB + (size_t)row * K + k0 + ((g & 7) ^ (row & 7)) * 8,
                    lB[buf] + g * 8);
        }
    };

    stage(0, 0);
    __syncthreads();
    int cur = 0;
    for (int k0 = 0; k0 < K; k0 += 64) {
        if (k0 + 64 < K) stage(cur ^ 1, k0 + 64);
        const unsigned short* cA = lA[cur];
        const unsigned short* cB = lB[cur];
#pragma unroll
        for (int kk = 0; kk < 2; ++kk) {
            bf16x8 af[4], bfr[NF];
#pragma unroll
            for (int f = 0; f < 4; ++f)
                af[f] = lds_read8_sw(cA, wr + f * 16 + lane15, kk * 64 + lh * 16);
#pragma unroll
            for (int f = 0; f < NF; ++f)
                bfr[f] = lds_read8_sw(cB, wc + f * 16 + lane15, kk * 64 + lh * 16);
#pragma unroll
            for (int mi = 0; mi < 4; ++mi)
#pragma unroll
                for (int ni = 0; ni < NF; ++ni)
                    acc[mi][ni] = __builtin_amdgcn_mfma_f32_16x16x32_bf16(
                        af[mi], bfr[ni], acc[mi][ni], 0, 0, 0);
        }
        __syncthreads();
        cur ^= 1;
    }

#pragma unroll
    for (int mi = 0; mi < 4; ++mi) {
        int rowb = bm * 128 + wr + mi * 16 + lh * 4;
#pragma unroll
        for (int ni = 0; ni < NF; ++ni) {
            int col = bn * BN + wc + ni * 16 + lane15;
#pragma unroll
            for (int r = 0; r < 4; ++r) {
                float x = acc[mi][ni][r];
                if (MODE == 0) {
                    C[(size_t)(rowb + r) * N + col] = x;
                } else if (MODE == 1) {
                    x += bias[col];
                    Cbf[(size_t)(rowb + r) * N + col] = f2bf(x > 0.f ? x : 0.f);
                } else if (MODE == 2) {
                    C[(size_t)(rowb + r) * N + col] = x + bias[col];
                } else { // MODE 5
                    C[(size_t)(rowb + r) * N + col] = x;
                    Cbf[(size_t)(rowb + r) * N + col] = f2bf(x);
                }
            }
        }
    }
}

// ---------------------------------------------------------------------------
// Split-K=2 GEMM (one launch, 2x blocks); reduce fused into the LN kernels.
// ---------------------------------------------------------------------------
template <int BN>
__global__ __launch_bounds__(256)
void gemm_sk(const unsigned short* __restrict__ A, const unsigned short* __restrict__ BT,
             float* __restrict__ C01, int M, int N, int K) {
    constexpr int NF = BN / 32;
    __shared__ unsigned short lA[2][128 * 64];
    __shared__ unsigned short lB[2][BN * 64];
    const int tid = threadIdx.x;
    const int w = tid >> 6, l = tid & 63;
    const int lane15 = l & 15, lh = l >> 4;
    const int nwg = gridDim.x;
    const int cpx = nwg >> 3;
    const int swz = (blockIdx.x & 7) * cpx + (blockIdx.x >> 3);
    const int nbn = N / BN;
    const int nhalf = (M / 128) * nbn;
    const int half = swz / nhalf;
    const int rem = swz % nhalf;
    const int bm = rem / nbn, bn = rem % nbn;
    const int KH = K >> 1;
    const int koff = half * KH;
    const int wr = (w >> 1) * 64, wc = (w & 1) * (BN / 2);

    f32x4 acc[4][NF] = {};

    const unsigned short* gA = A + (size_t)(bm * 128) * K + koff;
    const unsigned short* gB = BT + (size_t)(bn * BN) * K + koff;

    auto stage = [&](int buf, int k0) {
#pragma unroll
        for (int s = 0; s < 4; ++s) {
            int g = tid + s * 256, row = g >> 3;
            gload16(gA + (size_t)row * K + k0 + ((g & 7) ^ (row & 7)) * 8,
                    lA[buf] + g * 8);
        }
#pragma unroll
        for (int s = 0; s < BN / 32; ++s) {
            int g = tid + s * 256, row = g >> 3;
            gload16(gB + (size_t)row * K + k0 + ((g & 7) ^ (row & 7)) * 8,
                    lB[buf] + g * 8);
        }
    };

    stage(0, 0);
    __syncthreads();
    int cur = 0;
    for (int k0 = 0; k0 < KH; k0 += 64) {
        if (k0 + 64 < KH) stage(cur ^ 1, k0 + 64);
        const unsigned short* cA = lA[cur];
        const unsigned short* cB = lB[cur];
#pragma unroll
        for (int kk = 0; kk < 2; ++kk) {
            bf16x8 af[4], bfr[NF];
#pragma unroll
            for (int f = 0; f < 4; ++f)
                af[f] = lds_read8_sw(cA, wr + f * 16 + lane15, kk * 64 + lh * 16);
#pragma unroll
            for (int f = 0; f < NF; ++f)
                bfr[f] = lds_read8_sw(cB, wc + f * 16 + lane15, kk * 64 + lh * 16);
#pragma unroll
            for (int mi = 0; mi < 4; ++mi)
#pragma unroll
                for (int ni = 0; ni < NF; ++ni)
                    acc[mi][ni] = __builtin_amdgcn_mfma_f32_16x16x32_bf16(
                        af[mi], bfr[ni], acc[mi][ni], 0, 0, 0);
        }
        __syncthreads();
        cur ^= 1;
    }

    float* Cout = C01 + (size_t)half * M * N;
#pragma unroll
    for (int mi = 0; mi < 4; ++mi) {
        int rowb = bm * 128 + wr + mi * 16 + lh * 4;
#pragma unroll
        for (int ni = 0; ni < NF; ++ni) {
            int col = bn * BN + wc + ni * 16 + lane15;
#pragma unroll
            for (int r = 0; r < 4; ++r)
                Cout[(size_t)(rowb + r) * N + col] = acc[mi][ni][r];
        }
    }
}

// ---------------------------------------------------------------------------
// Combined QKV(KV) + QKV(Q live rows) + r_head_k GEMM, one launch, 128x64
// tiles (48 KB LDS -> 3 blocks/CU). Grid 1408:
// [0,1024) KV (4096x2048), [1024,1280) Q (2048x1024), [1280,1408) RK.
// ---------------------------------------------------------------------------
__global__ __launch_bounds__(256)
void qkv_rk_gemm(const unsigned short* __restrict__ catb, const unsigned short* __restrict__ posb,
                 const unsigned short* __restrict__ qkvT, const unsigned short* __restrict__ rT,
                 const float* __restrict__ rwb, const float* __restrict__ rrb,
                 unsigned short* __restrict__ Qw, unsigned short* __restrict__ Qr,
                 unsigned short* __restrict__ Kb, unsigned short* __restrict__ VTb,
                 unsigned short* __restrict__ Rb) {
    __shared__ unsigned short lA[2][128 * 64];
    __shared__ unsigned short lB[2][64 * 64];
    const int tid = threadIdx.x;
    const int w = tid >> 6, l = tid & 63;
    const int lane15 = l & 15, lh = l >> 4;
    const int cpx = gridDim.x >> 3;   // 176
    const int swz = (blockIdx.x & 7) * cpx + (blockIdx.x >> 3);
    const int wr = (w >> 1) * 64, wc = (w & 1) * 32;

    const unsigned short* gA;
    const unsigned short* gB;
    int part, bm, bn;
    if (swz < 1024)      { part = 0; bm = swz >> 5; bn = swz & 31;
                           gA = catb + (size_t)(bm * 128) * 1024;
                           gB = qkvT + (size_t)(1024 + bn * 64) * 1024; }
    else if (swz < 1280) { part = 1; int q = swz - 1024; bm = q >> 4; bn = q & 15;
                           gA = catb + (size_t)(2048 + bm * 128) * 1024;
                           gB = qkvT + (size_t)(bn * 64) * 1024; }
    else                 { part = 2; int q = swz - 1280; bm = q >> 4; bn = q & 15;
                           gA = posb + (size_t)(bm * 128) * 1024;
                           gB = rT + (size_t)(bn * 64) * 1024; }

    f32x4 acc[4][2] = {};
    auto stage = [&](int buf, int k0) {
#pragma unroll
        for (int s = 0; s < 4; ++s) {
            int g = tid + s * 256, row = g >> 3;
            gload16(gA + (size_t)row * 1024 + k0 + ((g & 7) ^ (row & 7)) * 8, lA[buf] + g * 8);
        }
#pragma unroll
        for (int s = 0; s < 2; ++s) {
            int g = tid + s * 256, row = g >> 3;
            gload16(gB + (size_t)row * 1024 + k0 + ((g & 7) ^ (row & 7)) * 8, lB[buf] + g * 8);
        }
    };
    stage(0, 0);
    __syncthreads();
    int cur = 0;
    for (int k0 = 0; k0 < 1024; k0 += 64) {
        if (k0 + 64 < 1024) stage(cur ^ 1, k0 + 64);
        const unsigned short* cA = lA[cur];
        const unsigned short* cB = lB[cur];
#pragma unroll
        for (int kk = 0; kk < 2; ++kk) {
            bf16x8 af[4], bfr[2];
#pragma unroll
            for (int f = 0; f < 4; ++f)
                af[f] = lds_read8_sw(cA, wr + f * 16 + lane15, kk * 64 + lh * 16);
#pragma unroll
            for (int f = 0; f < 2; ++f)
                bfr[f] = lds_read8_sw(cB, wc + f * 16 + lane15, kk * 64 + lh * 16);
#pragma unroll
            for (int mi = 0; mi < 4; ++mi)
#pragma unroll
                for (int ni = 0; ni < 2; ++ni)
                    acc[mi][ni] = __builtin_amdgcn_mfma_f32_16x16x32_bf16(
                        af[mi], bfr[ni], acc[mi][ni], 0, 0, 0);
        }
        __syncthreads();
        cur ^= 1;
    }

#pragma unroll
    for (int mi = 0; mi < 4; ++mi) {
        int rowb = bm * 128 + wr + mi * 16 + lh * 4;
#pragma unroll
        for (int ni = 0; ni < 2; ++ni) {
            int col = bn * 64 + wc + ni * 16 + lane15;
#pragma unroll
            for (int r = 0; r < 4; ++r) {
                float x = acc[mi][ni][r];
                if (part == 0) {           // KV scatter (all 4096 rows), N=2048
                    int j = rowb >> 2, bb_ = r;
                    if (col < 1024) {
                        int n = col >> 6, d = col & 63;
                        Kb[((size_t)(bb_ * NH + n) * KLEN + j) * DH + d] = f2bf(x);
                    } else {
                        int c2 = col - 1024, n = c2 >> 6, d = c2 & 63;
                        VTb[((size_t)(bb_ * NH + n) * DH + d) * KLEN + j] = f2bf(x);
                    }
                } else if (part == 1) {    // Q scatter (live rows), +biases, x1/8 into Qw
                    int i = rowb >> 2, bb_ = r;
                    int n = col >> 6, d = col & 63;
                    size_t o = ((size_t)(bb_ * NH + n) * QLEN + i) * DH + d;
                    Qw[o] = f2bf((x + rwb[col]) * 0.125f);
                    Qr[o] = f2bf(x + rrb[col]);
                } else {                   // RK scatter
                    int j = rowb + r;
                    int n = col >> 6, d = col & 63;
                    Rb[((size_t)n * KLEN + j) * DH + d] = f2bf(x);
                }
            }
        }
    }
}

// ---------------------------------------------------------------------------
// Batched BD GEMM (band-only): BDs[bn][i][k] = (Qr[i].Rb[k]) * 0.125
// ---------------------------------------------------------------------------
__global__ __launch_bounds__(256)
void bd_gemm(const unsigned short* __restrict__ Qr, const unsigned short* __restrict__ Rb,
             unsigned short* __restrict__ BDs) {
    __shared__ unsigned short lA[128 * 64];
    __shared__ unsigned short lB[128 * 64];
    const int tid = threadIdx.x;
    const int w = tid >> 6, l = tid & 63;
    const int lane15 = l & 15, lh = l >> 4;
    const int blk = blockIdx.x;
    const int bn = blk & 63;          // head-local XCD
    const int tile = blk >> 6;        // 0..25
    const int bd_mi[26] = {0,0,0,0,0, 1,1,1,1,1,1, 2,2,2,2,2,2,2, 3,3,3,3,3,3,3,3};
    const int bd_nj[26] = {3,4,5,6,7, 2,3,4,5,6,7, 1,2,3,4,5,6,7, 0,1,2,3,4,5,6,7};
    const int mi_ = bd_mi[tile], nj = bd_nj[tile];
    const int n = bn & 15;
    const int wr = (w >> 1) * 64, wc = (w & 1) * 64;

    const unsigned short* gA = Qr + (size_t)bn * QLEN * DH + (size_t)(mi_ * 128) * 64;
    const unsigned short* gB = Rb + (size_t)n * KLEN * DH + (size_t)(nj * 128) * 64;
#pragma unroll
    for (int s = 0; s < 4; ++s) {
        int g = tid + s * 256, row = g >> 3;
        gload16(gA + (size_t)row * 64 + ((g & 7) ^ (row & 7)) * 8, lA + g * 8);
        gload16(gB + (size_t)row * 64 + ((g & 7) ^ (row & 7)) * 8, lB + g * 8);
    }
    __syncthreads();
    f32x4 acc[4][4] = {};
#pragma unroll
    for (int kk = 0; kk < 2; ++kk) {
        bf16x8 af[4], bfr[4];
#pragma unroll
        for (int f = 0; f < 4; ++f) {
            af[f]  = lds_read8_sw(lA, wr + f * 16 + lane15, kk * 64 + lh * 16);
            bfr[f] = lds_read8_sw(lB, wc + f * 16 + lane15, kk * 64 + lh * 16);
        }
#pragma unroll
        for (int mi = 0; mi < 4; ++mi)
#pragma unroll
            for (int ni = 0; ni < 4; ++ni)
                acc[mi][ni] = __builtin_amdgcn_mfma_f32_16x16x32_bf16(
                    af[mi], bfr[ni], acc[mi][ni], 0, 0, 0);
    }
    unsigned short* out = BDs + (size_t)bn * 512 * BDLD;
#pragma unroll
    for (int mi = 0; mi < 4; ++mi) {
        int rowb = mi_ * 128 + wr + mi * 16 + lh * 4;
#pragma unroll
        for (int ni = 0; ni < 4; ++ni) {
            int col = nj * 128 + wc + ni * 16 + lane15;
#pragma unroll
            for (int r = 0; r < 4; ++r)
                out[(size_t)(rowb + r) * BDLD + col] = f2bf(acc[mi][ni][r] * 0.125f);
        }
    }
}

// ---------------------------------------------------------------------------
// Positional embedding table (1024 x 1024), bf16
// ---------------------------------------------------------------------------
__global__ __launch_bounds__(256)
void pos_kernel(unsigned short* __restrict__ posbf) {
    const int p = blockIdx.x, tid = threadIdx.x;
    const float ps = (float)(KLEN - 1 - p);
    const float c = -2.0f * 9.210340371976184f / 1024.0f; // -2*ln(10000)/D
#pragma unroll
    for (int j4 = 0; j4 < 4; ++j4) {
        int j = tid + j4 * 256;
        int m = (j < 512) ? j : j - 512;
        float freq = __expf((float)m * c);
        float ang = ps * freq;
        float v = (j < 512) ? sinf(ang) : cosf(ang);
        posbf[(size_t)p * DM + j] = f2bf(v);
    }
}

// ---------------------------------------------------------------------------
// mems[l] rows -> bf16 catb rows [0,2048)
// ---------------------------------------------------------------------------
__global__ __launch_bounds__(256)
void mems_cat(const float* __restrict__ mem_l, unsigned short* __restrict__ catbf) {
    const int t = blockIdx.x, tid = threadIdx.x;
    float4 v = ((const float4*)(mem_l + (size_t)t * DM))[tid];
    uint2 o;
    o.x = (unsigned)f2bf(v.x) | ((unsigned)f2bf(v.y) << 16);
    o.y = (unsigned)f2bf(v.z) | ((unsigned)f2bf(v.w) << 16);
    ((uint2*)(catbf + (size_t)t * DM))[tid] = o;
}

// ---------------------------------------------------------------------------
// Split-j-chunk rel-attention, stage 1 (R11/R13 structure).
// ---------------------------------------------------------------------------
__global__ __launch_bounds__(64)
void attn_part(const unsigned short* __restrict__ Qw,
               const unsigned short* __restrict__ Kb, const unsigned short* __restrict__ VTb,
               const unsigned short* __restrict__ BDs,
               unsigned short* __restrict__ Opart, float* __restrict__ ms) {
    __shared__ unsigned short lP[16 * 64];

    const int l = threadIdx.x;
    const int lane15 = l & 15, lh = l >> 4;
    const int blk = blockIdx.x;
    const int bn = blk & 63;          // head-local XCD
    const int rest = blk >> 6;        // 0..143
    const int rg = rest & 3;          // 16-row group within the 64-row i-tile
    const int c = rest >> 2;          // 0..35 chunk unit

    const int offt[8] = {0, 3, 7, 11, 15, 20, 25, 30};
    const int nctt[8] = {3, 4, 4, 4, 5, 5, 5, 6};
    int it = 0;
#pragma unroll
    for (int i = 1; i < 8; ++i) if (c >= offt[i]) it = i;
    const int cl = c - offt[it];
    const int nck = nctt[it];
    const int ntiles = it + 9;
    const int jt0 = (cl * ntiles) / nck;
    const int jt1 = ((cl + 1) * ntiles) / nck;
    const int i0 = it * 64;
    const int rowl = rg * 16 + lh * 4;

    bf16x8 qw[2];
    {
        size_t qb = ((size_t)bn * QLEN + i0 + rg * 16 + lane15) * DH + lh * 8;
        qw[0] = *(const bf16x8*)(Qw + qb);
        qw[1] = *(const bf16x8*)(Qw + qb + 32);
    }
    bf16x8 onesb;
#pragma unroll
    for (int j = 0; j < 8; ++j) onesb[j] = (short)0x3F80;   // bf16 1.0

    const unsigned short* kp = Kb + (size_t)bn * KLEN * DH + (size_t)(jt0 * 64 + lane15) * DH + lh * 8;
    const unsigned short* vp = VTb + (size_t)bn * DH * KLEN + (size_t)lane15 * KLEN + jt0 * 64 + lh * 8;
    const unsigned short* bdp[4];
#pragma unroll
    for (int r = 0; r < 4; ++r) {
        int row = i0 + rowl + r;                       // absolute i (<= 511)
        bdp[r] = BDs + (size_t)bn * 512 * BDLD + (size_t)row * BDLD
                 + (511 - row) + jt0 * 64 + lane15;    // col k = 511 + j - i
    }

    f32x4 oacc[4] = {};
    f32x4 srowv = {};   // row sums via ones-MFMA

    for (int jt = jt0; jt < jt1; ++jt) {
        float bdv[4][4];
#pragma unroll
        for (int f = 0; f < 4; ++f)
#pragma unroll
            for (int r = 0; r < 4; ++r)
                bdv[f][r] = bf2f(bdp[r][16 * f]);

        bf16x8 kf[2][4];
#pragma unroll
        for (int f = 0; f < 4; ++f) {
            const unsigned short* p = kp + (size_t)(f * 16) * DH;
            kf[0][f] = *(const bf16x8*)p;
            kf[1][f] = *(const bf16x8*)(p + 32);
        }

        f32x4 sac[4] = {};
        __builtin_amdgcn_s_setprio(1);
#pragma unroll
        for (int kk = 0; kk < 2; ++kk)
#pragma unroll
            for (int f = 0; f < 4; ++f)
                sac[f] = __builtin_amdgcn_mfma_f32_16x16x32_bf16(qw[kk], kf[kk][f], sac[f], 0, 0, 0);
        __builtin_amdgcn_s_setprio(0);

        bf16x8 vf[2][4];
#pragma unroll
        for (int kk = 0; kk < 2; ++kk)
#pragma unroll
            for (int f = 0; f < 4; ++f)
                vf[kk][f] = *(const bf16x8*)(vp + (size_t)(f * 16) * KLEN + kk * 32);

        const bool lastTile = (jt == it + 8);
        float pv[4][4];
#pragma unroll
        for (int f = 0; f < 4; ++f) {
            int lj = lane15 + 16 * f;
#pragma unroll
            for (int r = 0; r < 4; ++r) {
                float s = sac[f][r] + bdv[f][r];
                if (lastTile && (lj > rowl + r)) s = -1e30f;
                pv[f][r] = __expf(s - 8.f);
            }
        }

#pragma unroll
        for (int f = 0; f < 4; ++f)
#pragma unroll
            for (int r = 0; r < 4; ++r) {
                int row = lh * 4 + r, cb2 = (lane15 + 16 * f) * 2;
                *(unsigned short*)((char*)lP + row * 128 + (cb2 ^ ((row & 7) << 4))) =
                    f2bf(pv[f][r]);
            }
        bf16x8 pa[2];
        pa[0] = lds_read8_sw(lP, lane15, lh * 16);
        pa[1] = lds_read8_sw(lP, lane15, 64 + lh * 16);

        __builtin_amdgcn_s_setprio(1);
#pragma unroll
        for (int kk = 0; kk < 2; ++kk) {
#pragma unroll
            for (int f = 0; f < 4; ++f)
                oacc[f] = __builtin_amdgcn_mfma_f32_16x16x32_bf16(pa[kk], vf[kk][f], oacc[f], 0, 0, 0);
            srowv = __builtin_amdgcn_mfma_f32_16x16x32_bf16(pa[kk], onesb, srowv, 0, 0, 0);
        }
        __builtin_amdgcn_s_setprio(0);

        kp += 64 * DH;
        vp += 64;
#pragma unroll
        for (int r = 0; r < 4; ++r) bdp[r] += 64;
    }

    const int slot = (bn * 8 + it) * 6 + cl;
    unsigned short* Op = Opart + (size_t)slot * 4096;
#pragma unroll
    for (int f = 0; f < 4; ++f)
#pragma unroll
        for (int r = 0; r < 4; ++r)
            Op[(rowl + r) * 64 + lane15 + 16 * f] = f2bf(oacc[f][r]);
    if (lane15 == 0) {
        float* msp = ms + (size_t)slot * 64;
#pragma unroll
        for (int r = 0; r < 4; ++r) msp[rowl + r] = srowv[r];
    }
}

// ---------------------------------------------------------------------------
// Split-j merge: block = (head, i-tile); sums <=6 partials per row.
// ---------------------------------------------------------------------------
__global__ __launch_bounds__(256)
void attn_merge(const unsigned short* __restrict__ Opart, const float* __restrict__ ms,
                unsigned short* __restrict__ avec) {
    const int blk = blockIdx.x;          // 512
    const int bn = blk & 63, it = blk >> 6;
    const int n = bn & 15, b = bn >> 4;
    const int nctt[8] = {3, 4, 4, 4, 5, 5, 5, 6};
    const int k = nctt[it];
    const int tid = threadIdx.x;
    const int r = tid >> 2, cq = (tid & 3) * 16;
    const int base_slot = (bn * 8 + it) * 6;

    float S = 0.f;
    for (int c = 0; c < k; ++c) S += ms[(size_t)(base_slot + c) * 64 + r];

    float acc[16];
#pragma unroll
    for (int j = 0; j < 16; ++j) acc[j] = 0.f;
    for (int c = 0; c < k; ++c) {
        const bf16x8* op = (const bf16x8*)(Opart + (size_t)(base_slot + c) * 4096 + r * 64 + cq);
        bf16x8 v0 = op[0], v1 = op[1];
#pragma unroll
        for (int j = 0; j < 8; ++j) {
            acc[j]     += bf2f((unsigned short)v0[j]);
            acc[8 + j] += bf2f((unsigned short)v1[j]);
        }
    }
    float inv = 1.0f / S;
    int t = (it * 64 + r) * 4 + b;
    unsigned short* dst = avec + (size_t)t * DM + n * 64 + cq;
#pragma unroll
    for (int j = 0; j < 16; ++j) dst[j] = f2bf(acc[j] * inv);
}

// ---------------------------------------------------------------------------
// LayerNorm with fused split-K reduce: h = LN(hin + res0 + res1 [+ bias2])
// ---------------------------------------------------------------------------
__global__ __launch_bounds__(256)
void ln_kernel(const float* __restrict__ hin, const float* __restrict__ res0,
               const float* __restrict__ res1, const float* __restrict__ bias2,
               const float* __restrict__ g, const float* __restrict__ bb,
               float* __restrict__ hout, unsigned short* __restrict__ hbf) {
    __shared__ float ls[8];
    const int t = blockIdx.x, tid = threadIdx.x;
    float4 x = ((const float4*)(hin + (size_t)t * DM))[tid];
    float4 r0 = ((const float4*)(res0 + (size_t)t * DM))[tid];
    float4 r1 = ((const float4*)(res1 + (size_t)t * DM))[tid];
    float v0 = x.x + r0.x + r1.x, v1 = x.y + r0.y + r1.y;
    float v2 = x.z + r0.z + r1.z, v3 = x.w + r0.w + r1.w;
    if (bias2) {
        float4 b2 = ((const float4*)bias2)[tid];
        v0 += b2.x; v1 += b2.y; v2 += b2.z; v3 += b2.w;
    }
    float s = v0 + v1 + v2 + v3;
    float sq = v0 * v0 + v1 * v1 + v2 * v2 + v3 * v3;
#pragma unroll
    for (int off = 1; off < 64; off <<= 1) {
        s += __shfl_xor(s, off);
        sq += __shfl_xor(sq, off);
    }
    const int w = tid >> 6;
    if ((tid & 63) == 0) { ls[w] = s; ls[4 + w] = sq; }
    __syncthreads();
    s = ls[0] + ls[1] + ls[2] + ls[3];
    sq = ls[4] + ls[5] + ls[6] + ls[7];
    float mu = s * (1.f / 1024.f);
    float var = sq * (1.f / 1024.f) - mu * mu;
    float rstd = rsqrtf(var + 1e-5f);
    float y[4] = {v0, v1, v2, v3};
    float4 of;
    uint2 ob;
    float* op = &of.x;
#pragma unroll
    for (int j = 0; j < 4; ++j) {
        int d = tid * 4 + j;
        op[j] = (y[j] - mu) * rstd * g[d] + bb[d];
    }
    ob.x = (unsigned)f2bf(of.x) | ((unsigned)f2bf(of.y) << 16);
    ob.y = (unsigned)f2bf(of.z) | ((unsigned)f2bf(of.w) << 16);
    ((float4*)(hout + (size_t)t * DM))[tid] = of;
    ((uint2*)(hbf + (size_t)t * DM))[tid] = ob;
}

__global__ __launch_bounds__(256)
void out_kernel(const float* __restrict__ h, float* __restrict__ out) {
    const int t = blockIdx.x, tid = threadIdx.x;
    const int i = t >> 2, b = t & 3;
    ((float4*)(out + ((size_t)b * QLEN + i) * DM))[tid] =
        ((const float4*)(h + (size_t)t * DM))[tid];
}

// ---------------------------------------------------------------------------
extern "C" void kernel_launch(void* const* d_in, const int* in_sizes, int n_in,
                              void* d_out, int out_size, void* d_ws, size_t ws_size,
                              hipStream_t stream) {
    const int* ids = (const int*)d_in[0];
    const float* mems = (const float*)d_in[1];
    const float* embp[4] = {nullptr, nullptr, nullptr, nullptr};
    const float* projp[4] = {nullptr, nullptr, nullptr, nullptr};
    const long long esz[4] = {20000LL * 1024, 20000LL * 256, 160000LL * 64, 67735LL * 16};
    const long long psz[4] = {1024LL * 1024, 256LL * 1024, 64LL * 1024, 16LL * 1024};
    for (int idx = 2; idx <= 9 && idx < n_in; ++idx) {
        long long s = in_sizes[idx];
        for (int c = 0; c < 4; ++c) {
            if (s == esz[c]) embp[c] = (const float*)d_in[idx];
            else if (s == psz[c]) projp[c] = (const float*)d_in[idx];
        }
    }
    const float* qkvW = (const float*)d_in[10];
    const float* rW   = (const float*)d_in[11];
    const float* oW   = (const float*)d_in[12];
    const float* rwb  = (const float*)d_in[13];
    const float* rrb  = (const float*)d_in[14];
    const float* ln1g = (const float*)d_in[15];
    const float* ln1b = (const float*)d_in[16];
    const float* ffw1 = (const float*)d_in[17];
    const float* ffb1 = (const float*)d_in[18];
    const float* ffw2 = (const float*)d_in[19];
    const float* ffb2 = (const float*)d_in[20];
    const float* ln2g = (const float*)d_in[21];
    const float* ln2b = (const float*)d_in[22];

    size_t off = 0;
    char* base = (char*)d_ws;
    auto alloc = [&](size_t bytes) -> char* {
        char* p = base + off;
        off = (off + bytes + 255) & ~(size_t)255;
        return p;
    };
    unsigned short* qkvT  = (unsigned short*)alloc(3072ull * 1024 * 2);
    unsigned short* rT    = (unsigned short*)alloc(1024ull * 1024 * 2);
    unsigned short* oT    = (unsigned short*)alloc(1024ull * 1024 * 2);
    unsigned short* w1T   = (unsigned short*)alloc(4096ull * 1024 * 2);
    unsigned short* w2T   = (unsigned short*)alloc(1024ull * 4096 * 2);
    unsigned short* embA  = (unsigned short*)alloc(2048ull * EK * 2);
    unsigned short* embBT = (unsigned short*)alloc(1024ull * EK * 2);
    float* h              = (float*)alloc(2048ull * 1024 * 4);
    unsigned short* hbf   = (unsigned short*)alloc(2048ull * 1024 * 2);
    unsigned short* catb  = (unsigned short*)alloc(4096ull * 1024 * 2);
    unsigned short* posb  = (unsigned short*)alloc(1024ull * 1024 * 2);
    unsigned short* Qw    = (unsigned short*)alloc(4ull * 16 * 512 * 64 * 2);
    unsigned short* Qr    = (unsigned short*)alloc(4ull * 16 * 512 * 64 * 2);
    unsigned short* Kb    = (unsigned short*)alloc(4ull * 16 * 1024 * 64 * 2);
    unsigned short* VTb   = (unsigned short*)alloc(4ull * 16 * 1024 * 64 * 2);
    unsigned short* Rb    = (unsigned short*)alloc(16ull * 1024 * 64 * 2);
    unsigned short* avec  = (unsigned short*)alloc(2048ull * 1024 * 2);
    float* resid01        = (float*)alloc(2ull * 2048 * 1024 * 4);        // 16 MB
    unsigned short* ff1b  = (unsigned short*)alloc(2048ull * 4096 * 2);
    unsigned short* Opart = (unsigned short*)alloc(3072ull * 4096 * 2);   // 24 MB
    float* msbuf          = (float*)alloc(3072ull * 64 * 4);              // 0.75 MB
    unsigned short* BDs   = (unsigned short*)alloc(64ull * 512 * BDLD * 2); // 75.5 MB
    (void)ws_size; (void)out_size;

    unsigned short* catbHi = catb + 2048ull * 1024;   // h-half of cat (bf16)
    float* resid1 = resid01 + 2048ull * 1024;

    // ---- embeddings (gather + GEMM) + positional table ----
    emb_gather<<<(2048 * 176 + 255) / 256, 256, 0, stream>>>(
        ids, embp[0], embp[1], embp[2], embp[3], embA);
    transpose_pad<<<dim3(32, 32), 256, 0, stream>>>(projp[0], embBT, 1024, 1024, EK, 0);
    transpose_pad<<<dim3(32, 8),  256, 0, stream>>>(projp[1], embBT, 256,  1024, EK, 1024);
    transpose_pad<<<dim3(32, 2),  256, 0, stream>>>(projp[2], embBT, 64,   1024, EK, 1280);
    transpose_pad<<<dim3(32, 2),  256, 0, stream>>>(projp[3], embBT, 16,   1024, EK, 1344);
    pos_kernel<<<1024, 256, 0, stream>>>(posb);
    gemm_bt<5, 128><<<(2048 / 128) * (1024 / 128), 256, 0, stream>>>(
        embA, embBT, h, catbHi, nullptr, 2048, 1024, EK);

    for (int l = 0; l < N_LAYER; ++l) {
        const float* qkvWl = qkvW + (size_t)l * 1024 * 3072;
        const float* rWl   = rW + (size_t)l * 1024 * 1024;
        const float* oWl   = oW + (size_t)l * 1024 * 1024;
        const float* w1l   = ffw1 + (size_t)l * 1024 * 4096;
        const float* w2l   = ffw2 + (size_t)l * 4096 * 1024;

        transpose_all<<<3328, 256, 0, stream>>>(qkvWl, rWl, oWl, w1l, w2l,
                                                qkvT, rT, oT, w1T, w2T);

        mems_cat<<<2048, 256, 0, stream>>>(mems + (size_t)l * 2048 * 1024, catb);

        qkv_rk_gemm<<<1408, 256, 0, stream>>>(catb, posb, qkvT, rT,
                                              rwb + l * 1024, rrb + l * 1024,
                                              Qw, Qr, Kb, VTb, Rb);

        bd_gemm<<<64 * 26, 256, 0, stream>>>(Qr, Rb, BDs);

        attn_part<<<64 * 144, 64, 0, stream>>>(Qw, Kb, VTb, BDs, Opart, msbuf);
        attn_merge<<<512, 256, 0, stream>>>(Opart, msbuf, avec);

        gemm_sk<64><<<2 * (2048 / 128) * (1024 / 64), 256, 0, stream>>>(
            avec, oT, resid01, 2048, 1024, 1024);
        ln_kernel<<<2048, 256, 0, stream>>>(h, resid01, resid1, nullptr,
                                            ln1g + l * 1024, ln1b + l * 1024, h, hbf);

        gemm_bt<1, 64><<<(2048 / 128) * (4096 / 64), 256, 0, stream>>>(
            hbf, w1T, nullptr, ff1b, ffb1 + l * 4096, 2048, 4096, 1024);

        gemm_sk<64><<<2 * (2048 / 128) * (1024 / 64), 256, 0, stream>>>(
            ff1b, w2T, resid01, 2048, 1024, 4096);
        ln_kernel<<<2048, 256, 0, stream>>>(h, resid01, resid1, ffb2 + l * 1024,
                                            ln2g + l * 1024, ln2b + l * 1024, h,
                                            (l < 3) ? catbHi : hbf);
    }

    out_kernel<<<2048, 256, 0, stream>>>(h, (float*)d_out);
}

// Round 17
// 966.848 us; speedup vs baseline: 1.1809x; 1.0032x over previous
//
#include <hip/hip_runtime.h>

typedef __attribute__((ext_vector_type(8))) short bf16x8;
typedef __attribute__((ext_vector_type(4))) float f32x4;

#define N_LAYER 4
#define QLEN 512
#define MLEN 512
#define KLEN 1024
#define BSZ 4
#define DM 1024
#define NH 16
#define DH 64
#define DINNER 4096
#define EK 1408
#define BDLD 1152  // BDs row stride (1024 + 128 pad; pad cols never written, always masked)

__device__ __forceinline__ unsigned short f2bf(float x) {
    unsigned u = __float_as_uint(x);
    u += 0x7fffu + ((u >> 16) & 1u);
    return (unsigned short)(u >> 16);
}
__device__ __forceinline__ float bf2f(unsigned short v) {
    return __uint_as_float(((unsigned)v) << 16);
}

__device__ __forceinline__ void gload16(const unsigned short* g, unsigned short* l) {
    __builtin_amdgcn_global_load_lds(
        (const __attribute__((address_space(1))) unsigned int*)g,
        (__attribute__((address_space(3))) unsigned int*)l, 16, 0, 0);
}

// swizzled b128 LDS read for 128B-row-stride bf16 tiles: byte ^= (row&7)<<4
__device__ __forceinline__ bf16x8 lds_read8_sw(const unsigned short* base, int row, int cb) {
    return *(const bf16x8*)((const char*)base + row * 128 + (cb ^ ((row & 7) << 4)));
}

// ---------------------------------------------------------------------------
// Per-layer prep in ONE launch: 5 weight transposes (blocks [0,3328)) +
// mems->bf16 cat rows (blocks [3328,5376)).
// ---------------------------------------------------------------------------
__global__ __launch_bounds__(256)
void prep_all(const float* __restrict__ qkvWl, const float* __restrict__ rWl,
              const float* __restrict__ oWl, const float* __restrict__ w1l,
              const float* __restrict__ w2l,
              unsigned short* __restrict__ qkvT, unsigned short* __restrict__ rT,
              unsigned short* __restrict__ oT, unsigned short* __restrict__ w1T,
              unsigned short* __restrict__ w2T,
              const float* __restrict__ mem_l, unsigned short* __restrict__ catbf) {
    const int tid = threadIdx.x;
    int id = blockIdx.x;
    if (id >= 3328) {   // mems_cat part
        const int t = id - 3328;
        float4 v = ((const float4*)(mem_l + (size_t)t * DM))[tid];
        uint2 o;
        o.x = (unsigned)f2bf(v.x) | ((unsigned)f2bf(v.y) << 16);
        o.y = (unsigned)f2bf(v.z) | ((unsigned)f2bf(v.w) << 16);
        ((uint2*)(catbf + (size_t)t * DM))[tid] = o;
        return;
    }
    __shared__ float tile[64][65];
    const float* W; unsigned short* D; int K, N, bx, by;
    if (id < 768)       { W = qkvWl; D = qkvT; K = 1024; N = 3072; bx = id % 48; by = id / 48; }
    else if (id < 1024) { id -= 768;  W = rWl;  D = rT;  K = 1024; N = 1024; bx = id & 15; by = id >> 4; }
    else if (id < 1280) { id -= 1024; W = oWl;  D = oT;  K = 1024; N = 1024; bx = id & 15; by = id >> 4; }
    else if (id < 2304) { id -= 1280; W = w1l;  D = w1T; K = 1024; N = 4096; bx = id & 63; by = id >> 6; }
    else                { id -= 2304; W = w2l;  D = w2T; K = 4096; N = 1024; bx = id & 15; by = id >> 4; }
#pragma unroll
    for (int s = 0; s < 4; ++s) {
        int idx = s * 256 + tid;
        int kr = idx >> 4, c4 = (idx & 15) * 4;
        float4 v = *(const float4*)(W + (size_t)(by * 64 + kr) * N + bx * 64 + c4);
        tile[kr][c4] = v.x; tile[kr][c4 + 1] = v.y;
        tile[kr][c4 + 2] = v.z; tile[kr][c4 + 3] = v.w;
    }
    __syncthreads();
#pragma unroll
    for (int s = 0; s < 2; ++s) {
        int idx = s * 256 + tid;
        int nl = idx >> 3, k8 = (idx & 7) * 8;
        unsigned short tmp[8];
#pragma unroll
        for (int j = 0; j < 8; ++j) tmp[j] = f2bf(tile[k8 + j][nl]);
        *(uint4*)(D + (size_t)(bx * 64 + nl) * K + by * 64 + k8) = *(uint4*)tmp;
    }
}

// Transpose with zero-padding beyond K rows, into a slice of a wider dst row.
__global__ __launch_bounds__(256)
void transpose_pad(const float* __restrict__ W, unsigned short* __restrict__ dst,
                   int K, int N, int dstLD, int dstOff) {
    __shared__ float tile[32][33];
    const int tx = threadIdx.x & 31, ty = threadIdx.x >> 5;
    const int bx = blockIdx.x, by = blockIdx.y;
#pragma unroll
    for (int i = 0; i < 4; ++i) {
        int k = by * 32 + ty + i * 8;
        tile[ty + i * 8][tx] = (k < K) ? W[(size_t)k * N + bx * 32 + tx] : 0.f;
    }
    __syncthreads();
#pragma unroll
    for (int i = 0; i < 4; ++i) {
        int n = bx * 32 + ty + i * 8;
        int k = by * 32 + tx;
        dst[(size_t)n * dstLD + dstOff + k] = f2bf(tile[tx][ty + i * 8]);
    }
}

// ---------------------------------------------------------------------------
// Adaptive-embedding gather: embA[t][0:1408) = masked cluster row * 32, bf16
// ---------------------------------------------------------------------------
__global__ __launch_bounds__(256)
void emb_gather(const int* __restrict__ ids,
                const float* __restrict__ e0, const float* __restrict__ e1,
                const float* __restrict__ e2, const float* __restrict__ e3,
                unsigned short* __restrict__ embA) {
    const int chunk = blockIdx.x * 256 + threadIdx.x;
    if (chunk >= 2048 * 176) return;
    const int t = chunk / 176;
    const int e8 = (chunk - t * 176) * 8;
    const int i = t >> 2, b = t & 3;
    const int id = ids[b * QLEN + i];
    const float* src = nullptr;
    if (e8 < 1024) {
        if (id < 20000) src = e0 + (size_t)id * 1024 + e8;
    } else if (e8 < 1280) {
        if (id >= 20000 && id < 40000) src = e1 + (size_t)(id - 20000) * 256 + (e8 - 1024);
    } else if (e8 < 1344) {
        if (id >= 40000 && id < 200000) src = e2 + (size_t)(id - 40000) * 64 + (e8 - 1280);
    } else if (e8 < 1360) {
        if (id >= 200000) src = e3 + (size_t)(id - 200000) * 16 + (e8 - 1344);
    }
    uint4 o = {0u, 0u, 0u, 0u};
    if (src) {
        float4 v0 = *(const float4*)src;
        float4 v1 = *(const float4*)(src + 4);
        o.x = (unsigned)f2bf(v0.x * 32.f) | ((unsigned)f2bf(v0.y * 32.f) << 16);
        o.y = (unsigned)f2bf(v0.z * 32.f) | ((unsigned)f2bf(v0.w * 32.f) << 16);
        o.z = (unsigned)f2bf(v1.x * 32.f) | ((unsigned)f2bf(v1.y * 32.f) << 16);
        o.w = (unsigned)f2bf(v1.z * 32.f) | ((unsigned)f2bf(v1.w * 32.f) << 16);
    }
    *(uint4*)(embA + (size_t)t * EK + e8) = o;
}

// ---------------------------------------------------------------------------
// Generic GEMM (BK=64 dbuf, T2 swizzle, XCD swizzle).
// MODE 0: f32. 1: bf16(relu(+bias)). 2: f32+bias. 5: f32 + bf16 dual.
// ---------------------------------------------------------------------------
template <int MODE, int BN>
__global__ __launch_bounds__(256)
void gemm_bt(const unsigned short* __restrict__ A, const unsigned short* __restrict__ BT,
             float* __restrict__ C, unsigned short* __restrict__ Cbf,
             const float* __restrict__ bias, int M, int N, int K) {
    constexpr int NF = BN / 32;
    __shared__ unsigned short lA[2][128 * 64];
    __shared__ unsigned short lB[2][BN * 64];
    const int tid = threadIdx.x;
    const int w = tid >> 6, l = tid & 63;
    const int lane15 = l & 15, lh = l >> 4;
    const int nwg = gridDim.x;
    const int cpx = nwg >> 3;
    const int swz = (blockIdx.x & 7) * cpx + (blockIdx.x >> 3);
    const int nbn = N / BN;
    const int bm = swz / nbn, bn = swz % nbn;
    const int wr = (w >> 1) * 64, wc = (w & 1) * (BN / 2);

    f32x4 acc[4][NF] = {};

    const unsigned short* gA = A + (size_t)(bm * 128) * K;
    const unsigned short* gB = BT + (size_t)(bn * BN) * K;

    auto stage = [&](int buf, int k0) {
#pragma unroll
        for (int s = 0; s < 4; ++s) {
            int g = tid + s * 256, row = g >> 3;
            gload16(gA + (size_t)row * K + k0 + ((g & 7) ^ (row & 7)) * 8,
                    lA[buf] + g * 8);
        }
#pragma unroll
        for (int s = 0; s < BN / 32; ++s) {
            int g = tid + s * 256, row = g >> 3;
            gload16(gB + (size_t)row * K + k0 + ((g & 7) ^ (row & 7)) * 8,
                    lB[buf] + g * 8);
        }
    };

    stage(0, 0);
    __syncthreads();
    int cur = 0;
    for (int k0 = 0; k0 < K; k0 += 64) {
        if (k0 + 64 < K) stage(cur ^ 1, k0 + 64);
        const unsigned short* cA = lA[cur];
        const unsigned short* cB = lB[cur];
#pragma unroll
        for (int kk = 0; kk < 2; ++kk) {
            bf16x8 af[4], bfr[NF];
#pragma unroll
            for (int f = 0; f < 4; ++f)
                af[f] = lds_read8_sw(cA, wr + f * 16 + lane15, kk * 64 + lh * 16);
#pragma unroll
            for (int f = 0; f < NF; ++f)
                bfr[f] = lds_read8_sw(cB, wc + f * 16 + lane15, kk * 64 + lh * 16);
#pragma unroll
            for (int mi = 0; mi < 4; ++mi)
#pragma unroll
                for (int ni = 0; ni < NF; ++ni)
                    acc[mi][ni] = __builtin_amdgcn_mfma_f32_16x16x32_bf16(
                        af[mi], bfr[ni], acc[mi][ni], 0, 0, 0);
        }
        __syncthreads();
        cur ^= 1;
    }

#pragma unroll
    for (int mi = 0; mi < 4; ++mi) {
        int rowb = bm * 128 + wr + mi * 16 + lh * 4;
#pragma unroll
        for (int ni = 0; ni < NF; ++ni) {
            int col = bn * BN + wc + ni * 16 + lane15;
#pragma unroll
            for (int r = 0; r < 4; ++r) {
                float x = acc[mi][ni][r];
                if (MODE == 0) {
                    C[(size_t)(rowb + r) * N + col] = x;
                } else if (MODE == 1) {
                    x += bias[col];
                    Cbf[(size_t)(rowb + r) * N + col] = f2bf(x > 0.f ? x : 0.f);
                } else if (MODE == 2) {
                    C[(size_t)(rowb + r) * N + col] = x + bias[col];
                } else { // MODE 5
                    C[(size_t)(rowb + r) * N + col] = x;
                    Cbf[(size_t)(rowb + r) * N + col] = f2bf(x);
                }
            }
        }
    }
}

// ---------------------------------------------------------------------------
// Split-K=2 GEMM (one launch, 2x blocks); reduce fused into the LN kernels.
// ---------------------------------------------------------------------------
template <int BN>
__global__ __launch_bounds__(256)
void gemm_sk(const unsigned short* __restrict__ A, const unsigned short* __restrict__ BT,
             float* __restrict__ C01, int M, int N, int K) {
    constexpr int NF = BN / 32;
    __shared__ unsigned short lA[2][128 * 64];
    __shared__ unsigned short lB[2][BN * 64];
    const int tid = threadIdx.x;
    const int w = tid >> 6, l = tid & 63;
    const int lane15 = l & 15, lh = l >> 4;
    const int nwg = gridDim.x;
    const int cpx = nwg >> 3;
    const int swz = (blockIdx.x & 7) * cpx + (blockIdx.x >> 3);
    const int nbn = N / BN;
    const int nhalf = (M / 128) * nbn;
    const int half = swz / nhalf;
    const int rem = swz % nhalf;
    const int bm = rem / nbn, bn = rem % nbn;
    const int KH = K >> 1;
    const int koff = half * KH;
    const int wr = (w >> 1) * 64, wc = (w & 1) * (BN / 2);

    f32x4 acc[4][NF] = {};

    const unsigned short* gA = A + (size_t)(bm * 128) * K + koff;
    const unsigned short* gB = BT + (size_t)(bn * BN) * K + koff;

    auto stage = [&](int buf, int k0) {
#pragma unroll
        for (int s = 0; s < 4; ++s) {
            int g = tid + s * 256, row = g >> 3;
            gload16(gA + (size_t)row * K + k0 + ((g & 7) ^ (row & 7)) * 8,
                    lA[buf] + g * 8);
        }
#pragma unroll
        for (int s = 0; s < BN / 32; ++s) {
            int g = tid + s * 256, row = g >> 3;
            gload16(gB + (size_t)row * K + k0 + ((g & 7) ^ (row & 7)) * 8,
                    lB[buf] + g * 8);
        }
    };

    stage(0, 0);
    __syncthreads();
    int cur = 0;
    for (int k0 = 0; k0 < KH; k0 += 64) {
        if (k0 + 64 < KH) stage(cur ^ 1, k0 + 64);
        const unsigned short* cA = lA[cur];
        const unsigned short* cB = lB[cur];
#pragma unroll
        for (int kk = 0; kk < 2; ++kk) {
            bf16x8 af[4], bfr[NF];
#pragma unroll
            for (int f = 0; f < 4; ++f)
                af[f] = lds_read8_sw(cA, wr + f * 16 + lane15, kk * 64 + lh * 16);
#pragma unroll
            for (int f = 0; f < NF; ++f)
                bfr[f] = lds_read8_sw(cB, wc + f * 16 + lane15, kk * 64 + lh * 16);
#pragma unroll
            for (int mi = 0; mi < 4; ++mi)
#pragma unroll
                for (int ni = 0; ni < NF; ++ni)
                    acc[mi][ni] = __builtin_amdgcn_mfma_f32_16x16x32_bf16(
                        af[mi], bfr[ni], acc[mi][ni], 0, 0, 0);
        }
        __syncthreads();
        cur ^= 1;
    }

    float* Cout = C01 + (size_t)half * M * N;
#pragma unroll
    for (int mi = 0; mi < 4; ++mi) {
        int rowb = bm * 128 + wr + mi * 16 + lh * 4;
#pragma unroll
        for (int ni = 0; ni < NF; ++ni) {
            int col = bn * BN + wc + ni * 16 + lane15;
#pragma unroll
            for (int r = 0; r < 4; ++r)
                Cout[(size_t)(rowb + r) * N + col] = acc[mi][ni][r];
        }
    }
}

// ---------------------------------------------------------------------------
// Combined QKV(KV) + QKV(Q live rows) + r_head_k GEMM, one launch, 128x64
// tiles. Grid 1408.
// ---------------------------------------------------------------------------
__global__ __launch_bounds__(256)
void qkv_rk_gemm(const unsigned short* __restrict__ catb, const unsigned short* __restrict__ posb,
                 const unsigned short* __restrict__ qkvT, const unsigned short* __restrict__ rT,
                 const float* __restrict__ rwb, const float* __restrict__ rrb,
                 unsigned short* __restrict__ Qw, unsigned short* __restrict__ Qr,
                 unsigned short* __restrict__ Kb, unsigned short* __restrict__ VTb,
                 unsigned short* __restrict__ Rb) {
    __shared__ unsigned short lA[2][128 * 64];
    __shared__ unsigned short lB[2][64 * 64];
    const int tid = threadIdx.x;
    const int w = tid >> 6, l = tid & 63;
    const int lane15 = l & 15, lh = l >> 4;
    const int cpx = gridDim.x >> 3;   // 176
    const int swz = (blockIdx.x & 7) * cpx + (blockIdx.x >> 3);
    const int wr = (w >> 1) * 64, wc = (w & 1) * 32;

    const unsigned short* gA;
    const unsigned short* gB;
    int part, bm, bn;
    if (swz < 1024)      { part = 0; bm = swz >> 5; bn = swz & 31;
                           gA = catb + (size_t)(bm * 128) * 1024;
                           gB = qkvT + (size_t)(1024 + bn * 64) * 1024; }
    else if (swz < 1280) { part = 1; int q = swz - 1024; bm = q >> 4; bn = q & 15;
                           gA = catb + (size_t)(2048 + bm * 128) * 1024;
                           gB = qkvT + (size_t)(bn * 64) * 1024; }
    else                 { part = 2; int q = swz - 1280; bm = q >> 4; bn = q & 15;
                           gA = posb + (size_t)(bm * 128) * 1024;
                           gB = rT + (size_t)(bn * 64) * 1024; }

    f32x4 acc[4][2] = {};
    auto stage = [&](int buf, int k0) {
#pragma unroll
        for (int s = 0; s < 4; ++s) {
            int g = tid + s * 256, row = g >> 3;
            gload16(gA + (size_t)row * 1024 + k0 + ((g & 7) ^ (row & 7)) * 8, lA[buf] + g * 8);
        }
#pragma unroll
        for (int s = 0; s < 2; ++s) {
            int g = tid + s * 256, row = g >> 3;
            gload16(gB + (size_t)row * 1024 + k0 + ((g & 7) ^ (row & 7)) * 8, lB[buf] + g * 8);
        }
    };
    stage(0, 0);
    __syncthreads();
    int cur = 0;
    for (int k0 = 0; k0 < 1024; k0 += 64) {
        if (k0 + 64 < 1024) stage(cur ^ 1, k0 + 64);
        const unsigned short* cA = lA[cur];
        const unsigned short* cB = lB[cur];
#pragma unroll
        for (int kk = 0; kk < 2; ++kk) {
            bf16x8 af[4], bfr[2];
#pragma unroll
            for (int f = 0; f < 4; ++f)
                af[f] = lds_read8_sw(cA, wr + f * 16 + lane15, kk * 64 + lh * 16);
#pragma unroll
            for (int f = 0; f < 2; ++f)
                bfr[f] = lds_read8_sw(cB, wc + f * 16 + lane15, kk * 64 + lh * 16);
#pragma unroll
            for (int mi = 0; mi < 4; ++mi)
#pragma unroll
                for (int ni = 0; ni < 2; ++ni)
                    acc[mi][ni] = __builtin_amdgcn_mfma_f32_16x16x32_bf16(
                        af[mi], bfr[ni], acc[mi][ni], 0, 0, 0);
        }
        __syncthreads();
        cur ^= 1;
    }

#pragma unroll
    for (int mi = 0; mi < 4; ++mi) {
        int rowb = bm * 128 + wr + mi * 16 + lh * 4;
#pragma unroll
        for (int ni = 0; ni < 2; ++ni) {
            int col = bn * 64 + wc + ni * 16 + lane15;
#pragma unroll
            for (int r = 0; r < 4; ++r) {
                float x = acc[mi][ni][r];
                if (part == 0) {           // KV scatter (all 4096 rows), N=2048
                    int j = rowb >> 2, bb_ = r;
                    if (col < 1024) {
                        int n = col >> 6, d = col & 63;
                        Kb[((size_t)(bb_ * NH + n) * KLEN + j) * DH + d] = f2bf(x);
                    } else {
                        int c2 = col - 1024, n = c2 >> 6, d = c2 & 63;
                        VTb[((size_t)(bb_ * NH + n) * DH + d) * KLEN + j] = f2bf(x);
                    }
                } else if (part == 1) {    // Q scatter (live rows), +biases, x1/8 into Qw
                    int i = rowb >> 2, bb_ = r;
                    int n = col >> 6, d = col & 63;
                    size_t o = ((size_t)(bb_ * NH + n) * QLEN + i) * DH + d;
                    Qw[o] = f2bf((x + rwb[col]) * 0.125f);
                    Qr[o] = f2bf(x + rrb[col]);
                } else {                   // RK scatter
                    int j = rowb + r;
                    int n = col >> 6, d = col & 63;
                    Rb[((size_t)n * KLEN + j) * DH + d] = f2bf(x);
                }
            }
        }
    }
}

// ---------------------------------------------------------------------------
// Batched BD GEMM (band-only): BDs[bn][i][k] = (Qr[i].Rb[k]) * 0.125
// ---------------------------------------------------------------------------
__global__ __launch_bounds__(256)
void bd_gemm(const unsigned short* __restrict__ Qr, const unsigned short* __restrict__ Rb,
             unsigned short* __restrict__ BDs) {
    __shared__ unsigned short lA[128 * 64];
    __shared__ unsigned short lB[128 * 64];
    const int tid = threadIdx.x;
    const int w = tid >> 6, l = tid & 63;
    const int lane15 = l & 15, lh = l >> 4;
    const int blk = blockIdx.x;
    const int bn = blk & 63;          // head-local XCD
    const int tile = blk >> 6;        // 0..25
    const int bd_mi[26] = {0,0,0,0,0, 1,1,1,1,1,1, 2,2,2,2,2,2,2, 3,3,3,3,3,3,3,3};
    const int bd_nj[26] = {3,4,5,6,7, 2,3,4,5,6,7, 1,2,3,4,5,6,7, 0,1,2,3,4,5,6,7};
    const int mi_ = bd_mi[tile], nj = bd_nj[tile];
    const int n = bn & 15;
    const int wr = (w >> 1) * 64, wc = (w & 1) * 64;

    const unsigned short* gA = Qr + (size_t)bn * QLEN * DH + (size_t)(mi_ * 128) * 64;
    const unsigned short* gB = Rb + (size_t)n * KLEN * DH + (size_t)(nj * 128) * 64;
#pragma unroll
    for (int s = 0; s < 4; ++s) {
        int g = tid + s * 256, row = g >> 3;
        gload16(gA + (size_t)row * 64 + ((g & 7) ^ (row & 7)) * 8, lA + g * 8);
        gload16(gB + (size_t)row * 64 + ((g & 7) ^ (row & 7)) * 8, lB + g * 8);
    }
    __syncthreads();
    f32x4 acc[4][4] = {};
#pragma unroll
    for (int kk = 0; kk < 2; ++kk) {
        bf16x8 af[4], bfr[4];
#pragma unroll
        for (int f = 0; f < 4; ++f) {
            af[f]  = lds_read8_sw(lA, wr + f * 16 + lane15, kk * 64 + lh * 16);
            bfr[f] = lds_read8_sw(lB, wc + f * 16 + lane15, kk * 64 + lh * 16);
        }
#pragma unroll
        for (int mi = 0; mi < 4; ++mi)
#pragma unroll
            for (int ni = 0; ni < 4; ++ni)
                acc[mi][ni] = __builtin_amdgcn_mfma_f32_16x16x32_bf16(
                    af[mi], bfr[ni], acc[mi][ni], 0, 0, 0);
    }
    unsigned short* out = BDs + (size_t)bn * 512 * BDLD;
#pragma unroll
    for (int mi = 0; mi < 4; ++mi) {
        int rowb = mi_ * 128 + wr + mi * 16 + lh * 4;
#pragma unroll
        for (int ni = 0; ni < 4; ++ni) {
            int col = nj * 128 + wc + ni * 16 + lane15;
#pragma unroll
            for (int r = 0; r < 4; ++r)
                out[(size_t)(rowb + r) * BDLD + col] = f2bf(acc[mi][ni][r] * 0.125f);
        }
    }
}

// ---------------------------------------------------------------------------
// Positional embedding table (1024 x 1024), bf16
// ---------------------------------------------------------------------------
__global__ __launch_bounds__(256)
void pos_kernel(unsigned short* __restrict__ posbf) {
    const int p = blockIdx.x, tid = threadIdx.x;
    const float ps = (float)(KLEN - 1 - p);
    const float c = -2.0f * 9.210340371976184f / 1024.0f; // -2*ln(10000)/D
#pragma unroll
    for (int j4 = 0; j4 < 4; ++j4) {
        int j = tid + j4 * 256;
        int m = (j < 512) ? j : j - 512;
        float freq = __expf((float)m * c);
        float ang = ps * freq;
        float v = (j < 512) ? sinf(ang) : cosf(ang);
        posbf[(size_t)p * DM + j] = f2bf(v);
    }
}

// ---------------------------------------------------------------------------
// Split-j-chunk rel-attention, stage 1. BD NEXT-TILE PREFETCH: only the 16
// BD u16s are double-buffered (+~16 VGPR), hiding the L3-latency chain head.
// ---------------------------------------------------------------------------
__global__ __launch_bounds__(64)
void attn_part(const unsigned short* __restrict__ Qw,
               const unsigned short* __restrict__ Kb, const unsigned short* __restrict__ VTb,
               const unsigned short* __restrict__ BDs,
               unsigned short* __restrict__ Opart, float* __restrict__ ms) {
    __shared__ unsigned short lP[16 * 64];

    const int l = threadIdx.x;
    const int lane15 = l & 15, lh = l >> 4;
    const int blk = blockIdx.x;
    const int bn = blk & 63;          // head-local XCD
    const int rest = blk >> 6;        // 0..143
    const int rg = rest & 3;          // 16-row group within the 64-row i-tile
    const int c = rest >> 2;          // 0..35 chunk unit

    const int offt[8] = {0, 3, 7, 11, 15, 20, 25, 30};
    const int nctt[8] = {3, 4, 4, 4, 5, 5, 5, 6};
    int it = 0;
#pragma unroll
    for (int i = 1; i < 8; ++i) if (c >= offt[i]) it = i;
    const int cl = c - offt[it];
    const int nck = nctt[it];
    const int ntiles = it + 9;
    const int jt0 = (cl * ntiles) / nck;
    const int jt1 = ((cl + 1) * ntiles) / nck;
    const int i0 = it * 64;
    const int rowl = rg * 16 + lh * 4;

    bf16x8 qw[2];
    {
        size_t qb = ((size_t)bn * QLEN + i0 + rg * 16 + lane15) * DH + lh * 8;
        qw[0] = *(const bf16x8*)(Qw + qb);
        qw[1] = *(const bf16x8*)(Qw + qb + 32);
    }
    bf16x8 onesb;
#pragma unroll
    for (int j = 0; j < 8; ++j) onesb[j] = (short)0x3F80;   // bf16 1.0

    const unsigned short* kp = Kb + (size_t)bn * KLEN * DH + (size_t)(jt0 * 64 + lane15) * DH + lh * 8;
    const unsigned short* vp = VTb + (size_t)bn * DH * KLEN + (size_t)lane15 * KLEN + jt0 * 64 + lh * 8;
    const unsigned short* bdp[4];
#pragma unroll
    for (int r = 0; r < 4; ++r) {
        int row = i0 + rowl + r;                       // absolute i (<= 511)
        bdp[r] = BDs + (size_t)bn * 512 * BDLD + (size_t)row * BDLD
                 + (511 - row) + jt0 * 64 + lane15;    // col k = 511 + j - i
    }

    f32x4 oacc[4] = {};
    f32x4 srowv = {};   // row sums via ones-MFMA

    unsigned short bdcur[16], bdnxt[16];
    auto loadBD = [&](int d, unsigned short (&dst)[16]) {
#pragma unroll
        for (int f = 0; f < 4; ++f)
#pragma unroll
            for (int r = 0; r < 4; ++r)
                dst[f * 4 + r] = bdp[r][d * 64 + 16 * f];
    };
    loadBD(0, bdcur);

    for (int jt = jt0; jt < jt1; ++jt) {
        const int d = jt - jt0;
        if (jt + 1 < jt1) loadBD(d + 1, bdnxt);   // prefetch: hides L3 latency

        bf16x8 kf[2][4];
#pragma unroll
        for (int f = 0; f < 4; ++f) {
            const unsigned short* p = kp + (size_t)(f * 16) * DH;
            kf[0][f] = *(const bf16x8*)p;
            kf[1][f] = *(const bf16x8*)(p + 32);
        }

        f32x4 sac[4] = {};
        __builtin_amdgcn_s_setprio(1);
#pragma unroll
        for (int kk = 0; kk < 2; ++kk)
#pragma unroll
            for (int f = 0; f < 4; ++f)
                sac[f] = __builtin_amdgcn_mfma_f32_16x16x32_bf16(qw[kk], kf[kk][f], sac[f], 0, 0, 0);
        __builtin_amdgcn_s_setprio(0);

        bf16x8 vf[2][4];
#pragma unroll
        for (int kk = 0; kk < 2; ++kk)
#pragma unroll
            for (int f = 0; f < 4; ++f)
                vf[kk][f] = *(const bf16x8*)(vp + (size_t)(f * 16) * KLEN + kk * 32);

        const bool lastTile = (jt == it + 8);
        float pv[4][4];
#pragma unroll
        for (int f = 0; f < 4; ++f) {
            int lj = lane15 + 16 * f;
#pragma unroll
            for (int r = 0; r < 4; ++r) {
                float s = sac[f][r] + bf2f(bdcur[f * 4 + r]);
                if (lastTile && (lj > rowl + r)) s = -1e30f;
                pv[f][r] = __expf(s - 8.f);
            }
        }

#pragma unroll
        for (int f = 0; f < 4; ++f)
#pragma unroll
            for (int r = 0; r < 4; ++r) {
                int row = lh * 4 + r, cb2 = (lane15 + 16 * f) * 2;
                *(unsigned short*)((char*)lP + row * 128 + (cb2 ^ ((row & 7) << 4))) =
                    f2bf(pv[f][r]);
            }
        bf16x8 pa[2];
        pa[0] = lds_read8_sw(lP, lane15, lh * 16);
        pa[1] = lds_read8_sw(lP, lane15, 64 + lh * 16);

        __builtin_amdgcn_s_setprio(1);
#pragma unroll
        for (int kk = 0; kk < 2; ++kk) {
#pragma unroll
            for (int f = 0; f < 4; ++f)
                oacc[f] = __builtin_amdgcn_mfma_f32_16x16x32_bf16(pa[kk], vf[kk][f], oacc[f], 0, 0, 0);
            srowv = __builtin_amdgcn_mfma_f32_16x16x32_bf16(pa[kk], onesb, srowv, 0, 0, 0);
        }
        __builtin_amdgcn_s_setprio(0);

        kp += 64 * DH;
        vp += 64;
#pragma unroll
        for (int q = 0; q < 16; ++q) bdcur[q] = bdnxt[q];   // rotate
    }

    const int slot = (bn * 8 + it) * 6 + cl;
    unsigned short* Op = Opart + (size_t)slot * 4096;
#pragma unroll
    for (int f = 0; f < 4; ++f)
#pragma unroll
        for (int r = 0; r < 4; ++r)
            Op[(rowl + r) * 64 + lane15 + 16 * f] = f2bf(oacc[f][r]);
    if (lane15 == 0) {
        float* msp = ms + (size_t)slot * 64;
#pragma unroll
        for (int r = 0; r < 4; ++r) msp[rowl + r] = srowv[r];
    }
}

// ---------------------------------------------------------------------------
// Split-j merge: block = (head, i-tile); sums <=6 partials per row.
// ---------------------------------------------------------------------------
__global__ __launch_bounds__(256)
void attn_merge(const unsigned short* __restrict__ Opart, const float* __restrict__ ms,
                unsigned short* __restrict__ avec) {
    const int blk = blockIdx.x;          // 512
    const int bn = blk & 63, it = blk >> 6;
    const int n = bn & 15, b = bn >> 4;
    const int nctt[8] = {3, 4, 4, 4, 5, 5, 5, 6};
    const int k = nctt[it];
    const int tid = threadIdx.x;
    const int r = tid >> 2, cq = (tid & 3) * 16;
    const int base_slot = (bn * 8 + it) * 6;

    float S = 0.f;
    for (int c = 0; c < k; ++c) S += ms[(size_t)(base_slot + c) * 64 + r];

    float acc[16];
#pragma unroll
    for (int j = 0; j < 16; ++j) acc[j] = 0.f;
    for (int c = 0; c < k; ++c) {
        const bf16x8* op = (const bf16x8*)(Opart + (size_t)(base_slot + c) * 4096 + r * 64 + cq);
        bf16x8 v0 = op[0], v1 = op[1];
#pragma unroll
        for (int j = 0; j < 8; ++j) {
            acc[j]     += bf2f((unsigned short)v0[j]);
            acc[8 + j] += bf2f((unsigned short)v1[j]);
        }
    }
    float inv = 1.0f / S;
    int t = (it * 64 + r) * 4 + b;
    unsigned short* dst = avec + (size_t)t * DM + n * 64 + cq;
#pragma unroll
    for (int j = 0; j < 16; ++j) dst[j] = f2bf(acc[j] * inv);
}

// ---------------------------------------------------------------------------
// LayerNorm with fused split-K reduce: h = LN(hin + res0 + res1 [+ bias2])
// ---------------------------------------------------------------------------
__global__ __launch_bounds__(256)
void ln_kernel(const float* __restrict__ hin, const float* __restrict__ res0,
               const float* __restrict__ res1, const float* __restrict__ bias2,
               const float* __restrict__ g, const float* __restrict__ bb,
               float* __restrict__ hout, unsigned short* __restrict__ hbf) {
    __shared__ float ls[8];
    const int t = blockIdx.x, tid = threadIdx.x;
    float4 x = ((const float4*)(hin + (size_t)t * DM))[tid];
    float4 r0 = ((const float4*)(res0 + (size_t)t * DM))[tid];
    float4 r1 = ((const float4*)(res1 + (size_t)t * DM))[tid];
    float v0 = x.x + r0.x + r1.x, v1 = x.y + r0.y + r1.y;
    float v2 = x.z + r0.z + r1.z, v3 = x.w + r0.w + r1.w;
    if (bias2) {
        float4 b2 = ((const float4*)bias2)[tid];
        v0 += b2.x; v1 += b2.y; v2 += b2.z; v3 += b2.w;
    }
    float s = v0 + v1 + v2 + v3;
    float sq = v0 * v0 + v1 * v1 + v2 * v2 + v3 * v3;
#pragma unroll
    for (int off = 1; off < 64; off <<= 1) {
        s += __shfl_xor(s, off);
        sq += __shfl_xor(sq, off);
    }
    const int w = tid >> 6;
    if ((tid & 63) == 0) { ls[w] = s; ls[4 + w] = sq; }
    __syncthreads();
    s = ls[0] + ls[1] + ls[2] + ls[3];
    sq = ls[4] + ls[5] + ls[6] + ls[7];
    float mu = s * (1.f / 1024.f);
    float var = sq * (1.f / 1024.f) - mu * mu;
    float rstd = rsqrtf(var + 1e-5f);
    float y[4] = {v0, v1, v2, v3};
    float4 of;
    uint2 ob;
    float* op = &of.x;
#pragma unroll
    for (int j = 0; j < 4; ++j) {
        int d = tid * 4 + j;
        op[j] = (y[j] - mu) * rstd * g[d] + bb[d];
    }
    ob.x = (unsigned)f2bf(of.x) | ((unsigned)f2bf(of.y) << 16);
    ob.y = (unsigned)f2bf(of.z) | ((unsigned)f2bf(of.w) << 16);
    ((float4*)(hout + (size_t)t * DM))[tid] = of;
    ((uint2*)(hbf + (size_t)t * DM))[tid] = ob;
}

__global__ __launch_bounds__(256)
void out_kernel(const float* __restrict__ h, float* __restrict__ out) {
    const int t = blockIdx.x, tid = threadIdx.x;
    const int i = t >> 2, b = t & 3;
    ((float4*)(out + ((size_t)b * QLEN + i) * DM))[tid] =
        ((const float4*)(h + (size_t)t * DM))[tid];
}

// ---------------------------------------------------------------------------
extern "C" void kernel_launch(void* const* d_in, const int* in_sizes, int n_in,
                              void* d_out, int out_size, void* d_ws, size_t ws_size,
                              hipStream_t stream) {
    const int* ids = (const int*)d_in[0];
    const float* mems = (const float*)d_in[1];
    const float* embp[4] = {nullptr, nullptr, nullptr, nullptr};
    const float* projp[4] = {nullptr, nullptr, nullptr, nullptr};
    const long long esz[4] = {20000LL * 1024, 20000LL * 256, 160000LL * 64, 67735LL * 16};
    const long long psz[4] = {1024LL * 1024, 256LL * 1024, 64LL * 1024, 16LL * 1024};
    for (int idx = 2; idx <= 9 && idx < n_in; ++idx) {
        long long s = in_sizes[idx];
        for (int c = 0; c < 4; ++c) {
            if (s == esz[c]) embp[c] = (const float*)d_in[idx];
            else if (s == psz[c]) projp[c] = (const float*)d_in[idx];
        }
    }
    const float* qkvW = (const float*)d_in[10];
    const float* rW   = (const float*)d_in[11];
    const float* oW   = (const float*)d_in[12];
    const float* rwb  = (const float*)d_in[13];
    const float* rrb  = (const float*)d_in[14];
    const float* ln1g = (const float*)d_in[15];
    const float* ln1b = (const float*)d_in[16];
    const float* ffw1 = (const float*)d_in[17];
    const float* ffb1 = (const float*)d_in[18];
    const float* ffw2 = (const float*)d_in[19];
    const float* ffb2 = (const float*)d_in[20];
    const float* ln2g = (const float*)d_in[21];
    const float* ln2b = (const float*)d_in[22];

    size_t off = 0;
    char* base = (char*)d_ws;
    auto alloc = [&](size_t bytes) -> char* {
        char* p = base + off;
        off = (off + bytes + 255) & ~(size_t)255;
        return p;
    };
    unsigned short* qkvT  = (unsigned short*)alloc(3072ull * 1024 * 2);
    unsigned short* rT    = (unsigned short*)alloc(1024ull * 1024 * 2);
    unsigned short* oT    = (unsigned short*)alloc(1024ull * 1024 * 2);
    unsigned short* w1T   = (unsigned short*)alloc(4096ull * 1024 * 2);
    unsigned short* w2T   = (unsigned short*)alloc(1024ull * 4096 * 2);
    unsigned short* embA  = (unsigned short*)alloc(2048ull * EK * 2);
    unsigned short* embBT = (unsigned short*)alloc(1024ull * EK * 2);
    float* h              = (float*)alloc(2048ull * 1024 * 4);
    unsigned short* hbf   = (unsigned short*)alloc(2048ull * 1024 * 2);
    unsigned short* catb  = (unsigned short*)alloc(4096ull * 1024 * 2);
    unsigned short* posb  = (unsigned short*)alloc(1024ull * 1024 * 2);
    unsigned short* Qw    = (unsigned short*)alloc(4ull * 16 * 512 * 64 * 2);
    unsigned short* Qr    = (unsigned short*)alloc(4ull * 16 * 512 * 64 * 2);
    unsigned short* Kb    = (unsigned short*)alloc(4ull * 16 * 1024 * 64 * 2);
    unsigned short* VTb   = (unsigned short*)alloc(4ull * 16 * 1024 * 64 * 2);
    unsigned short* Rb    = (unsigned short*)alloc(16ull * 1024 * 64 * 2);
    unsigned short* avec  = (unsigned short*)alloc(2048ull * 1024 * 2);
    float* resid01        = (float*)alloc(2ull * 2048 * 1024 * 4);        // 16 MB
    unsigned short* ff1b  = (unsigned short*)alloc(2048ull * 4096 * 2);
    unsigned short* Opart = (unsigned short*)alloc(3072ull * 4096 * 2);   // 24 MB
    float* msbuf          = (float*)alloc(3072ull * 64 * 4);              // 0.75 MB
    unsigned short* BDs   = (unsigned short*)alloc(64ull * 512 * BDLD * 2); // 75.5 MB
    (void)ws_size; (void)out_size;

    unsigned short* catbHi = catb + 2048ull * 1024;   // h-half of cat (bf16)
    float* resid1 = resid01 + 2048ull * 1024;

    // ---- embeddings (gather + GEMM) + positional table ----
    emb_gather<<<(2048 * 176 + 255) / 256, 256, 0, stream>>>(
        ids, embp[0], embp[1], embp[2], embp[3], embA);
    transpose_pad<<<dim3(32, 32), 256, 0, stream>>>(projp[0], embBT, 1024, 1024, EK, 0);
    transpose_pad<<<dim3(32, 8),  256, 0, stream>>>(projp[1], embBT, 256,  1024, EK, 1024);
    transpose_pad<<<dim3(32, 2),  256, 0, stream>>>(projp[2], embBT, 64,   1024, EK, 1280);
    transpose_pad<<<dim3(32, 2),  256, 0, stream>>>(projp[3], embBT, 16,   1024, EK, 1344);
    pos_kernel<<<1024, 256, 0, stream>>>(posb);
    gemm_bt<5, 128><<<(2048 / 128) * (1024 / 128), 256, 0, stream>>>(
        embA, embBT, h, catbHi, nullptr, 2048, 1024, EK);

    for (int l = 0; l < N_LAYER; ++l) {
        const float* qkvWl = qkvW + (size_t)l * 1024 * 3072;
        const float* rWl   = rW + (size_t)l * 1024 * 1024;
        const float* oWl   = oW + (size_t)l * 1024 * 1024;
        const float* w1l   = ffw1 + (size_t)l * 1024 * 4096;
        const float* w2l   = ffw2 + (size_t)l * 4096 * 1024;

        prep_all<<<5376, 256, 0, stream>>>(qkvWl, rWl, oWl, w1l, w2l,
                                           qkvT, rT, oT, w1T, w2T,
                                           mems + (size_t)l * 2048 * 1024, catb);

        qkv_rk_gemm<<<1408, 256, 0, stream>>>(catb, posb, qkvT, rT,
                                              rwb + l * 1024, rrb + l * 1024,
                                              Qw, Qr, Kb, VTb, Rb);

        bd_gemm<<<64 * 26, 256, 0, stream>>>(Qr, Rb, BDs);

        attn_part<<<64 * 144, 64, 0, stream>>>(Qw, Kb, VTb, BDs, Opart, msbuf);
        attn_merge<<<512, 256, 0, stream>>>(Opart, msbuf, avec);

        gemm_sk<64><<<2 * (2048 / 128) * (1024 / 64), 256, 0, stream>>>(
            avec, oT, resid01, 2048, 1024, 1024);
        ln_kernel<<<2048, 256, 0, stream>>>(h, resid01, resid1, nullptr,
                                            ln1g + l * 1024, ln1b + l * 1024, h, hbf);

        gemm_bt<1, 64><<<(2048 / 128) * (4096 / 64), 256, 0, stream>>>(
            hbf, w1T, nullptr, ff1b, ffb1 + l * 4096, 2048, 4096, 1024);

        gemm_sk<64><<<2 * (2048 / 128) * (1024 / 64), 256, 0, stream>>>(
            ff1b, w2T, resid01, 2048, 1024, 4096);
        ln_kernel<<<2048, 256, 0, stream>>>(h, resid01, resid1, ffb2 + l * 1024,
                                            ln2g + l * 1024, ln2b + l * 1024, h,
                                            (l < 3) ? catbHi : hbf);
    }

    out_kernel<<<2048, 256, 0, stream>>>(h, (float*)d_out);
}